// Round 1
// baseline (5762.296 us; speedup 1.0000x reference)
//
#include <hip/hip_runtime.h>
#include <math.h>

constexpr int Bc   = 4;
constexpr int Nc   = 200;
constexpr int Cc   = 64;
constexpr int Mc   = 600;    // 3*N
constexpr int ATTc = 128;
constexpr int OUTFc = 128;
constexpr int PREDc = 12;
constexpr int CHUNK = 8;     // batch-window chunk for attention buffers

static __device__ __forceinline__ float wave_sum(float v) {
#pragma unroll
    for (int o = 32; o > 0; o >>= 1) v += __shfl_down(v, o, 64);
    return v;
}
static __device__ __forceinline__ float wave_max(float v) {
#pragma unroll
    for (int o = 32; o > 0; o >>= 1) v = fmaxf(v, __shfl_down(v, o, 64));
    return v;
}

// ---------------- embed + sliding window ----------------
// dst[b, w, j*N+n, c] = src[b, w+j, n, c] + temb[w+j, c] + semb[n, c]
__global__ __launch_bounds__(256)
void embed_window_k(const float* __restrict__ src, const float* __restrict__ temb,
                    const float* __restrict__ semb, float* __restrict__ dst,
                    int Tin, int nw, long total)
{
    long idx = (long)blockIdx.x * 256 + threadIdx.x;
    if (idx >= total) return;
    int c = (int)(idx & 63);
    long r = idx >> 6;
    int n = (int)(r % Nc); r /= Nc;
    int j = (int)(r % 3);  r /= 3;
    int w = (int)(r % nw);
    int b = (int)(r / nw);
    int t = w + j;
    dst[idx] = src[(((long)b * Tin + t) * Nc + n) * Cc + c]
             + temb[t * Cc + c] + semb[n * Cc + c];
}

// ---------------- node mean over (B, nw) ----------------
__global__ __launch_bounds__(256)
void node_mean_k(const float* __restrict__ cur, float* __restrict__ node, int BW)
{
    int idx = blockIdx.x * 256 + threadIdx.x;
    if (idx >= Mc * Cc) return;
    float s = 0.f;
    for (int bw = 0; bw < BW; bw++) s += cur[(long)bw * Mc * Cc + idx];
    node[idx] = s * (1.f / BW);
}

// ---------------- generic tiled fp32 GEMM ----------------
// C = epi(alpha * A·op(B) + bias). A: M×K (lda). B: BT ? N×K (C=A·B^T) : K×N.
// RELUB applies relu to B on load. EPI: 0 none, 1 sigmoid, 2 relu.
// Batched over blockIdx.z with element strides sA/sB/sC.
template<bool BT, bool RELUB, int EPI>
__global__ __launch_bounds__(256)
void gemm_k(const float* __restrict__ A, const float* __restrict__ Bm,
            const float* __restrict__ bias, float* __restrict__ C,
            int M, int N, int K, int lda, int ldb, int ldc,
            long sA, long sB, long sC, float alpha)
{
    __shared__ float As[16][65];
    __shared__ float Bs[16][65];
    const int z = blockIdx.z;
    A  += (long)z * sA;
    Bm += (long)z * sB;
    C  += (long)z * sC;
    const int m0 = blockIdx.y * 64, n0 = blockIdx.x * 64;
    const int t = threadIdx.x;
    const int tx = t & 15, ty = t >> 4;
    float acc[4][4] = {};
    for (int k0 = 0; k0 < K; k0 += 16) {
        {   // A tile: rows m0..m0+63, k k0..k0+15 -> As[k][m]
            int r = t >> 2, kb = (t & 3) << 2;
            int gm = m0 + r;
            const float* ap = A + (long)gm * lda + k0 + kb;
#pragma unroll
            for (int i = 0; i < 4; i++) {
                int gk = k0 + kb + i;
                As[kb + i][r] = (gm < M && gk < K) ? ap[i] : 0.f;
            }
        }
        if (!BT) {  // B K×N -> Bs[k][n]
            int nn = t & 63, kq = t >> 6;
#pragma unroll
            for (int i = 0; i < 4; i++) {
                int kk = kq * 4 + i;
                int gk = k0 + kk, gn = n0 + nn;
                float v = (gk < K && gn < N) ? Bm[(long)gk * ldb + gn] : 0.f;
                if (RELUB) v = fmaxf(v, 0.f);
                Bs[kk][nn] = v;
            }
        } else {    // B N×K -> Bs[k][n]
            int nn = t >> 2, kb = (t & 3) << 2;
            int gn = n0 + nn;
            const float* bp = Bm + (long)gn * ldb + k0 + kb;
#pragma unroll
            for (int i = 0; i < 4; i++) {
                int gk = k0 + kb + i;
                float v = (gn < N && gk < K) ? bp[i] : 0.f;
                if (RELUB) v = fmaxf(v, 0.f);
                Bs[kb + i][nn] = v;
            }
        }
        __syncthreads();
#pragma unroll
        for (int kk = 0; kk < 16; kk++) {
            float a[4], b[4];
#pragma unroll
            for (int i = 0; i < 4; i++) a[i] = As[kk][ty * 4 + i];
#pragma unroll
            for (int j = 0; j < 4; j++) b[j] = Bs[kk][tx * 4 + j];
#pragma unroll
            for (int i = 0; i < 4; i++)
#pragma unroll
                for (int j = 0; j < 4; j++) acc[i][j] += a[i] * b[j];
        }
        __syncthreads();
    }
#pragma unroll
    for (int i = 0; i < 4; i++) {
        int gm = m0 + ty * 4 + i;
        if (gm >= M) continue;
#pragma unroll
        for (int j = 0; j < 4; j++) {
            int gn = n0 + tx * 4 + j;
            if (gn >= N) continue;
            float v = acc[i][j] * alpha;
            if (bias) v += bias[gn];
            if (EPI == 1) v = 1.f / (1.f + __expf(-v));
            if (EPI == 2) v = fmaxf(v, 0.f);
            C[(long)gm * ldc + gn] = v;
        }
    }
}

// ---------------- softmax * adj, renormalize (in place over score rows) ----
__global__ __launch_bounds__(256)
void softmax_adj_k(float* __restrict__ sc, const float* __restrict__ adj)
{
    __shared__ float red[4];
    long row = blockIdx.x;
    int m = (int)(row % Mc);
    float* s = sc + row * Mc;
    const float* a = adj + (long)m * Mc;
    int t = threadIdx.x;

    float mx = -1e30f;
    for (int j = t; j < Mc; j += 256) mx = fmaxf(mx, s[j]);
    mx = wave_max(mx);
    if ((t & 63) == 0) red[t >> 6] = mx;
    __syncthreads();
    mx = fmaxf(fmaxf(red[0], red[1]), fmaxf(red[2], red[3]));
    __syncthreads();

    float sum = 0.f;
    for (int j = t; j < Mc; j += 256) {
        float p = __expf(s[j] - mx);
        s[j] = p;
        sum += p;
    }
    sum = wave_sum(sum);
    if ((t & 63) == 0) red[t >> 6] = sum;
    __syncthreads();
    float E = red[0] + red[1] + red[2] + red[3];
    __syncthreads();

    float invE = 1.f / E;
    float ss = 0.f;
    for (int j = t; j < Mc; j += 256) {
        float aw = s[j] * invE * a[j];
        s[j] = aw;
        ss += aw;
    }
    ss = wave_sum(ss);
    if ((t & 63) == 0) red[t >> 6] = ss;
    __syncthreads();
    float SS = red[0] + red[1] + red[2] + red[3];

    float scf = (SS > 0.f) ? 1.f / (SS + 1e-8f) : 0.f;
    for (int j = t; j < Mc; j += 256) s[j] *= scf;
}

// ---------------- running max of middle-window slice [2N:3N] ---------------
__global__ __launch_bounds__(256)
void cand_update_k(const float* __restrict__ cur, float* __restrict__ cand,
                   int bw0, long total, int first)
{
    long idx = (long)blockIdx.x * 256 + threadIdx.x;
    if (idx >= total) return;
    int c = (int)(idx & 63);
    long r = idx >> 6;
    int n = (int)(r % Nc);
    int i = (int)(r / Nc);
    long bw = bw0 + i;
    float v = cur[((bw * Mc) + 2 * Nc + n) * Cc + c];
    long o = ((bw * Nc) + n) * Cc + c;
    cand[o] = first ? v : fmaxf(cand[o], v);
}

// ---------------- output: gather-transpose, GEMM(512->128), relu, tile x12 -
__global__ __launch_bounds__(128)
void output_k(const float* __restrict__ h2, const float* __restrict__ Wo,
              const float* __restrict__ bo, float* __restrict__ out)
{
    __shared__ float ds[512];
    int row = blockIdx.x;           // b*N + n
    int b = row / Nc, n = row % Nc;
    int t = threadIdx.x;            // 0..127 -> output feature
    for (int e = t; e < 512; e += 128) {
        int tt = e >> 6, c = e & 63;
        ds[e] = h2[(((long)b * 8 + tt) * Nc + n) * Cc + c];
    }
    __syncthreads();
    float acc = bo[t];
    for (int e = 0; e < 512; e++) acc += ds[e] * Wo[e * OUTFc + t];
    acc = fmaxf(acc, 0.f);
    for (int p = 0; p < PREDc; p++)
        out[(((long)b * PREDc + p) * Nc + n) * (long)OUTFc + t] = acc;
}

extern "C" void kernel_launch(void* const* d_in, const int* in_sizes, int n_in,
                              void* d_out, int out_size, void* d_ws, size_t ws_size,
                              hipStream_t stream)
{
    (void)in_sizes; (void)n_in; (void)out_size; (void)ws_size;
    const float* x     = (const float*)d_in[0];
    // d_in[1] cur_epi, d_in[2] his_hn, d_in[3] his_cn: LSTM branch is dead code
    const float* Wqkv  = (const float*)d_in[4];
    const float* bqkv  = (const float*)d_in[5];
    const float* Wlin  = (const float*)d_in[6];
    const float* blin  = (const float*)d_in[7];
    const float* Wa    = (const float*)d_in[8];
    const float* Wb    = (const float*)d_in[9];
    const float* temb0 = (const float*)d_in[13];
    const float* temb1 = (const float*)d_in[14];
    const float* semb  = (const float*)d_in[15];
    const float* Wo    = (const float*)d_in[16];
    const float* bo    = (const float*)d_in[17];
    float* out = (float*)d_out;

    // workspace layout (floats), ~30 MB total
    float* ws   = (float*)d_ws;
    float* CUR  = ws;                              // 40*600*64   = 1,536,000
    float* QKV  = CUR  + 40 * Mc * Cc;             // CHUNK*600*384
    float* SC   = QKV  + (long)CHUNK * Mc * 384;   // CHUNK*600*600
    float* ATTB = SC   + (long)CHUNK * Mc * Mc;    // CHUNK*600*128
    float* NODE = ATTB + (long)CHUNK * Mc * ATTc;  // 600*64
    float* NA   = NODE + Mc * Cc;
    float* NB   = NA   + Mc * Cc;
    float* ADJ  = NB   + Mc * Cc;                  // 600*600
    float* CAND = ADJ  + Mc * Mc;                  // 40*200*64

    const float inv_sqrt_att = 0.08838834764831845f; // 1/sqrt(128)

    for (int layer = 0; layer < 2; layer++) {
        int Tin = layer ? 10 : 12;
        int nw  = Tin - 2;
        int BW  = Bc * nw;                         // 40 then 32
        const float* src  = layer ? CAND : x;      // layer-2 input = layer-1 cand max
        const float* temb = layer ? temb1 : temb0;

        long etotal = (long)BW * Mc * Cc;
        embed_window_k<<<dim3((unsigned)((etotal + 255) / 256)), dim3(256), 0, stream>>>(
            src, temb, semb, CUR, Tin, nw, etotal);

        for (int it = 0; it < 3; it++) {
            // adjacency from mean node features (LSTM part of adjgen is dead)
            node_mean_k<<<dim3((Mc * Cc + 255) / 256), dim3(256), 0, stream>>>(CUR, NODE, BW);
            gemm_k<false, false, 0><<<dim3(1, 10, 1), dim3(256), 0, stream>>>(
                NODE, Wa, nullptr, NA, Mc, Cc, Cc, Cc, Cc, Cc, 0, 0, 0, 1.f);
            gemm_k<false, false, 0><<<dim3(1, 10, 1), dim3(256), 0, stream>>>(
                NODE, Wb, nullptr, NB, Mc, Cc, Cc, Cc, Cc, Cc, 0, 0, 0, 1.f);
            gemm_k<true, false, 1><<<dim3(10, 10, 1), dim3(256), 0, stream>>>(
                NA, NB, nullptr, ADJ, Mc, Mc, Cc, Cc, Cc, Mc, 0, 0, 0, 0.125f);

            for (int bw0 = 0; bw0 < BW; bw0 += CHUNK) {
                int cs = (BW - bw0 < CHUNK) ? (BW - bw0) : CHUNK;
                float* curc = CUR + (long)bw0 * Mc * Cc;
                int Mrows = cs * Mc;
                // QKV = cur @ Wqkv + bqkv   (rows flattened over chunk)
                gemm_k<false, false, 0><<<dim3(6, (Mrows + 63) / 64, 1), dim3(256), 0, stream>>>(
                    curc, Wqkv, bqkv, QKV, Mrows, 3 * ATTc, Cc, Cc, 3 * ATTc, 3 * ATTc,
                    0, 0, 0, 1.f);
                // scores = Q K^T / sqrt(ATT), batched per window
                gemm_k<true, false, 0><<<dim3(10, 10, cs), dim3(256), 0, stream>>>(
                    QKV, QKV + ATTc, nullptr, SC, Mc, Mc, ATTc, 3 * ATTc, 3 * ATTc, Mc,
                    (long)Mc * 3 * ATTc, (long)Mc * 3 * ATTc, (long)Mc * Mc, inv_sqrt_att);
                // softmax * adj, renormalize (in place)
                softmax_adj_k<<<dim3(cs * Mc), dim3(256), 0, stream>>>(SC, ADJ);
                // att = W @ relu(V)
                gemm_k<false, true, 0><<<dim3(2, 10, cs), dim3(256), 0, stream>>>(
                    SC, QKV + 2 * ATTc, nullptr, ATTB, Mc, ATTc, Mc, Mc, 3 * ATTc, ATTc,
                    (long)Mc * Mc, (long)Mc * 3 * ATTc, (long)Mc * ATTc, 1.f);
                // cur_next = att @ Wlin + blin  (in place over cur chunk)
                gemm_k<false, false, 0><<<dim3(1, (Mrows + 63) / 64, 1), dim3(256), 0, stream>>>(
                    ATTB, Wlin, blin, curc, Mrows, Cc, ATTc, ATTc, Cc, Cc, 0, 0, 0, 1.f);
                // running max of middle window
                long ctotal = (long)cs * Nc * Cc;
                cand_update_k<<<dim3((unsigned)((ctotal + 255) / 256)), dim3(256), 0, stream>>>(
                    CUR, CAND, bw0, ctotal, it == 0 ? 1 : 0);
            }
        }
    }
    output_k<<<dim3(Bc * Nc), dim3(128), 0, stream>>>(CAND, Wo, bo, out);
}

// Round 2
// 2528.695 us; speedup vs baseline: 2.2788x; 2.2788x over previous
//
#include <hip/hip_runtime.h>
#include <math.h>

constexpr int Bc   = 4;
constexpr int Nc   = 200;
constexpr int Cc   = 64;
constexpr int Mc   = 600;    // 3*N
constexpr int ATTc = 128;
constexpr int OUTFc = 128;
constexpr int PREDc = 12;
constexpr int MAXBW = 40;

static __device__ __forceinline__ float wave_sum(float v) {
#pragma unroll
    for (int o = 32; o > 0; o >>= 1) v += __shfl_down(v, o, 64);
    return v;
}
static __device__ __forceinline__ float wave_max(float v) {
#pragma unroll
    for (int o = 32; o > 0; o >>= 1) v = fmaxf(v, __shfl_down(v, o, 64));
    return v;
}

// ---------------- embed + sliding window ----------------
// dst[b, w, j*N+n, c] = src[b, w+j, n, c] + temb[w+j, c] + semb[n, c]
__global__ __launch_bounds__(256)
void embed_window_k(const float* __restrict__ src, const float* __restrict__ temb,
                    const float* __restrict__ semb, float* __restrict__ dst,
                    int Tin, int nw, long total)
{
    long idx = (long)blockIdx.x * 256 + threadIdx.x;
    if (idx >= total) return;
    int c = (int)(idx & 63);
    long r = idx >> 6;
    int n = (int)(r % Nc); r /= Nc;
    int j = (int)(r % 3);  r /= 3;
    int w = (int)(r % nw);
    int b = (int)(r / nw);
    int t = w + j;
    dst[idx] = src[(((long)b * Tin + t) * Nc + n) * Cc + c]
             + temb[t * Cc + c] + semb[n * Cc + c];
}

// ---------------- node mean over (B, nw) ----------------
__global__ __launch_bounds__(256)
void node_mean_k(const float* __restrict__ cur, float* __restrict__ node, int BW)
{
    int idx = blockIdx.x * 256 + threadIdx.x;
    if (idx >= Mc * Cc) return;
    float s = 0.f;
    for (int bw = 0; bw < BW; bw++) s += cur[(long)bw * Mc * Cc + idx];
    node[idx] = s * (1.f / BW);
}

// ---------------- generic tiled fp32 GEMM ----------------
// C = epi(alpha * A·op(B) + bias). A: M×K (lda). B: BT ? N×K (C=A·B^T) : K×N.
// RELUB applies relu to B on load. EPI: 0 none, 1 sigmoid, 2 relu.
// Batched over blockIdx.z with element strides sA/sB/sC.
template<bool BT, bool RELUB, int EPI>
__global__ __launch_bounds__(256)
void gemm_k(const float* __restrict__ A, const float* __restrict__ Bm,
            const float* __restrict__ bias, float* __restrict__ C,
            int M, int N, int K, int lda, int ldb, int ldc,
            long sA, long sB, long sC, float alpha)
{
    // stride 68: keeps float4 alignment for ds_read_b128, 4-bank row shift
    __shared__ float As[16][68];
    __shared__ float Bs[16][68];
    const int z = blockIdx.z;
    A  += (long)z * sA;
    Bm += (long)z * sB;
    C  += (long)z * sC;
    const int m0 = blockIdx.y * 64, n0 = blockIdx.x * 64;
    const int t = threadIdx.x;
    const int tx = t & 15, ty = t >> 4;
    float acc[4][4] = {};
    for (int k0 = 0; k0 < K; k0 += 16) {
        {   // A tile: rows m0..m0+63, k k0..k0+15 -> As[k][m]
            int r = t >> 2, kb = (t & 3) << 2;
            int gm = m0 + r;
            const float* ap = A + (long)gm * lda + k0 + kb;
#pragma unroll
            for (int i = 0; i < 4; i++) {
                int gk = k0 + kb + i;
                As[kb + i][r] = (gm < M && gk < K) ? ap[i] : 0.f;
            }
        }
        if (!BT) {  // B K×N -> Bs[k][n]
            int nn = t & 63, kq = t >> 6;
#pragma unroll
            for (int i = 0; i < 4; i++) {
                int kk = kq * 4 + i;
                int gk = k0 + kk, gn = n0 + nn;
                float v = (gk < K && gn < N) ? Bm[(long)gk * ldb + gn] : 0.f;
                if (RELUB) v = fmaxf(v, 0.f);
                Bs[kk][nn] = v;
            }
        } else {    // B N×K -> Bs[k][n]
            int nn = t >> 2, kb = (t & 3) << 2;
            int gn = n0 + nn;
            const float* bp = Bm + (long)gn * ldb + k0 + kb;
#pragma unroll
            for (int i = 0; i < 4; i++) {
                int gk = k0 + kb + i;
                float v = (gn < N && gk < K) ? bp[i] : 0.f;
                if (RELUB) v = fmaxf(v, 0.f);
                Bs[kb + i][nn] = v;
            }
        }
        __syncthreads();
#pragma unroll
        for (int kk = 0; kk < 16; kk++) {
            const float4 a4 = *(const float4*)&As[kk][ty * 4];
            const float4 b4 = *(const float4*)&Bs[kk][tx * 4];
            const float a[4] = {a4.x, a4.y, a4.z, a4.w};
            const float b[4] = {b4.x, b4.y, b4.z, b4.w};
#pragma unroll
            for (int i = 0; i < 4; i++)
#pragma unroll
                for (int j = 0; j < 4; j++) acc[i][j] += a[i] * b[j];
        }
        __syncthreads();
    }
#pragma unroll
    for (int i = 0; i < 4; i++) {
        int gm = m0 + ty * 4 + i;
        if (gm >= M) continue;
#pragma unroll
        for (int j = 0; j < 4; j++) {
            int gn = n0 + tx * 4 + j;
            if (gn >= N) continue;
            float v = acc[i][j] * alpha;
            if (bias) v += bias[gn];
            if (EPI == 1) v = 1.f / (1.f + __expf(-v));
            if (EPI == 2) v = fmaxf(v, 0.f);
            C[(long)gm * ldc + gn] = v;
        }
    }
}

// ---------------- softmax * adj, renormalize (in place over score rows) ----
__global__ __launch_bounds__(256)
void softmax_adj_k(float* __restrict__ sc, const float* __restrict__ adj)
{
    __shared__ float red[4];
    long row = blockIdx.x;
    int m = (int)(row % Mc);
    float* s = sc + row * Mc;
    const float* a = adj + (long)m * Mc;
    int t = threadIdx.x;

    float mx = -1e30f;
    for (int j = t; j < Mc; j += 256) mx = fmaxf(mx, s[j]);
    mx = wave_max(mx);
    if ((t & 63) == 0) red[t >> 6] = mx;
    __syncthreads();
    mx = fmaxf(fmaxf(red[0], red[1]), fmaxf(red[2], red[3]));
    __syncthreads();

    float sum = 0.f;
    for (int j = t; j < Mc; j += 256) {
        float p = __expf(s[j] - mx);
        s[j] = p;
        sum += p;
    }
    sum = wave_sum(sum);
    if ((t & 63) == 0) red[t >> 6] = sum;
    __syncthreads();
    float E = red[0] + red[1] + red[2] + red[3];
    __syncthreads();

    float invE = 1.f / E;
    float ss = 0.f;
    for (int j = t; j < Mc; j += 256) {
        float aw = s[j] * invE * a[j];
        s[j] = aw;
        ss += aw;
    }
    ss = wave_sum(ss);
    if ((t & 63) == 0) red[t >> 6] = ss;
    __syncthreads();
    float SS = red[0] + red[1] + red[2] + red[3];

    float scf = (SS > 0.f) ? 1.f / (SS + 1e-8f) : 0.f;
    for (int j = t; j < Mc; j += 256) s[j] *= scf;
}

// ---------------- running max of middle-window slice [2N:3N] ---------------
__global__ __launch_bounds__(256)
void cand_update_k(const float* __restrict__ cur, float* __restrict__ cand,
                   int bw0, long total, int first)
{
    long idx = (long)blockIdx.x * 256 + threadIdx.x;
    if (idx >= total) return;
    int c = (int)(idx & 63);
    long r = idx >> 6;
    int n = (int)(r % Nc);
    int i = (int)(r / Nc);
    long bw = bw0 + i;
    float v = cur[((bw * Mc) + 2 * Nc + n) * Cc + c];
    long o = ((bw * Nc) + n) * Cc + c;
    cand[o] = first ? v : fmaxf(cand[o], v);
}

// ---------------- output: gather-transpose, GEMM(512->128), relu, tile x12 -
__global__ __launch_bounds__(128)
void output_k(const float* __restrict__ h2, const float* __restrict__ Wo,
              const float* __restrict__ bo, float* __restrict__ out)
{
    __shared__ float ds[512];
    int row = blockIdx.x;           // b*N + n
    int b = row / Nc, n = row % Nc;
    int t = threadIdx.x;            // 0..127 -> output feature
    for (int e = t; e < 512; e += 128) {
        int tt = e >> 6, c = e & 63;
        ds[e] = h2[(((long)b * 8 + tt) * Nc + n) * Cc + c];
    }
    __syncthreads();
    float acc = bo[t];
    for (int e = 0; e < 512; e++) acc += ds[e] * Wo[e * OUTFc + t];
    acc = fmaxf(acc, 0.f);
    for (int p = 0; p < PREDc; p++)
        out[(((long)b * PREDc + p) * Nc + n) * (long)OUTFc + t] = acc;
}

extern "C" void kernel_launch(void* const* d_in, const int* in_sizes, int n_in,
                              void* d_out, int out_size, void* d_ws, size_t ws_size,
                              hipStream_t stream)
{
    (void)in_sizes; (void)n_in; (void)out_size;
    const float* x     = (const float*)d_in[0];
    // d_in[1] cur_epi, d_in[2] his_hn, d_in[3] his_cn: LSTM branch is dead code
    const float* Wqkv  = (const float*)d_in[4];
    const float* bqkv  = (const float*)d_in[5];
    const float* Wlin  = (const float*)d_in[6];
    const float* blin  = (const float*)d_in[7];
    const float* Wa    = (const float*)d_in[8];
    const float* Wb    = (const float*)d_in[9];
    const float* temb0 = (const float*)d_in[13];
    const float* temb1 = (const float*)d_in[14];
    const float* semb  = (const float*)d_in[15];
    const float* Wo    = (const float*)d_in[16];
    const float* bo    = (const float*)d_in[17];
    float* out = (float*)d_out;

    // ---- workspace layout (floats) ----
    // fixed buffers, then per-window attention buffers sized by CHUNK,
    // where CHUNK is derived from ws_size (deterministic per call).
    const long fixedFl = (long)MAXBW * Mc * Cc   // CUR
                       + 3L * Mc * Cc            // NODE, NA, NB
                       + (long)Mc * Mc           // ADJ
                       + (long)MAXBW * Nc * Cc;  // CAND
    const long perwFl  = (long)Mc * 3 * ATTc     // QKV
                       + (long)Mc * Mc           // SC
                       + (long)Mc * ATTc;        // ATTB
    long avail = (long)(ws_size / 4) - fixedFl;
    int CHUNK = (int)(avail / perwFl);
    if (CHUNK > MAXBW) CHUNK = MAXBW;
    if (CHUNK < 1) CHUNK = 1;

    float* ws   = (float*)d_ws;
    float* CUR  = ws;
    float* NODE = CUR  + (long)MAXBW * Mc * Cc;
    float* NA   = NODE + Mc * Cc;
    float* NB   = NA   + Mc * Cc;
    float* ADJ  = NB   + Mc * Cc;
    float* CAND = ADJ  + (long)Mc * Mc;
    float* QKV  = CAND + (long)MAXBW * Nc * Cc;
    float* SC   = QKV  + (long)CHUNK * Mc * 3 * ATTc;
    float* ATTB = SC   + (long)CHUNK * Mc * Mc;

    const float inv_sqrt_att = 0.08838834764831845f; // 1/sqrt(128)

    for (int layer = 0; layer < 2; layer++) {
        int Tin = layer ? 10 : 12;
        int nw  = Tin - 2;
        int BW  = Bc * nw;                         // 40 then 32
        const float* src  = layer ? CAND : x;      // layer-2 input = layer-1 cand max
        const float* temb = layer ? temb1 : temb0;

        long etotal = (long)BW * Mc * Cc;
        embed_window_k<<<dim3((unsigned)((etotal + 255) / 256)), dim3(256), 0, stream>>>(
            src, temb, semb, CUR, Tin, nw, etotal);

        for (int it = 0; it < 3; it++) {
            // adjacency from mean node features (LSTM part of adjgen is dead)
            node_mean_k<<<dim3((Mc * Cc + 255) / 256), dim3(256), 0, stream>>>(CUR, NODE, BW);
            gemm_k<false, false, 0><<<dim3(1, 10, 1), dim3(256), 0, stream>>>(
                NODE, Wa, nullptr, NA, Mc, Cc, Cc, Cc, Cc, Cc, 0, 0, 0, 1.f);
            gemm_k<false, false, 0><<<dim3(1, 10, 1), dim3(256), 0, stream>>>(
                NODE, Wb, nullptr, NB, Mc, Cc, Cc, Cc, Cc, Cc, 0, 0, 0, 1.f);
            gemm_k<true, false, 1><<<dim3(10, 10, 1), dim3(256), 0, stream>>>(
                NA, NB, nullptr, ADJ, Mc, Mc, Cc, Cc, Cc, Mc, 0, 0, 0, 0.125f);

            for (int bw0 = 0; bw0 < BW; bw0 += CHUNK) {
                int cs = (BW - bw0 < CHUNK) ? (BW - bw0) : CHUNK;
                float* curc = CUR + (long)bw0 * Mc * Cc;
                int Mrows = cs * Mc;
                // QKV = cur @ Wqkv + bqkv   (rows flattened over chunk)
                gemm_k<false, false, 0><<<dim3(6, (Mrows + 63) / 64, 1), dim3(256), 0, stream>>>(
                    curc, Wqkv, bqkv, QKV, Mrows, 3 * ATTc, Cc, Cc, 3 * ATTc, 3 * ATTc,
                    0, 0, 0, 1.f);
                // scores = Q K^T / sqrt(ATT), batched per window
                gemm_k<true, false, 0><<<dim3(10, 10, cs), dim3(256), 0, stream>>>(
                    QKV, QKV + ATTc, nullptr, SC, Mc, Mc, ATTc, 3 * ATTc, 3 * ATTc, Mc,
                    (long)Mc * 3 * ATTc, (long)Mc * 3 * ATTc, (long)Mc * Mc, inv_sqrt_att);
                // softmax * adj, renormalize (in place)
                softmax_adj_k<<<dim3(cs * Mc), dim3(256), 0, stream>>>(SC, ADJ);
                // att = W @ relu(V)
                gemm_k<false, true, 0><<<dim3(2, 10, cs), dim3(256), 0, stream>>>(
                    SC, QKV + 2 * ATTc, nullptr, ATTB, Mc, ATTc, Mc, Mc, 3 * ATTc, ATTc,
                    (long)Mc * Mc, (long)Mc * 3 * ATTc, (long)Mc * ATTc, 1.f);
                // cur_next = att @ Wlin + blin  (in place over cur chunk)
                gemm_k<false, false, 0><<<dim3(1, (Mrows + 63) / 64, 1), dim3(256), 0, stream>>>(
                    ATTB, Wlin, blin, curc, Mrows, Cc, ATTc, ATTc, Cc, Cc, 0, 0, 0, 1.f);
                // running max of middle window
                long ctotal = (long)cs * Nc * Cc;
                cand_update_k<<<dim3((unsigned)((ctotal + 255) / 256)), dim3(256), 0, stream>>>(
                    CUR, CAND, bw0, ctotal, it == 0 ? 1 : 0);
            }
        }
    }
    output_k<<<dim3(Bc * Nc), dim3(128), 0, stream>>>(CAND, Wo, bo, out);
}

// Round 3
// 2260.692 us; speedup vs baseline: 2.5489x; 1.1185x over previous
//
#include <hip/hip_runtime.h>
#include <math.h>

constexpr int Bc   = 4;
constexpr int Nc   = 200;
constexpr int Cc   = 64;
constexpr int Mc   = 600;    // 3*N
constexpr int ATTc = 128;
constexpr int OUTFc = 128;
constexpr int PREDc = 12;
constexpr int MAXBW = 40;

static __device__ __forceinline__ float wave_sum(float v) {
#pragma unroll
    for (int o = 32; o > 0; o >>= 1) v += __shfl_down(v, o, 64);
    return v;
}
static __device__ __forceinline__ float wave_max(float v) {
#pragma unroll
    for (int o = 32; o > 0; o >>= 1) v = fmaxf(v, __shfl_down(v, o, 64));
    return v;
}

// ---------------- embed + sliding window ----------------
__global__ __launch_bounds__(256)
void embed_window_k(const float* __restrict__ src, const float* __restrict__ temb,
                    const float* __restrict__ semb, float* __restrict__ dst,
                    int Tin, int nw, long total)
{
    long idx = (long)blockIdx.x * 256 + threadIdx.x;
    if (idx >= total) return;
    int c = (int)(idx & 63);
    long r = idx >> 6;
    int n = (int)(r % Nc); r /= Nc;
    int j = (int)(r % 3);  r /= 3;
    int w = (int)(r % nw);
    int b = (int)(r / nw);
    int t = w + j;
    dst[idx] = src[(((long)b * Tin + t) * Nc + n) * Cc + c]
             + temb[t * Cc + c] + semb[n * Cc + c];
}

// ---------------- node mean over (B, nw) ----------------
__global__ __launch_bounds__(256)
void node_mean_k(const float* __restrict__ cur, float* __restrict__ node, int BW)
{
    int idx = blockIdx.x * 256 + threadIdx.x;
    if (idx >= Mc * Cc) return;
    float s = 0.f;
    for (int bw = 0; bw < BW; bw++) s += cur[(long)bw * Mc * Cc + idx];
    node[idx] = s * (1.f / BW);
}

// ---------------- 64-tile fp32 GEMM (for small matrices) ----------------
template<bool BT, bool RELUB, int EPI>
__global__ __launch_bounds__(256)
void gemm_k(const float* __restrict__ A, const float* __restrict__ Bm,
            const float* __restrict__ bias, float* __restrict__ C,
            int M, int N, int K, int lda, int ldb, int ldc,
            long sA, long sB, long sC, float alpha)
{
    __shared__ float As[16][68];
    __shared__ float Bs[16][68];
    const int z = blockIdx.z;
    A  += (long)z * sA;
    Bm += (long)z * sB;
    C  += (long)z * sC;
    const int m0 = blockIdx.y * 64, n0 = blockIdx.x * 64;
    const int t = threadIdx.x;
    const int tx = t & 15, ty = t >> 4;
    float acc[4][4] = {};
    for (int k0 = 0; k0 < K; k0 += 16) {
        {
            int r = t >> 2, kb = (t & 3) << 2;
            int gm = m0 + r;
            const float* ap = A + (long)gm * lda + k0 + kb;
#pragma unroll
            for (int i = 0; i < 4; i++) {
                int gk = k0 + kb + i;
                As[kb + i][r] = (gm < M && gk < K) ? ap[i] : 0.f;
            }
        }
        if (!BT) {
            int nn = t & 63, kq = t >> 6;
#pragma unroll
            for (int i = 0; i < 4; i++) {
                int kk = kq * 4 + i;
                int gk = k0 + kk, gn = n0 + nn;
                float v = (gk < K && gn < N) ? Bm[(long)gk * ldb + gn] : 0.f;
                if (RELUB) v = fmaxf(v, 0.f);
                Bs[kk][nn] = v;
            }
        } else {
            int nn = t >> 2, kb = (t & 3) << 2;
            int gn = n0 + nn;
            const float* bp = Bm + (long)gn * ldb + k0 + kb;
#pragma unroll
            for (int i = 0; i < 4; i++) {
                int gk = k0 + kb + i;
                float v = (gn < N && gk < K) ? bp[i] : 0.f;
                if (RELUB) v = fmaxf(v, 0.f);
                Bs[kb + i][nn] = v;
            }
        }
        __syncthreads();
#pragma unroll
        for (int kk = 0; kk < 16; kk++) {
            const float4 a4 = *(const float4*)&As[kk][ty * 4];
            const float4 b4 = *(const float4*)&Bs[kk][tx * 4];
            const float a[4] = {a4.x, a4.y, a4.z, a4.w};
            const float b[4] = {b4.x, b4.y, b4.z, b4.w};
#pragma unroll
            for (int i = 0; i < 4; i++)
#pragma unroll
                for (int j = 0; j < 4; j++) acc[i][j] += a[i] * b[j];
        }
        __syncthreads();
    }
#pragma unroll
    for (int i = 0; i < 4; i++) {
        int gm = m0 + ty * 4 + i;
        if (gm >= M) continue;
#pragma unroll
        for (int j = 0; j < 4; j++) {
            int gn = n0 + tx * 4 + j;
            if (gn >= N) continue;
            float v = acc[i][j] * alpha;
            if (bias) v += bias[gn];
            if (EPI == 1) v = 1.f / (1.f + __expf(-v));
            if (EPI == 2) v = fmaxf(v, 0.f);
            C[(long)gm * ldc + gn] = v;
        }
    }
}

// ---------------- 128-tile, 8x8-microtile fp32 GEMM (heavy matrices) -------
// C = alpha*A.op(B) + bias, EPI as above. 256 threads, BM=BN=128, BK=16.
// Per kk: 4 ds_read_b128 feed 64 FMAs -> DS-pipe demand ~matches capacity.
template<bool BT, bool RELUB, int EPI>
__global__ __launch_bounds__(256)
void gemm128_k(const float* __restrict__ A, const float* __restrict__ Bm,
               const float* __restrict__ bias, float* __restrict__ C,
               int M, int N, int K, int lda, int ldb, int ldc,
               long sA, long sB, long sC, float alpha)
{
    __shared__ float As[16][132];   // [k][m], stride 132 rotates banks by 4/row
    __shared__ float Bs[16][132];   // [k][n]
    const int z = blockIdx.z;
    A  += (long)z * sA;
    Bm += (long)z * sB;
    C  += (long)z * sC;
    const int m0 = blockIdx.y * 128, n0 = blockIdx.x * 128;
    const int t = threadIdx.x;
    const int tx = t & 15, ty = t >> 4;
    float acc[8][8] = {};

    for (int k0 = 0; k0 < K; k0 += 16) {
        const bool kfull = (k0 + 16 <= K);
        // ---- A tile: 128 rows x 16 k -> As[k][m] (transpose on store) ----
#pragma unroll
        for (int pass = 0; pass < 2; pass++) {
            int e = t + pass * 256;          // 0..511
            int r = e >> 2, kb = (e & 3) << 2;
            int gm = m0 + r;
            float4 v = make_float4(0.f, 0.f, 0.f, 0.f);
            if (gm < M) {
                const float* ap = A + (long)gm * lda + k0 + kb;
                if (kfull) v = *(const float4*)ap;
                else {
#pragma unroll
                    for (int i = 0; i < 4; i++)
                        if (k0 + kb + i < K) ((float*)&v)[i] = ap[i];
                }
            }
            As[kb + 0][r] = v.x; As[kb + 1][r] = v.y;
            As[kb + 2][r] = v.z; As[kb + 3][r] = v.w;
        }
        // ---- B tile -> Bs[k][n] ----
        if (!BT) {
#pragma unroll
            for (int pass = 0; pass < 2; pass++) {
                int e = t + pass * 256;
                int kk = e >> 5, n4 = (e & 31) << 2;
                int gk = k0 + kk, gn = n0 + n4;
                float4 v = make_float4(0.f, 0.f, 0.f, 0.f);
                if (gk < K) {
                    const float* bp = Bm + (long)gk * ldb + gn;
                    if (gn + 3 < N) v = *(const float4*)bp;
                    else {
#pragma unroll
                        for (int i = 0; i < 4; i++)
                            if (gn + i < N) ((float*)&v)[i] = bp[i];
                    }
                }
                if (RELUB) {
                    v.x = fmaxf(v.x, 0.f); v.y = fmaxf(v.y, 0.f);
                    v.z = fmaxf(v.z, 0.f); v.w = fmaxf(v.w, 0.f);
                }
                *(float4*)&Bs[kk][n4] = v;
            }
        } else {
#pragma unroll
            for (int pass = 0; pass < 2; pass++) {
                int e = t + pass * 256;
                int r = e >> 2, kb = (e & 3) << 2;
                int gn = n0 + r;
                float4 v = make_float4(0.f, 0.f, 0.f, 0.f);
                if (gn < N) {
                    const float* bp = Bm + (long)gn * ldb + k0 + kb;
                    if (kfull) v = *(const float4*)bp;
                    else {
#pragma unroll
                        for (int i = 0; i < 4; i++)
                            if (k0 + kb + i < K) ((float*)&v)[i] = bp[i];
                    }
                }
                if (RELUB) {
                    v.x = fmaxf(v.x, 0.f); v.y = fmaxf(v.y, 0.f);
                    v.z = fmaxf(v.z, 0.f); v.w = fmaxf(v.w, 0.f);
                }
                Bs[kb + 0][r] = v.x; Bs[kb + 1][r] = v.y;
                Bs[kb + 2][r] = v.z; Bs[kb + 3][r] = v.w;
            }
        }
        __syncthreads();
#pragma unroll
        for (int kk = 0; kk < 16; kk++) {
            float a[8], b[8];
            *(float4*)&a[0] = *(const float4*)&As[kk][ty * 8];
            *(float4*)&a[4] = *(const float4*)&As[kk][ty * 8 + 4];
            *(float4*)&b[0] = *(const float4*)&Bs[kk][tx * 8];
            *(float4*)&b[4] = *(const float4*)&Bs[kk][tx * 8 + 4];
#pragma unroll
            for (int i = 0; i < 8; i++)
#pragma unroll
                for (int j = 0; j < 8; j++) acc[i][j] += a[i] * b[j];
        }
        __syncthreads();
    }
    // ---- epilogue ----
#pragma unroll
    for (int i = 0; i < 8; i++) {
        int gm = m0 + ty * 8 + i;
        if (gm >= M) continue;
#pragma unroll
        for (int j4 = 0; j4 < 2; j4++) {
            int gn = n0 + tx * 8 + j4 * 4;
            float4 v;
#pragma unroll
            for (int q = 0; q < 4; q++) {
                float x = acc[i][j4 * 4 + q] * alpha;
                if (bias) x += bias[gn + q < N ? gn + q : 0];
                if (EPI == 1) x = 1.f / (1.f + __expf(-x));
                if (EPI == 2) x = fmaxf(x, 0.f);
                ((float*)&v)[q] = x;
            }
            float* cp = C + (long)gm * ldc + gn;
            if (gn + 3 < N) *(float4*)cp = v;
            else {
#pragma unroll
                for (int q = 0; q < 4; q++)
                    if (gn + q < N) cp[q] = ((float*)&v)[q];
            }
        }
    }
}

// ---------------- softmax * adj, renormalize (in place) ----
__global__ __launch_bounds__(256)
void softmax_adj_k(float* __restrict__ sc, const float* __restrict__ adj)
{
    __shared__ float red[4];
    long row = blockIdx.x;
    int m = (int)(row % Mc);
    float* s = sc + row * Mc;
    const float* a = adj + (long)m * Mc;
    int t = threadIdx.x;

    float mx = -1e30f;
    for (int j = t; j < Mc; j += 256) mx = fmaxf(mx, s[j]);
    mx = wave_max(mx);
    if ((t & 63) == 0) red[t >> 6] = mx;
    __syncthreads();
    mx = fmaxf(fmaxf(red[0], red[1]), fmaxf(red[2], red[3]));
    __syncthreads();

    float sum = 0.f;
    for (int j = t; j < Mc; j += 256) {
        float p = __expf(s[j] - mx);
        s[j] = p;
        sum += p;
    }
    sum = wave_sum(sum);
    if ((t & 63) == 0) red[t >> 6] = sum;
    __syncthreads();
    float E = red[0] + red[1] + red[2] + red[3];
    __syncthreads();

    float invE = 1.f / E;
    float ss = 0.f;
    for (int j = t; j < Mc; j += 256) {
        float aw = s[j] * invE * a[j];
        s[j] = aw;
        ss += aw;
    }
    ss = wave_sum(ss);
    if ((t & 63) == 0) red[t >> 6] = ss;
    __syncthreads();
    float SS = red[0] + red[1] + red[2] + red[3];

    float scf = (SS > 0.f) ? 1.f / (SS + 1e-8f) : 0.f;
    for (int j = t; j < Mc; j += 256) s[j] *= scf;
}

// ---------------- running max of middle-window slice [2N:3N] ---------------
__global__ __launch_bounds__(256)
void cand_update_k(const float* __restrict__ cur, float* __restrict__ cand,
                   int bw0, long total, int first)
{
    long idx = (long)blockIdx.x * 256 + threadIdx.x;
    if (idx >= total) return;
    int c = (int)(idx & 63);
    long r = idx >> 6;
    int n = (int)(r % Nc);
    int i = (int)(r / Nc);
    long bw = bw0 + i;
    float v = cur[((bw * Mc) + 2 * Nc + n) * Cc + c];
    long o = ((bw * Nc) + n) * Cc + c;
    cand[o] = first ? v : fmaxf(cand[o], v);
}

// ---------------- output layer ----------------
__global__ __launch_bounds__(128)
void output_k(const float* __restrict__ h2, const float* __restrict__ Wo,
              const float* __restrict__ bo, float* __restrict__ out)
{
    __shared__ float ds[512];
    int row = blockIdx.x;
    int b = row / Nc, n = row % Nc;
    int t = threadIdx.x;
    for (int e = t; e < 512; e += 128) {
        int tt = e >> 6, c = e & 63;
        ds[e] = h2[(((long)b * 8 + tt) * Nc + n) * Cc + c];
    }
    __syncthreads();
    float acc = bo[t];
    for (int e = 0; e < 512; e++) acc += ds[e] * Wo[e * OUTFc + t];
    acc = fmaxf(acc, 0.f);
    for (int p = 0; p < PREDc; p++)
        out[(((long)b * PREDc + p) * Nc + n) * (long)OUTFc + t] = acc;
}

extern "C" void kernel_launch(void* const* d_in, const int* in_sizes, int n_in,
                              void* d_out, int out_size, void* d_ws, size_t ws_size,
                              hipStream_t stream)
{
    (void)in_sizes; (void)n_in; (void)out_size;
    const float* x     = (const float*)d_in[0];
    const float* Wqkv  = (const float*)d_in[4];
    const float* bqkv  = (const float*)d_in[5];
    const float* Wlin  = (const float*)d_in[6];
    const float* blin  = (const float*)d_in[7];
    const float* Wa    = (const float*)d_in[8];
    const float* Wb    = (const float*)d_in[9];
    const float* temb0 = (const float*)d_in[13];
    const float* temb1 = (const float*)d_in[14];
    const float* semb  = (const float*)d_in[15];
    const float* Wo    = (const float*)d_in[16];
    const float* bo    = (const float*)d_in[17];
    float* out = (float*)d_out;

    const long fixedFl = (long)MAXBW * Mc * Cc
                       + 3L * Mc * Cc
                       + (long)Mc * Mc
                       + (long)MAXBW * Nc * Cc;
    const long perwFl  = (long)Mc * 3 * ATTc
                       + (long)Mc * Mc
                       + (long)Mc * ATTc;
    long avail = (long)(ws_size / 4) - fixedFl;
    int CHUNK = (int)(avail / perwFl);
    if (CHUNK > MAXBW) CHUNK = MAXBW;
    if (CHUNK < 1) CHUNK = 1;

    float* ws   = (float*)d_ws;
    float* CUR  = ws;
    float* NODE = CUR  + (long)MAXBW * Mc * Cc;
    float* NA   = NODE + Mc * Cc;
    float* NB   = NA   + Mc * Cc;
    float* ADJ  = NB   + Mc * Cc;
    float* CAND = ADJ  + (long)Mc * Mc;
    float* QKV  = CAND + (long)MAXBW * Nc * Cc;
    float* SC   = QKV  + (long)CHUNK * Mc * 3 * ATTc;
    float* ATTB = SC   + (long)CHUNK * Mc * Mc;

    const float inv_sqrt_att = 0.08838834764831845f; // 1/sqrt(128)

    for (int layer = 0; layer < 2; layer++) {
        int Tin = layer ? 10 : 12;
        int nw  = Tin - 2;
        int BW  = Bc * nw;
        const float* src  = layer ? CAND : x;
        const float* temb = layer ? temb1 : temb0;

        long etotal = (long)BW * Mc * Cc;
        embed_window_k<<<dim3((unsigned)((etotal + 255) / 256)), dim3(256), 0, stream>>>(
            src, temb, semb, CUR, Tin, nw, etotal);

        for (int it = 0; it < 3; it++) {
            node_mean_k<<<dim3((Mc * Cc + 255) / 256), dim3(256), 0, stream>>>(CUR, NODE, BW);
            gemm_k<false, false, 0><<<dim3(1, 10, 1), dim3(256), 0, stream>>>(
                NODE, Wa, nullptr, NA, Mc, Cc, Cc, Cc, Cc, Cc, 0, 0, 0, 1.f);
            gemm_k<false, false, 0><<<dim3(1, 10, 1), dim3(256), 0, stream>>>(
                NODE, Wb, nullptr, NB, Mc, Cc, Cc, Cc, Cc, Cc, 0, 0, 0, 1.f);
            gemm_k<true, false, 1><<<dim3(10, 10, 1), dim3(256), 0, stream>>>(
                NA, NB, nullptr, ADJ, Mc, Mc, Cc, Cc, Cc, Mc, 0, 0, 0, 0.125f);

            for (int bw0 = 0; bw0 < BW; bw0 += CHUNK) {
                int cs = (BW - bw0 < CHUNK) ? (BW - bw0) : CHUNK;
                float* curc = CUR + (long)bw0 * Mc * Cc;
                int Mrows = cs * Mc;
                // QKV = cur @ Wqkv + bqkv
                gemm128_k<false, false, 0><<<dim3(3, (Mrows + 127) / 128, 1), dim3(256), 0, stream>>>(
                    curc, Wqkv, bqkv, QKV, Mrows, 3 * ATTc, Cc, Cc, 3 * ATTc, 3 * ATTc,
                    0, 0, 0, 1.f);
                // scores = Q K^T / sqrt(ATT)
                gemm128_k<true, false, 0><<<dim3(5, 5, cs), dim3(256), 0, stream>>>(
                    QKV, QKV + ATTc, nullptr, SC, Mc, Mc, ATTc, 3 * ATTc, 3 * ATTc, Mc,
                    (long)Mc * 3 * ATTc, (long)Mc * 3 * ATTc, (long)Mc * Mc, inv_sqrt_att);
                // softmax * adj, renormalize
                softmax_adj_k<<<dim3(cs * Mc), dim3(256), 0, stream>>>(SC, ADJ);
                // att = W @ relu(V)
                gemm128_k<false, true, 0><<<dim3(1, 5, cs), dim3(256), 0, stream>>>(
                    SC, QKV + 2 * ATTc, nullptr, ATTB, Mc, ATTc, Mc, Mc, 3 * ATTc, ATTc,
                    (long)Mc * Mc, (long)Mc * 3 * ATTc, (long)Mc * ATTc, 1.f);
                // cur_next = att @ Wlin + blin
                gemm128_k<false, false, 0><<<dim3(1, (Mrows + 127) / 128, 1), dim3(256), 0, stream>>>(
                    ATTB, Wlin, blin, curc, Mrows, Cc, ATTc, ATTc, Cc, Cc, 0, 0, 0, 1.f);
                long ctotal = (long)cs * Nc * Cc;
                cand_update_k<<<dim3((unsigned)((ctotal + 255) / 256)), dim3(256), 0, stream>>>(
                    CUR, CAND, bw0, ctotal, it == 0 ? 1 : 0);
            }
        }
    }
    output_k<<<dim3(Bc * Nc), dim3(128), 0, stream>>>(CAND, Wo, bo, out);
}

// Round 4
// 1632.469 us; speedup vs baseline: 3.5298x; 1.3848x over previous
//
#include <hip/hip_runtime.h>
#include <hip/hip_bf16.h>
#include <math.h>

constexpr int Bc   = 4;
constexpr int Nc   = 200;
constexpr int Cc   = 64;
constexpr int Mc   = 600;    // 3*N
constexpr int ATTc = 128;
constexpr int OUTFc = 128;
constexpr int PREDc = 12;
constexpr int MAXBW = 40;

typedef short short8 __attribute__((ext_vector_type(8)));
typedef float f32x4  __attribute__((ext_vector_type(4)));

static __device__ __forceinline__ float wave_sum(float v) {
#pragma unroll
    for (int o = 32; o > 0; o >>= 1) v += __shfl_down(v, o, 64);
    return v;
}
static __device__ __forceinline__ float wave_max(float v) {
#pragma unroll
    for (int o = 32; o > 0; o >>= 1) v = fmaxf(v, __shfl_down(v, o, 64));
    return v;
}

// ---------------- embed + sliding window ----------------
__global__ __launch_bounds__(256)
void embed_window_k(const float* __restrict__ src, const float* __restrict__ temb,
                    const float* __restrict__ semb, float* __restrict__ dst,
                    int Tin, int nw, long total)
{
    long idx = (long)blockIdx.x * 256 + threadIdx.x;
    if (idx >= total) return;
    int c = (int)(idx & 63);
    long r = idx >> 6;
    int n = (int)(r % Nc); r /= Nc;
    int j = (int)(r % 3);  r /= 3;
    int w = (int)(r % nw);
    int b = (int)(r / nw);
    int t = w + j;
    dst[idx] = src[(((long)b * Tin + t) * Nc + n) * Cc + c]
             + temb[t * Cc + c] + semb[n * Cc + c];
}

// ---------------- fused node-mean + NA/NB projection ----------------
// NODE = mean over BW windows of CUR; NA = NODE@Wa, NB = NODE@Wb. Grid 10.
__global__ __launch_bounds__(256)
void mean_nab_k(const float* __restrict__ cur, const float* __restrict__ Wa,
                const float* __restrict__ Wb, float* __restrict__ NA,
                float* __restrict__ NB, int BW)
{
    __shared__ float Ns[64][68];   // [k][m] node tile, transposed
    __shared__ float Ws[64][132];  // [k][ Wa(0..63) | Wb(64..127) ]
    const int m0 = blockIdx.x * 64;
    const int t = threadIdx.x;
    for (int e = t; e < 1024; e += 256) {
        int r = e >> 4, c4 = (e & 15) << 2;
        *(float4*)&Ws[r][c4]      = *(const float4*)&Wa[r * 64 + c4];
        *(float4*)&Ws[r][64 + c4] = *(const float4*)&Wb[r * 64 + c4];
    }
    const float inv = 1.f / BW;
    for (int e = t; e < 1024; e += 256) {
        int r = e >> 4, c4 = (e & 15) << 2;
        int gm = m0 + r;
        float4 sv = make_float4(0.f, 0.f, 0.f, 0.f);
        if (gm < Mc) {
            for (int bw = 0; bw < BW; bw++) {
                const float4 v = *(const float4*)&cur[((long)bw * Mc + gm) * Cc + c4];
                sv.x += v.x; sv.y += v.y; sv.z += v.z; sv.w += v.w;
            }
            sv.x *= inv; sv.y *= inv; sv.z *= inv; sv.w *= inv;
        }
        Ns[c4 + 0][r] = sv.x; Ns[c4 + 1][r] = sv.y;
        Ns[c4 + 2][r] = sv.z; Ns[c4 + 3][r] = sv.w;
    }
    __syncthreads();
    const int ty = t >> 4, tx = t & 15;
    float acc[4][8] = {};
    for (int k = 0; k < 64; k++) {
        float av[4], bv[8];
        *(float4*)&av[0] = *(const float4*)&Ns[k][ty * 4];
        *(float4*)&bv[0] = *(const float4*)&Ws[k][tx * 8];
        *(float4*)&bv[4] = *(const float4*)&Ws[k][tx * 8 + 4];
#pragma unroll
        for (int i = 0; i < 4; i++)
#pragma unroll
            for (int j = 0; j < 8; j++) acc[i][j] += av[i] * bv[j];
    }
#pragma unroll
    for (int i = 0; i < 4; i++) {
        int gm = m0 + ty * 4 + i;
        if (gm >= Mc) continue;
#pragma unroll
        for (int j = 0; j < 8; j++) {
            int col = tx * 8 + j;
            if (col < 64) NA[gm * 64 + col] = acc[i][j];
            else          NB[gm * 64 + col - 64] = acc[i][j];
        }
    }
}

// ---------------- 64-tile fp32 GEMM (adj, Wlin) ----------------
template<bool BT, bool RELUB, int EPI>
__global__ __launch_bounds__(256)
void gemm_k(const float* __restrict__ A, const float* __restrict__ Bm,
            const float* __restrict__ bias, float* __restrict__ C,
            int M, int N, int K, int lda, int ldb, int ldc,
            long sA, long sB, long sC, float alpha)
{
    __shared__ float As[16][68];
    __shared__ float Bs[16][68];
    const int z = blockIdx.z;
    A  += (long)z * sA;
    Bm += (long)z * sB;
    C  += (long)z * sC;
    const int m0 = blockIdx.y * 64, n0 = blockIdx.x * 64;
    const int t = threadIdx.x;
    const int tx = t & 15, ty = t >> 4;
    float acc[4][4] = {};
    for (int k0 = 0; k0 < K; k0 += 16) {
        {
            int r = t >> 2, kb = (t & 3) << 2;
            int gm = m0 + r;
            const float* ap = A + (long)gm * lda + k0 + kb;
#pragma unroll
            for (int i = 0; i < 4; i++) {
                int gk = k0 + kb + i;
                As[kb + i][r] = (gm < M && gk < K) ? ap[i] : 0.f;
            }
        }
        if (!BT) {
            int nn = t & 63, kq = t >> 6;
#pragma unroll
            for (int i = 0; i < 4; i++) {
                int kk = kq * 4 + i;
                int gk = k0 + kk, gn = n0 + nn;
                float v = (gk < K && gn < N) ? Bm[(long)gk * ldb + gn] : 0.f;
                if (RELUB) v = fmaxf(v, 0.f);
                Bs[kk][nn] = v;
            }
        } else {
            int nn = t >> 2, kb = (t & 3) << 2;
            int gn = n0 + nn;
            const float* bp = Bm + (long)gn * ldb + k0 + kb;
#pragma unroll
            for (int i = 0; i < 4; i++) {
                int gk = k0 + kb + i;
                float v = (gn < N && gk < K) ? bp[i] : 0.f;
                if (RELUB) v = fmaxf(v, 0.f);
                Bs[kb + i][nn] = v;
            }
        }
        __syncthreads();
#pragma unroll
        for (int kk = 0; kk < 16; kk++) {
            const float4 a4 = *(const float4*)&As[kk][ty * 4];
            const float4 b4 = *(const float4*)&Bs[kk][tx * 4];
            const float a[4] = {a4.x, a4.y, a4.z, a4.w};
            const float b[4] = {b4.x, b4.y, b4.z, b4.w};
#pragma unroll
            for (int i = 0; i < 4; i++)
#pragma unroll
                for (int j = 0; j < 4; j++) acc[i][j] += a[i] * b[j];
        }
        __syncthreads();
    }
#pragma unroll
    for (int i = 0; i < 4; i++) {
        int gm = m0 + ty * 4 + i;
        if (gm >= M) continue;
#pragma unroll
        for (int j = 0; j < 4; j++) {
            int gn = n0 + tx * 4 + j;
            if (gn >= N) continue;
            float v = acc[i][j] * alpha;
            if (bias) v += bias[gn];
            if (EPI == 1) v = 1.f / (1.f + __expf(-v));
            if (EPI == 2) v = fmaxf(v, 0.f);
            C[(long)gm * ldc + gn] = v;
        }
    }
}

// ---------------- QKV GEMM with bf16 hi/lo split epilogue ----------------
// A = CUR [M][64], B = Wqkv [64][384]. blockIdx.x = 0/1/2 selects q/k/v.
// q,k -> row-major [gm][128] hi/lo. v -> relu, transposed [bw][col][600] hi/lo.
__global__ __launch_bounds__(256)
void qkv_split_k(const float* __restrict__ A, const float* __restrict__ Bm,
                 const float* __restrict__ bias,
                 __hip_bfloat16* __restrict__ QH, __hip_bfloat16* __restrict__ QL,
                 __hip_bfloat16* __restrict__ KH, __hip_bfloat16* __restrict__ KL,
                 __hip_bfloat16* __restrict__ VTH, __hip_bfloat16* __restrict__ VTL,
                 int M)
{
    __shared__ float As[16][132];
    __shared__ float Bs[16][132];
    const int which = blockIdx.x;          // 0=q 1=k 2=v
    const int m0 = blockIdx.y * 128, n0 = which * 128;
    const int t = threadIdx.x;
    const int tx = t & 15, ty = t >> 4;
    float acc[8][8] = {};

    for (int k0 = 0; k0 < 64; k0 += 16) {
#pragma unroll
        for (int pass = 0; pass < 2; pass++) {
            int e = t + pass * 256;
            int r = e >> 2, kb = (e & 3) << 2;
            int gm = m0 + r;
            float4 v = make_float4(0.f, 0.f, 0.f, 0.f);
            if (gm < M) v = *(const float4*)(A + (long)gm * 64 + k0 + kb);
            As[kb + 0][r] = v.x; As[kb + 1][r] = v.y;
            As[kb + 2][r] = v.z; As[kb + 3][r] = v.w;
        }
#pragma unroll
        for (int pass = 0; pass < 2; pass++) {
            int e = t + pass * 256;
            int kk = e >> 5, n4 = (e & 31) << 2;
            float4 v = *(const float4*)(Bm + (long)(k0 + kk) * 384 + n0 + n4);
            *(float4*)&Bs[kk][n4] = v;
        }
        __syncthreads();
#pragma unroll
        for (int kk = 0; kk < 16; kk++) {
            float a[8], b[8];
            *(float4*)&a[0] = *(const float4*)&As[kk][ty * 8];
            *(float4*)&a[4] = *(const float4*)&As[kk][ty * 8 + 4];
            *(float4*)&b[0] = *(const float4*)&Bs[kk][tx * 8];
            *(float4*)&b[4] = *(const float4*)&Bs[kk][tx * 8 + 4];
#pragma unroll
            for (int i = 0; i < 8; i++)
#pragma unroll
                for (int j = 0; j < 8; j++) acc[i][j] += a[i] * b[j];
        }
        __syncthreads();
    }
#pragma unroll
    for (int i = 0; i < 8; i++) {
        int gm = m0 + ty * 8 + i;
        if (gm >= M) continue;
        int bw = gm / Mc;
        int rr = gm - bw * Mc;
#pragma unroll
        for (int j = 0; j < 8; j++) {
            int col = tx * 8 + j;
            float v = acc[i][j] + bias[n0 + col];
            if (which == 2) {
                v = fmaxf(v, 0.f);
                __hip_bfloat16 h = __float2bfloat16(v);
                __hip_bfloat16 l = __float2bfloat16(v - __bfloat162float(h));
                long o = ((long)bw * ATTc + col) * Mc + rr;
                VTH[o] = h; VTL[o] = l;
            } else {
                __hip_bfloat16 h = __float2bfloat16(v);
                __hip_bfloat16 l = __float2bfloat16(v - __bfloat162float(h));
                long o = (long)gm * ATTc + col;
                if (which == 0) { QH[o] = h; QL[o] = l; }
                else            { KH[o] = h; KL[o] = l; }
            }
        }
    }
}

// ---------------- split-bf16 MFMA GEMM: C = alpha * (Ah+Al) (Bh+Bl)^T ------
// A: [M][K] bf16 (lda), B: [N][K] bf16 (ldb). C fp32 [M][N] (ldc).
// BM=BN=128, BK=32; 4 waves of 64x64 (4x4 frags of 16x16x32 mfma).
// Per-lane fragment layouts (gfx950, HW-verified): A[m=lane&15][k=(lane>>4)*8+j],
// B[k][n=lane&15] same k-mapping, D col=lane&15 row=(lane>>4)*4+reg.
__global__ __launch_bounds__(256)
void mfma_bt_k(const ushort* __restrict__ Ah, const ushort* __restrict__ Al,
               const ushort* __restrict__ Bh, const ushort* __restrict__ Bl,
               float* __restrict__ C,
               int M, int N, int K, int lda, int ldb, int ldc,
               long zA, long zB, long zC, float alpha)
{
    __shared__ __align__(16) ushort As[2][128][40];  // [hi/lo][row][k] pad 40
    __shared__ __align__(16) ushort Bs[2][128][40];
    const int z = blockIdx.z;
    Ah += (long)z * zA; Al += (long)z * zA;
    Bh += (long)z * zB; Bl += (long)z * zB;
    C  += (long)z * zC;
    const int m0 = blockIdx.y * 128, n0 = blockIdx.x * 128;
    const int t = threadIdx.x;
    const int lane = t & 63, w = t >> 6;
    const int wm = (w >> 1) * 64, wn = (w & 1) * 64;
    const int lm = lane & 15, lq = lane >> 4;

    f32x4 acc[4][4];
#pragma unroll
    for (int i = 0; i < 4; i++)
#pragma unroll
        for (int j = 0; j < 4; j++)
#pragma unroll
            for (int r = 0; r < 4; r++) acc[i][j][r] = 0.f;

    for (int k0 = 0; k0 < K; k0 += 32) {
        __syncthreads();
#pragma unroll
        for (int p = 0; p < 2; p++) {
            int e = t + p * 256;                 // 0..511
            int row = e >> 2, ks = (e & 3) << 3; // seg of 8
            int gk = k0 + ks;
            bool kin = (gk < K);                 // K % 8 == 0 -> whole-seg granularity
            {
                int gm = m0 + row;
                short8 vh, vl;
#pragma unroll
                for (int q = 0; q < 8; q++) { vh[q] = 0; vl[q] = 0; }
                if (gm < M && kin) {
                    vh = *(const short8*)(Ah + (long)gm * lda + gk);
                    vl = *(const short8*)(Al + (long)gm * lda + gk);
                }
                *(short8*)&As[0][row][ks] = vh;
                *(short8*)&As[1][row][ks] = vl;
            }
            {
                int gn = n0 + row;
                short8 vh, vl;
#pragma unroll
                for (int q = 0; q < 8; q++) { vh[q] = 0; vl[q] = 0; }
                if (gn < N && kin) {
                    vh = *(const short8*)(Bh + (long)gn * ldb + gk);
                    vl = *(const short8*)(Bl + (long)gn * ldb + gk);
                }
                *(short8*)&Bs[0][row][ks] = vh;
                *(short8*)&Bs[1][row][ks] = vl;
            }
        }
        __syncthreads();

        short8 af[4][2], bf[4][2];
#pragma unroll
        for (int i = 0; i < 4; i++) {
            af[i][0] = *(const short8*)&As[0][wm + i * 16 + lm][lq * 8];
            af[i][1] = *(const short8*)&As[1][wm + i * 16 + lm][lq * 8];
        }
#pragma unroll
        for (int j = 0; j < 4; j++) {
            bf[j][0] = *(const short8*)&Bs[0][wn + j * 16 + lm][lq * 8];
            bf[j][1] = *(const short8*)&Bs[1][wn + j * 16 + lm][lq * 8];
        }
#pragma unroll
        for (int i = 0; i < 4; i++)
#pragma unroll
            for (int j = 0; j < 4; j++) {
                acc[i][j] = __builtin_amdgcn_mfma_f32_16x16x32_bf16(
                    af[i][0], bf[j][0], acc[i][j], 0, 0, 0);
                acc[i][j] = __builtin_amdgcn_mfma_f32_16x16x32_bf16(
                    af[i][0], bf[j][1], acc[i][j], 0, 0, 0);
                acc[i][j] = __builtin_amdgcn_mfma_f32_16x16x32_bf16(
                    af[i][1], bf[j][0], acc[i][j], 0, 0, 0);
            }
    }
#pragma unroll
    for (int i = 0; i < 4; i++) {
        int gmb = m0 + wm + i * 16 + lq * 4;
#pragma unroll
        for (int j = 0; j < 4; j++) {
            int gn = n0 + wn + j * 16 + lm;
            if (gn >= N) continue;
#pragma unroll
            for (int r = 0; r < 4; r++) {
                int gm = gmb + r;
                if (gm < M) C[(long)gm * ldc + gn] = acc[i][j][r] * alpha;
            }
        }
    }
}

// ---------------- fused softmax*adj + renorm + bf16 split (in place) -------
// Reads SC row (fp32), writes W hi/lo bf16 into the same 2400B row.
// w_j = e_j*a_j / (S + 1e-8*E), e = exp(s-mx), E = sum e, S = sum e*a.
__global__ __launch_bounds__(256)
void softmax_split_k(float* __restrict__ sc, const float* __restrict__ adj)
{
    __shared__ float rowb[Mc];
    __shared__ float arow[Mc];
    __shared__ float red[8];
    const long gr = blockIdx.x;
    const int m = (int)(gr % Mc);
    float* s = sc + gr * Mc;
    const float* a = adj + (long)m * Mc;
    const int t = threadIdx.x;

    for (int j = t; j < Mc; j += 256) { rowb[j] = s[j]; arow[j] = a[j]; }
    __syncthreads();

    float mx = -1e30f;
    for (int j = t; j < Mc; j += 256) mx = fmaxf(mx, rowb[j]);
    mx = wave_max(mx);
    if ((t & 63) == 0) red[t >> 6] = mx;
    __syncthreads();
    mx = fmaxf(fmaxf(red[0], red[1]), fmaxf(red[2], red[3]));
    __syncthreads();

    float esum = 0.f, ssum = 0.f;
    for (int j = t; j < Mc; j += 256) {
        float e = __expf(rowb[j] - mx);
        float ea = e * arow[j];
        rowb[j] = ea;
        esum += e; ssum += ea;
    }
    esum = wave_sum(esum); ssum = wave_sum(ssum);
    if ((t & 63) == 0) { red[t >> 6] = esum; red[4 + (t >> 6)] = ssum; }
    __syncthreads();
    float E = red[0] + red[1] + red[2] + red[3];
    float S = red[4] + red[5] + red[6] + red[7];
    float inv = 1.f / (S + 1e-8f * E);

    __hip_bfloat16* hi = reinterpret_cast<__hip_bfloat16*>(s);
    __hip_bfloat16* lo = hi + Mc;
    for (int j = t; j < Mc; j += 256) {
        float wv = rowb[j] * inv;
        __hip_bfloat16 h = __float2bfloat16(wv);
        __hip_bfloat16 l = __float2bfloat16(wv - __bfloat162float(h));
        hi[j] = h; lo[j] = l;
    }
}

// ---------------- running max of middle-window slice [2N:3N] ---------------
__global__ __launch_bounds__(256)
void cand_update_k(const float* __restrict__ cur, float* __restrict__ cand,
                   int bw0, long total, int first)
{
    long idx = (long)blockIdx.x * 256 + threadIdx.x;
    if (idx >= total) return;
    int c = (int)(idx & 63);
    long r = idx >> 6;
    int n = (int)(r % Nc);
    int i = (int)(r / Nc);
    long bw = bw0 + i;
    float v = cur[((bw * Mc) + 2 * Nc + n) * Cc + c];
    long o = ((bw * Nc) + n) * Cc + c;
    cand[o] = first ? v : fmaxf(cand[o], v);
}

// ---------------- output layer ----------------
__global__ __launch_bounds__(128)
void output_k(const float* __restrict__ h2, const float* __restrict__ Wo,
              const float* __restrict__ bo, float* __restrict__ out)
{
    __shared__ float ds[512];
    int row = blockIdx.x;
    int b = row / Nc, n = row % Nc;
    int t = threadIdx.x;
    for (int e = t; e < 512; e += 128) {
        int tt = e >> 6, c = e & 63;
        ds[e] = h2[(((long)b * 8 + tt) * Nc + n) * Cc + c];
    }
    __syncthreads();
    float acc = bo[t];
    for (int e = 0; e < 512; e++) acc += ds[e] * Wo[e * OUTFc + t];
    acc = fmaxf(acc, 0.f);
    for (int p = 0; p < PREDc; p++)
        out[(((long)b * PREDc + p) * Nc + n) * (long)OUTFc + t] = acc;
}

extern "C" void kernel_launch(void* const* d_in, const int* in_sizes, int n_in,
                              void* d_out, int out_size, void* d_ws, size_t ws_size,
                              hipStream_t stream)
{
    (void)in_sizes; (void)n_in; (void)out_size; (void)ws_size;
    const float* x     = (const float*)d_in[0];
    const float* Wqkv  = (const float*)d_in[4];
    const float* bqkv  = (const float*)d_in[5];
    const float* Wlin  = (const float*)d_in[6];
    const float* blin  = (const float*)d_in[7];
    const float* Wa    = (const float*)d_in[8];
    const float* Wb    = (const float*)d_in[9];
    const float* temb0 = (const float*)d_in[13];
    const float* temb1 = (const float*)d_in[14];
    const float* semb  = (const float*)d_in[15];
    const float* Wo    = (const float*)d_in[16];
    const float* bo    = (const float*)d_in[17];
    float* out = (float*)d_out;

    // ---- workspace (float offsets). total ~26.1M floats = 104.4 MB ----
    float* ws   = (float*)d_ws;
    float* CUR  = ws;                                  // 40*600*64 = 1,536,000
    float* SC   = CUR + (long)MAXBW * Mc * Cc;         // 40*600*600 = 14,400,000 (also W hi/lo bf16)
    float* QHf  = SC  + (long)MAXBW * Mc * Mc;         // each split buf: 1,536,000 fl (3.072M bf16)
    const long SPLIT = (long)MAXBW * Mc * ATTc / 2;    // in floats
    float* QLf  = QHf + SPLIT;
    float* KHf  = QLf + SPLIT;
    float* KLf  = KHf + SPLIT;
    float* VTHf = KLf + SPLIT;
    float* VTLf = VTHf + SPLIT;
    float* NA   = VTLf + SPLIT;
    float* NB   = NA + Mc * Cc;
    float* ADJ  = NB + Mc * Cc;
    float* CAND = ADJ + (long)Mc * Mc;
    float* ATTB = QHf;                                 // alias: QH+QL dead after scores

    __hip_bfloat16* QH  = (__hip_bfloat16*)QHf;
    __hip_bfloat16* QL  = (__hip_bfloat16*)QLf;
    __hip_bfloat16* KH  = (__hip_bfloat16*)KHf;
    __hip_bfloat16* KL  = (__hip_bfloat16*)KLf;
    __hip_bfloat16* VTH = (__hip_bfloat16*)VTHf;
    __hip_bfloat16* VTL = (__hip_bfloat16*)VTLf;

    const float inv_sqrt_att = 0.08838834764831845f;   // 1/sqrt(128)

    for (int layer = 0; layer < 2; layer++) {
        int Tin = layer ? 10 : 12;
        int nw  = Tin - 2;
        int BW  = Bc * nw;                             // 40 then 32
        int Mtot = BW * Mc;
        const float* src  = layer ? CAND : x;
        const float* temb = layer ? temb1 : temb0;

        long etotal = (long)BW * Mc * Cc;
        embed_window_k<<<dim3((unsigned)((etotal + 255) / 256)), dim3(256), 0, stream>>>(
            src, temb, semb, CUR, Tin, nw, etotal);

        for (int it = 0; it < 3; it++) {
            // adjacency: mean -> NA/NB -> sigmoid(NA NB^T / 8)
            mean_nab_k<<<dim3(10), dim3(256), 0, stream>>>(CUR, Wa, Wb, NA, NB, BW);
            gemm_k<true, false, 1><<<dim3(10, 10, 1), dim3(256), 0, stream>>>(
                NA, NB, nullptr, ADJ, Mc, Mc, Cc, Cc, Cc, Mc, 0, 0, 0, 0.125f);

            // QKV projection + hi/lo bf16 split (V relu'd + transposed)
            qkv_split_k<<<dim3(3, (Mtot + 127) / 128), dim3(256), 0, stream>>>(
                CUR, Wqkv, bqkv, QH, QL, KH, KL, VTH, VTL, Mtot);

            // scores = Q K^T / sqrt(ATT)  (split-bf16 MFMA)
            mfma_bt_k<<<dim3(5, 5, BW), dim3(256), 0, stream>>>(
                (const ushort*)QH, (const ushort*)QL, (const ushort*)KH, (const ushort*)KL,
                SC, Mc, Mc, ATTc, ATTc, ATTc, Mc,
                (long)Mc * ATTc, (long)Mc * ATTc, (long)Mc * Mc, inv_sqrt_att);

            // softmax * adj, renorm, write W hi/lo bf16 in place
            softmax_split_k<<<dim3(Mtot), dim3(256), 0, stream>>>(SC, ADJ);

            // att = W @ relu(V)  (split-bf16 MFMA, B = V^T)
            mfma_bt_k<<<dim3(1, 5, BW), dim3(256), 0, stream>>>(
                (const ushort*)SC, (const ushort*)SC + Mc,
                (const ushort*)VTH, (const ushort*)VTL,
                ATTB, Mc, ATTc, Mc, 2 * Mc, Mc, ATTc,
                (long)2 * Mc * Mc, (long)ATTc * Mc, (long)Mc * ATTc, 1.f);

            // cur_next = att @ Wlin + blin
            gemm_k<false, false, 0><<<dim3(1, (Mtot + 63) / 64, 1), dim3(256), 0, stream>>>(
                ATTB, Wlin, blin, CUR, Mtot, Cc, ATTc, ATTc, Cc, Cc, 0, 0, 0, 1.f);

            // running max of middle window
            long ctotal = (long)BW * Nc * Cc;
            cand_update_k<<<dim3((unsigned)((ctotal + 255) / 256)), dim3(256), 0, stream>>>(
                CUR, CAND, 0, ctotal, it == 0 ? 1 : 0);
        }
    }
    output_k<<<dim3(Bc * Nc), dim3(128), 0, stream>>>(CAND, Wo, bo, out);
}

// Round 6
// 1573.450 us; speedup vs baseline: 3.6622x; 1.0375x over previous
//
#include <hip/hip_runtime.h>
#include <hip/hip_bf16.h>
#include <math.h>

constexpr int Bc   = 4;
constexpr int Nc   = 200;
constexpr int Cc   = 64;
constexpr int Mc   = 600;    // 3*N
constexpr int ATTc = 128;
constexpr int OUTFc = 128;
constexpr int PREDc = 12;
constexpr int MAXBW = 40;
constexpr int MPAD  = 640;   // padded key/row count per window

typedef short short8 __attribute__((ext_vector_type(8)));
typedef float f32x4  __attribute__((ext_vector_type(4)));

static __device__ __forceinline__ float wave_sum(float v) {
#pragma unroll
    for (int o = 32; o > 0; o >>= 1) v += __shfl_down(v, o, 64);
    return v;
}
static __device__ __forceinline__ float wave_max(float v) {
#pragma unroll
    for (int o = 32; o > 0; o >>= 1) v = fmaxf(v, __shfl_down(v, o, 64));
    return v;
}
static __device__ __forceinline__ void bsplit(float v, short& h, short& l) {
    __hip_bfloat16 hb = __float2bfloat16(v);
    float hf = __bfloat162float(hb);
    __hip_bfloat16 lb = __float2bfloat16(v - hf);
    h = *(short*)&hb; l = *(short*)&lb;
}

// ---------------- embed + sliding window ----------------
__global__ __launch_bounds__(256)
void embed_window_k(const float* __restrict__ src, const float* __restrict__ temb,
                    const float* __restrict__ semb, float* __restrict__ dst,
                    int Tin, int nw, long total)
{
    long idx = (long)blockIdx.x * 256 + threadIdx.x;
    if (idx >= total) return;
    int c = (int)(idx & 63);
    long r = idx >> 6;
    int n = (int)(r % Nc); r /= Nc;
    int j = (int)(r % 3);  r /= 3;
    int w = (int)(r % nw);
    int b = (int)(r / nw);
    int t = w + j;
    dst[idx] = src[(((long)b * Tin + t) * Nc + n) * Cc + c]
             + temb[t * Cc + c] + semb[n * Cc + c];
}

// ---------------- fused node-mean + NA/NB projection (16-row blocks) -------
__global__ __launch_bounds__(256)
void mean_nab_k(const float* __restrict__ cur, const float* __restrict__ Wa,
                const float* __restrict__ Wb, float* __restrict__ NA,
                float* __restrict__ NB, int BW)
{
    __shared__ float Ns[64][17];   // [k][row]
    __shared__ float Ws[64][132];  // [k][ Wa | Wb ]
    const int m0 = blockIdx.x * 16;
    const int t = threadIdx.x;
    for (int e = t; e < 1024; e += 256) {
        int r = e >> 4, c4 = (e & 15) << 2;
        *(float4*)&Ws[r][c4]      = *(const float4*)&Wa[r * 64 + c4];
        *(float4*)&Ws[r][64 + c4] = *(const float4*)&Wb[r * 64 + c4];
    }
    {
        int row = t >> 4, c4 = (t & 15) << 2;
        int gm = m0 + row;
        float4 sv = make_float4(0.f, 0.f, 0.f, 0.f);
        if (gm < Mc) {
            for (int bw = 0; bw < BW; bw++) {
                const float4 v = *(const float4*)&cur[((long)bw * Mc + gm) * Cc + c4];
                sv.x += v.x; sv.y += v.y; sv.z += v.z; sv.w += v.w;
            }
        }
        const float inv = 1.f / BW;
        Ns[c4 + 0][row] = sv.x * inv; Ns[c4 + 1][row] = sv.y * inv;
        Ns[c4 + 2][row] = sv.z * inv; Ns[c4 + 3][row] = sv.w * inv;
    }
    __syncthreads();
    const int row = t >> 4, c8 = (t & 15) * 8;
    float acc[8] = {};
    for (int k = 0; k < 64; k++) {
        float a = Ns[k][row];
        float b[8];
        *(float4*)&b[0] = *(const float4*)&Ws[k][c8];
        *(float4*)&b[4] = *(const float4*)&Ws[k][c8 + 4];
#pragma unroll
        for (int j = 0; j < 8; j++) acc[j] += a * b[j];
    }
    int gm = m0 + row;
    if (gm < Mc) {
#pragma unroll
        for (int j = 0; j < 8; j++) {
            int col = c8 + j;
            if (col < 64) NA[gm * 64 + col] = acc[j];
            else          NB[gm * 64 + col - 64] = acc[j];
        }
    }
}

// ---------------- 64-tile fp32 GEMM (adj, Wlin) ----------------
template<bool BT, bool RELUB, int EPI>
__global__ __launch_bounds__(256)
void gemm_k(const float* __restrict__ A, const float* __restrict__ Bm,
            const float* __restrict__ bias, float* __restrict__ C,
            int M, int N, int K, int lda, int ldb, int ldc,
            long sA, long sB, long sC, float alpha)
{
    __shared__ float As[16][68];
    __shared__ float Bs[16][68];
    const int z = blockIdx.z;
    A  += (long)z * sA;
    Bm += (long)z * sB;
    C  += (long)z * sC;
    const int m0 = blockIdx.y * 64, n0 = blockIdx.x * 64;
    const int t = threadIdx.x;
    const int tx = t & 15, ty = t >> 4;
    float acc[4][4] = {};
    for (int k0 = 0; k0 < K; k0 += 16) {
        {
            int r = t >> 2, kb = (t & 3) << 2;
            int gm = m0 + r;
            const float* ap = A + (long)gm * lda + k0 + kb;
#pragma unroll
            for (int i = 0; i < 4; i++) {
                int gk = k0 + kb + i;
                As[kb + i][r] = (gm < M && gk < K) ? ap[i] : 0.f;
            }
        }
        if (!BT) {
            int nn = t & 63, kq = t >> 6;
#pragma unroll
            for (int i = 0; i < 4; i++) {
                int kk = kq * 4 + i;
                int gk = k0 + kk, gn = n0 + nn;
                float v = (gk < K && gn < N) ? Bm[(long)gk * ldb + gn] : 0.f;
                if (RELUB) v = fmaxf(v, 0.f);
                Bs[kk][nn] = v;
            }
        } else {
            int nn = t >> 2, kb = (t & 3) << 2;
            int gn = n0 + nn;
            const float* bp = Bm + (long)gn * ldb + k0 + kb;
#pragma unroll
            for (int i = 0; i < 4; i++) {
                int gk = k0 + kb + i;
                float v = (gn < N && gk < K) ? bp[i] : 0.f;
                if (RELUB) v = fmaxf(v, 0.f);
                Bs[kb + i][nn] = v;
            }
        }
        __syncthreads();
#pragma unroll
        for (int kk = 0; kk < 16; kk++) {
            const float4 a4 = *(const float4*)&As[kk][ty * 4];
            const float4 b4 = *(const float4*)&Bs[kk][tx * 4];
            const float a[4] = {a4.x, a4.y, a4.z, a4.w};
            const float b[4] = {b4.x, b4.y, b4.z, b4.w};
#pragma unroll
            for (int i = 0; i < 4; i++)
#pragma unroll
                for (int j = 0; j < 4; j++) acc[i][j] += a[i] * b[j];
        }
        __syncthreads();
    }
#pragma unroll
    for (int i = 0; i < 4; i++) {
        int gm = m0 + ty * 4 + i;
        if (gm >= M) continue;
#pragma unroll
        for (int j = 0; j < 4; j++) {
            int gn = n0 + tx * 4 + j;
            if (gn >= N) continue;
            float v = acc[i][j] * alpha;
            if (bias) v += bias[gn];
            if (EPI == 1) v = 1.f / (1.f + __expf(-v));
            if (EPI == 2) v = fmaxf(v, 0.f);
            C[(long)gm * ldc + gn] = v;
        }
    }
}

// ---------------- QKV GEMM -> packed hi/lo bf16 layouts ----------------
// Q/K: [z][row<640][128 hi | 128 lo] ushort. V: relu, transposed:
// [z][att col][640 hi | 640 lo]. Grid (3, 5, BW), M=600 rows per z.
__global__ __launch_bounds__(256)
void qkv_split_k(const float* __restrict__ CURp, const float* __restrict__ Wqkv,
                 const float* __restrict__ bias,
                 ushort* __restrict__ Qb, ushort* __restrict__ Kb,
                 ushort* __restrict__ Vb)
{
    __shared__ float As[16][132];
    __shared__ float Bs[16][132];
    const int which = blockIdx.x;          // 0=q 1=k 2=v
    const int m0 = blockIdx.y * 128;
    const int z  = blockIdx.z;
    const float* A = CURp + (long)z * Mc * Cc;
    const int n0 = which * 128;
    const int t = threadIdx.x;
    const int tx = t & 15, ty = t >> 4;
    float acc[8][8] = {};

    for (int k0 = 0; k0 < 64; k0 += 16) {
#pragma unroll
        for (int pass = 0; pass < 2; pass++) {
            int e = t + pass * 256;
            int r = e >> 2, kb = (e & 3) << 2;
            int gm = m0 + r;
            float4 v = make_float4(0.f, 0.f, 0.f, 0.f);
            if (gm < Mc) v = *(const float4*)(A + (long)gm * 64 + k0 + kb);
            As[kb + 0][r] = v.x; As[kb + 1][r] = v.y;
            As[kb + 2][r] = v.z; As[kb + 3][r] = v.w;
        }
#pragma unroll
        for (int pass = 0; pass < 2; pass++) {
            int e = t + pass * 256;
            int kk = e >> 5, n4 = (e & 31) << 2;
            float4 v = *(const float4*)(Wqkv + (long)(k0 + kk) * 384 + n0 + n4);
            *(float4*)&Bs[kk][n4] = v;
        }
        __syncthreads();
#pragma unroll
        for (int kk = 0; kk < 16; kk++) {
            float a[8], b[8];
            *(float4*)&a[0] = *(const float4*)&As[kk][ty * 8];
            *(float4*)&a[4] = *(const float4*)&As[kk][ty * 8 + 4];
            *(float4*)&b[0] = *(const float4*)&Bs[kk][tx * 8];
            *(float4*)&b[4] = *(const float4*)&Bs[kk][tx * 8 + 4];
#pragma unroll
            for (int i = 0; i < 8; i++)
#pragma unroll
                for (int j = 0; j < 8; j++) acc[i][j] += a[i] * b[j];
        }
        __syncthreads();
    }

    if (which == 2) {
        // key group m0+ty*8..+7 is all-valid or all-invalid (600 % 8 == 0)
        if (m0 + ty * 8 < Mc) {
            ushort* vz = Vb + (long)z * ATTc * (2 * MPAD);
#pragma unroll
            for (int j = 0; j < 8; j++) {
                int col = tx * 8 + j;
                short8 h8, l8;
#pragma unroll
                for (int i = 0; i < 8; i++) {
                    float v = fmaxf(acc[i][j] + bias[n0 + col], 0.f);
                    short hs, ls;
                    bsplit(v, hs, ls);
                    h8[i] = hs; l8[i] = ls;
                }
                *(short8*)(vz + (long)col * (2 * MPAD) + m0 + ty * 8) = h8;
                *(short8*)(vz + (long)col * (2 * MPAD) + MPAD + m0 + ty * 8) = l8;
            }
        }
    } else {
        ushort* dst = (which == 0 ? Qb : Kb) + (long)z * MPAD * 256;
#pragma unroll
        for (int i = 0; i < 8; i++) {
            int row = m0 + ty * 8 + i;
            if (row >= Mc) continue;
            short8 h8, l8;
#pragma unroll
            for (int j = 0; j < 8; j++) {
                float v = acc[i][j] + bias[n0 + tx * 8 + j];
                short hs, ls;
                bsplit(v, hs, ls);
                h8[j] = hs; l8[j] = ls;
            }
            *(short8*)(dst + (long)row * 256 + tx * 8) = h8;
            *(short8*)(dst + (long)row * 256 + 128 + tx * 8) = l8;
        }
    }
}

// ---------------- fused flash attention: S -> softmax*adj -> renorm -> PV --
// Grid (10 qtiles, BW). 4 waves x 16 Q rows. Split-bf16 MFMA, frags direct
// from global; P round-trips per-wave-private LDS. O = num/(S + 1e-8 E).
__global__ __launch_bounds__(256)
void flash_k(const ushort* __restrict__ Qb, const ushort* __restrict__ Kb,
             const ushort* __restrict__ Vb, const float* __restrict__ adj,
             float* __restrict__ O, float scale)
{
    __shared__ __align__(16) short PH[4][16][136];
    __shared__ __align__(16) short PL[4][16][136];
    const int z = blockIdx.y;
    const int m0 = blockIdx.x * 64;
    const int t = threadIdx.x;
    const int lane = t & 63, w = t >> 6;
    const int lm = lane & 15, lq = lane >> 4;
    const int qrow0 = m0 + w * 16;

    const ushort* Qz = Qb + (long)z * MPAD * 256;
    const ushort* Kz = Kb + (long)z * MPAD * 256;
    const ushort* Vz = Vb + (long)z * ATTc * (2 * MPAD);

    short8 qh[4], ql[4];
    {
        const ushort* qp = Qz + (long)(qrow0 + lm) * 256;
#pragma unroll
        for (int ks = 0; ks < 4; ks++) {
            qh[ks] = *(const short8*)(qp + ks * 32 + lq * 8);
            ql[ks] = *(const short8*)(qp + 128 + ks * 32 + lq * 8);
        }
    }

    f32x4 oacc[8];
#pragma unroll
    for (int at = 0; at < 8; at++)
#pragma unroll
        for (int r = 0; r < 4; r++) oacc[at][r] = 0.f;
    float mx[4] = {-3e38f, -3e38f, -3e38f, -3e38f};
    float E[4] = {}, S[4] = {};

    for (int kc = 0; kc < Mc; kc += 128) {
        // ---- S = Q K^T (split bf16) ----
        f32x4 sacc[8];
#pragma unroll
        for (int nt = 0; nt < 8; nt++)
#pragma unroll
            for (int r = 0; r < 4; r++) sacc[nt][r] = 0.f;
#pragma unroll
        for (int nt = 0; nt < 8; nt++) {
            const ushort* kp = Kz + (long)(kc + nt * 16 + lm) * 256;
            short8 kh[4], kl[4];
#pragma unroll
            for (int ks = 0; ks < 4; ks++) {
                kh[ks] = *(const short8*)(kp + ks * 32 + lq * 8);
                kl[ks] = *(const short8*)(kp + 128 + ks * 32 + lq * 8);
            }
#pragma unroll
            for (int ks = 0; ks < 4; ks++) {
                sacc[nt] = __builtin_amdgcn_mfma_f32_16x16x32_bf16(qh[ks], kh[ks], sacc[nt], 0, 0, 0);
                sacc[nt] = __builtin_amdgcn_mfma_f32_16x16x32_bf16(qh[ks], kl[ks], sacc[nt], 0, 0, 0);
                sacc[nt] = __builtin_amdgcn_mfma_f32_16x16x32_bf16(ql[ks], kh[ks], sacc[nt], 0, 0, 0);
            }
        }
        // ---- row stats (per quad: rows lq*4+r), 16-lane butterfly ----
        const int keyb = kc + lm;
        float tmax[4] = {-3e38f, -3e38f, -3e38f, -3e38f};
#pragma unroll
        for (int nt = 0; nt < 8; nt++) {
            bool valid = (keyb + nt * 16) < Mc;
#pragma unroll
            for (int r = 0; r < 4; r++) {
                float s = sacc[nt][r] * scale;
                sacc[nt][r] = s;
                if (valid) tmax[r] = fmaxf(tmax[r], s);
            }
        }
#pragma unroll
        for (int mk = 1; mk <= 8; mk <<= 1)
#pragma unroll
            for (int r = 0; r < 4; r++)
                tmax[r] = fmaxf(tmax[r], __shfl_xor(tmax[r], mk, 64));
        float al[4];
#pragma unroll
        for (int r = 0; r < 4; r++) {
            float nm = fmaxf(mx[r], tmax[r]);
            al[r] = __expf(mx[r] - nm);
            mx[r] = nm;
        }
        float tE[4] = {}, tS[4] = {};
#pragma unroll
        for (int nt = 0; nt < 8; nt++) {
            int key = keyb + nt * 16;
            bool valid = key < Mc;
#pragma unroll
            for (int r = 0; r < 4; r++) {
                float e = valid ? __expf(sacc[nt][r] - mx[r]) : 0.f;
                float a = valid ? adj[(long)(qrow0 + lq * 4 + r) * Mc + key] : 0.f;
                float ea = e * a;
                sacc[nt][r] = ea;
                tE[r] += e; tS[r] += ea;
            }
        }
#pragma unroll
        for (int mk = 1; mk <= 8; mk <<= 1)
#pragma unroll
            for (int r = 0; r < 4; r++) {
                tE[r] += __shfl_xor(tE[r], mk, 64);
                tS[r] += __shfl_xor(tS[r], mk, 64);
            }
#pragma unroll
        for (int r = 0; r < 4; r++) {
            E[r] = E[r] * al[r] + tE[r];
            S[r] = S[r] * al[r] + tS[r];
        }
#pragma unroll
        for (int at = 0; at < 8; at++)
#pragma unroll
            for (int r = 0; r < 4; r++) oacc[at][r] *= al[r];
        // ---- P -> LDS (hi/lo bf16), wave-private ----
#pragma unroll
        for (int nt = 0; nt < 8; nt++)
#pragma unroll
            for (int r = 0; r < 4; r++) {
                short h, l;
                bsplit(sacc[nt][r], h, l);
                PH[w][lq * 4 + r][nt * 16 + lm] = h;
                PL[w][lq * 4 + r][nt * 16 + lm] = l;
            }
        // ---- O += P V (split bf16) ----
        short8 ph[4], pl[4];
#pragma unroll
        for (int ks = 0; ks < 4; ks++) {
            ph[ks] = *(const short8*)&PH[w][lm][ks * 32 + lq * 8];
            pl[ks] = *(const short8*)&PL[w][lm][ks * 32 + lq * 8];
        }
#pragma unroll
        for (int at = 0; at < 8; at++) {
            const ushort* vp = Vz + (long)(at * 16 + lm) * (2 * MPAD) + kc;
            short8 vh[4], vl[4];
#pragma unroll
            for (int ks = 0; ks < 4; ks++) {
                vh[ks] = *(const short8*)(vp + ks * 32 + lq * 8);
                vl[ks] = *(const short8*)(vp + MPAD + ks * 32 + lq * 8);
            }
#pragma unroll
            for (int ks = 0; ks < 4; ks++) {
                oacc[at] = __builtin_amdgcn_mfma_f32_16x16x32_bf16(ph[ks], vh[ks], oacc[at], 0, 0, 0);
                oacc[at] = __builtin_amdgcn_mfma_f32_16x16x32_bf16(ph[ks], vl[ks], oacc[at], 0, 0, 0);
                oacc[at] = __builtin_amdgcn_mfma_f32_16x16x32_bf16(pl[ks], vh[ks], oacc[at], 0, 0, 0);
            }
        }
    }
    // ---- epilogue: O = num / (S + 1e-8 E) ----
    float inv[4];
#pragma unroll
    for (int r = 0; r < 4; r++) inv[r] = 1.f / (S[r] + 1e-8f * E[r]);
#pragma unroll
    for (int at = 0; at < 8; at++)
#pragma unroll
        for (int r = 0; r < 4; r++) {
            int row = qrow0 + lq * 4 + r;
            if (row < Mc)
                O[((long)z * Mc + row) * ATTc + at * 16 + lm] = oacc[at][r] * inv[r];
        }
}

// ---------------- running max of middle-window slice [2N:3N] ---------------
__global__ __launch_bounds__(256)
void cand_update_k(const float* __restrict__ cur, float* __restrict__ cand,
                   int bw0, long total, int first)
{
    long idx = (long)blockIdx.x * 256 + threadIdx.x;
    if (idx >= total) return;
    int c = (int)(idx & 63);
    long r = idx >> 6;
    int n = (int)(r % Nc);
    int i = (int)(r / Nc);
    long bw = bw0 + i;
    float v = cur[((bw * Mc) + 2 * Nc + n) * Cc + c];
    long o = ((bw * Nc) + n) * Cc + c;
    cand[o] = first ? v : fmaxf(cand[o], v);
}

// ---------------- output layer ----------------
__global__ __launch_bounds__(128)
void output_k(const float* __restrict__ h2, const float* __restrict__ Wo,
              const float* __restrict__ bo, float* __restrict__ out)
{
    __shared__ float ds[512];
    int row = blockIdx.x;
    int b = row / Nc, n = row % Nc;
    int t = threadIdx.x;
    for (int e = t; e < 512; e += 128) {
        int tt = e >> 6, c = e & 63;
        ds[e] = h2[(((long)b * 8 + tt) * Nc + n) * Cc + c];
    }
    __syncthreads();
    float acc = bo[t];
    for (int e = 0; e < 512; e++) acc += ds[e] * Wo[e * OUTFc + t];
    acc = fmaxf(acc, 0.f);
    for (int p = 0; p < PREDc; p++)
        out[(((long)b * PREDc + p) * Nc + n) * (long)OUTFc + t] = acc;
}

extern "C" void kernel_launch(void* const* d_in, const int* in_sizes, int n_in,
                              void* d_out, int out_size, void* d_ws, size_t ws_size,
                              hipStream_t stream)
{
    (void)in_sizes; (void)n_in; (void)out_size; (void)ws_size;
    const float* x     = (const float*)d_in[0];
    const float* Wqkv  = (const float*)d_in[4];
    const float* bqkv  = (const float*)d_in[5];
    const float* Wlin  = (const float*)d_in[6];
    const float* blin  = (const float*)d_in[7];
    const float* Wa    = (const float*)d_in[8];
    const float* Wb    = (const float*)d_in[9];
    const float* temb0 = (const float*)d_in[13];
    const float* temb1 = (const float*)d_in[14];
    const float* semb  = (const float*)d_in[15];
    const float* Wo    = (const float*)d_in[16];
    const float* bo    = (const float*)d_in[17];
    float* out = (float*)d_out;

    // ---- workspace (~61.5 MB) ----
    float* ws   = (float*)d_ws;
    float* CUR  = ws;                                        // 1,536,000 fl
    float* ATTB = CUR + (long)MAXBW * Mc * Cc;               // 3,072,000 fl
    float* NA   = ATTB + (long)MAXBW * Mc * ATTc;            // 38,400
    float* NB   = NA + Mc * Cc;
    float* ADJ  = NB + Mc * Cc;                              // 360,000
    float* CAND = ADJ + (long)Mc * Mc;                       // 512,000
    ushort* Qb  = (ushort*)(CAND + (long)MAXBW * Nc * Cc);   // 40*640*256 us
    ushort* Kb  = Qb + (long)MAXBW * MPAD * 256;
    ushort* Vb  = Kb + (long)MAXBW * MPAD * 256;             // 40*128*1280 us

    const float inv_sqrt_att = 0.08838834764831845f;         // 1/sqrt(128)

    for (int layer = 0; layer < 2; layer++) {
        int Tin = layer ? 10 : 12;
        int nw  = Tin - 2;
        int BW  = Bc * nw;                                   // 40 then 32
        int Mtot = BW * Mc;
        const float* src  = layer ? CAND : x;
        const float* temb = layer ? temb1 : temb0;

        long etotal = (long)BW * Mc * Cc;
        embed_window_k<<<dim3((unsigned)((etotal + 255) / 256)), dim3(256), 0, stream>>>(
            src, temb, semb, CUR, Tin, nw, etotal);

        for (int it = 0; it < 3; it++) {
            // adjacency: mean -> NA/NB -> sigmoid(NA NB^T / 8)
            mean_nab_k<<<dim3(38), dim3(256), 0, stream>>>(CUR, Wa, Wb, NA, NB, BW);
            gemm_k<true, false, 1><<<dim3(10, 10, 1), dim3(256), 0, stream>>>(
                NA, NB, nullptr, ADJ, Mc, Mc, Cc, Cc, Cc, Mc, 0, 0, 0, 0.125f);

            // QKV projection + packed hi/lo split (V relu'd + transposed)
            qkv_split_k<<<dim3(3, 5, BW), dim3(256), 0, stream>>>(
                CUR, Wqkv, bqkv, Qb, Kb, Vb);

            // fused attention: scores -> softmax*adj -> renorm -> PV
            flash_k<<<dim3(10, BW), dim3(256), 0, stream>>>(
                Qb, Kb, Vb, ADJ, ATTB, inv_sqrt_att);

            // cur_next = att @ Wlin + blin
            gemm_k<false, false, 0><<<dim3(1, (Mtot + 63) / 64, 1), dim3(256), 0, stream>>>(
                ATTB, Wlin, blin, CUR, Mtot, Cc, ATTc, ATTc, Cc, Cc, 0, 0, 0, 1.f);

            // running max of middle window
            long ctotal = (long)BW * Nc * Cc;
            cand_update_k<<<dim3((unsigned)((ctotal + 255) / 256)), dim3(256), 0, stream>>>(
                CUR, CAND, 0, ctotal, it == 0 ? 1 : 0);
        }
    }
    output_k<<<dim3(Bc * Nc), dim3(128), 0, stream>>>(CAND, Wo, bo, out);
}

// Round 7
// 1418.101 us; speedup vs baseline: 4.0634x; 1.1095x over previous
//
#include <hip/hip_runtime.h>
#include <hip/hip_bf16.h>
#include <math.h>

constexpr int Bc   = 4;
constexpr int Nc   = 200;
constexpr int Cc   = 64;
constexpr int Mc   = 600;    // 3*N
constexpr int ATTc = 128;
constexpr int OUTFc = 128;
constexpr int PREDc = 12;
constexpr int MAXBW = 40;
constexpr int MPAD  = 640;   // padded key/row count per window

typedef short short8 __attribute__((ext_vector_type(8)));
typedef float f32x4  __attribute__((ext_vector_type(4)));

static __device__ __forceinline__ void bsplit(float v, short& h, short& l) {
    __hip_bfloat16 hb = __float2bfloat16(v);
    float hf = __bfloat162float(hb);
    __hip_bfloat16 lb = __float2bfloat16(v - hf);
    h = *(short*)&hb; l = *(short*)&lb;
}

// ---------------- embed + sliding window ----------------
__global__ __launch_bounds__(256)
void embed_window_k(const float* __restrict__ src, const float* __restrict__ temb,
                    const float* __restrict__ semb, float* __restrict__ dst,
                    int Tin, int nw, long total)
{
    long idx = (long)blockIdx.x * 256 + threadIdx.x;
    if (idx >= total) return;
    int c = (int)(idx & 63);
    long r = idx >> 6;
    int n = (int)(r % Nc); r /= Nc;
    int j = (int)(r % 3);  r /= 3;
    int w = (int)(r % nw);
    int b = (int)(r / nw);
    int t = w + j;
    dst[idx] = src[(((long)b * Tin + t) * Nc + n) * Cc + c]
             + temb[t * Cc + c] + semb[n * Cc + c];
}

// ---------------- fused node-mean + NA/NB projection (16-row blocks) -------
__global__ __launch_bounds__(256)
void mean_nab_k(const float* __restrict__ cur, const float* __restrict__ Wa,
                const float* __restrict__ Wb, float* __restrict__ NA,
                float* __restrict__ NB, int BW)
{
    __shared__ float Ns[64][17];   // [k][row]
    __shared__ float Ws[64][132];  // [k][ Wa | Wb ]
    const int m0 = blockIdx.x * 16;
    const int t = threadIdx.x;
    for (int e = t; e < 1024; e += 256) {
        int r = e >> 4, c4 = (e & 15) << 2;
        *(float4*)&Ws[r][c4]      = *(const float4*)&Wa[r * 64 + c4];
        *(float4*)&Ws[r][64 + c4] = *(const float4*)&Wb[r * 64 + c4];
    }
    {
        int row = t >> 4, c4 = (t & 15) << 2;
        int gm = m0 + row;
        float4 sv = make_float4(0.f, 0.f, 0.f, 0.f);
        if (gm < Mc) {
            for (int bw = 0; bw < BW; bw++) {
                const float4 v = *(const float4*)&cur[((long)bw * Mc + gm) * Cc + c4];
                sv.x += v.x; sv.y += v.y; sv.z += v.z; sv.w += v.w;
            }
        }
        const float inv = 1.f / BW;
        Ns[c4 + 0][row] = sv.x * inv; Ns[c4 + 1][row] = sv.y * inv;
        Ns[c4 + 2][row] = sv.z * inv; Ns[c4 + 3][row] = sv.w * inv;
    }
    __syncthreads();
    const int row = t >> 4, c8 = (t & 15) * 8;
    float acc[8] = {};
    for (int k = 0; k < 64; k++) {
        float a = Ns[k][row];
        float b[8];
        *(float4*)&b[0] = *(const float4*)&Ws[k][c8];
        *(float4*)&b[4] = *(const float4*)&Ws[k][c8 + 4];
#pragma unroll
        for (int j = 0; j < 8; j++) acc[j] += a * b[j];
    }
    int gm = m0 + row;
    if (gm < Mc) {
#pragma unroll
        for (int j = 0; j < 8; j++) {
            int col = c8 + j;
            if (col < 64) NA[gm * 64 + col] = acc[j];
            else          NB[gm * 64 + col - 64] = acc[j];
        }
    }
}

// ---------------- 64-tile fp32 GEMM (adj, Wlin) ----------------
template<bool BT, bool RELUB, int EPI>
__global__ __launch_bounds__(256)
void gemm_k(const float* __restrict__ A, const float* __restrict__ Bm,
            const float* __restrict__ bias, float* __restrict__ C,
            int M, int N, int K, int lda, int ldb, int ldc,
            long sA, long sB, long sC, float alpha)
{
    __shared__ float As[16][68];
    __shared__ float Bs[16][68];
    const int z = blockIdx.z;
    A  += (long)z * sA;
    Bm += (long)z * sB;
    C  += (long)z * sC;
    const int m0 = blockIdx.y * 64, n0 = blockIdx.x * 64;
    const int t = threadIdx.x;
    const int tx = t & 15, ty = t >> 4;
    float acc[4][4] = {};
    for (int k0 = 0; k0 < K; k0 += 16) {
        {
            int r = t >> 2, kb = (t & 3) << 2;
            int gm = m0 + r;
            const float* ap = A + (long)gm * lda + k0 + kb;
#pragma unroll
            for (int i = 0; i < 4; i++) {
                int gk = k0 + kb + i;
                As[kb + i][r] = (gm < M && gk < K) ? ap[i] : 0.f;
            }
        }
        if (!BT) {
            int nn = t & 63, kq = t >> 6;
#pragma unroll
            for (int i = 0; i < 4; i++) {
                int kk = kq * 4 + i;
                int gk = k0 + kk, gn = n0 + nn;
                float v = (gk < K && gn < N) ? Bm[(long)gk * ldb + gn] : 0.f;
                if (RELUB) v = fmaxf(v, 0.f);
                Bs[kk][nn] = v;
            }
        } else {
            int nn = t >> 2, kb = (t & 3) << 2;
            int gn = n0 + nn;
            const float* bp = Bm + (long)gn * ldb + k0 + kb;
#pragma unroll
            for (int i = 0; i < 4; i++) {
                int gk = k0 + kb + i;
                float v = (gn < N && gk < K) ? bp[i] : 0.f;
                if (RELUB) v = fmaxf(v, 0.f);
                Bs[kb + i][nn] = v;
            }
        }
        __syncthreads();
#pragma unroll
        for (int kk = 0; kk < 16; kk++) {
            const float4 a4 = *(const float4*)&As[kk][ty * 4];
            const float4 b4 = *(const float4*)&Bs[kk][tx * 4];
            const float a[4] = {a4.x, a4.y, a4.z, a4.w};
            const float b[4] = {b4.x, b4.y, b4.z, b4.w};
#pragma unroll
            for (int i = 0; i < 4; i++)
#pragma unroll
                for (int j = 0; j < 4; j++) acc[i][j] += a[i] * b[j];
        }
        __syncthreads();
    }
#pragma unroll
    for (int i = 0; i < 4; i++) {
        int gm = m0 + ty * 4 + i;
        if (gm >= M) continue;
#pragma unroll
        for (int j = 0; j < 4; j++) {
            int gn = n0 + tx * 4 + j;
            if (gn >= N) continue;
            float v = acc[i][j] * alpha;
            if (bias) v += bias[gn];
            if (EPI == 1) v = 1.f / (1.f + __expf(-v));
            if (EPI == 2) v = fmaxf(v, 0.f);
            C[(long)gm * ldc + gn] = v;
        }
    }
}

// ---------------- QKV GEMM -> packed hi/lo bf16 layouts ----------------
__global__ __launch_bounds__(256)
void qkv_split_k(const float* __restrict__ CURp, const float* __restrict__ Wqkv,
                 const float* __restrict__ bias,
                 ushort* __restrict__ Qb, ushort* __restrict__ Kb,
                 ushort* __restrict__ Vb)
{
    __shared__ float As[16][132];
    __shared__ float Bs[16][132];
    const int which = blockIdx.x;          // 0=q 1=k 2=v
    const int m0 = blockIdx.y * 128;
    const int z  = blockIdx.z;
    const float* A = CURp + (long)z * Mc * Cc;
    const int n0 = which * 128;
    const int t = threadIdx.x;
    const int tx = t & 15, ty = t >> 4;
    float acc[8][8] = {};

    for (int k0 = 0; k0 < 64; k0 += 16) {
#pragma unroll
        for (int pass = 0; pass < 2; pass++) {
            int e = t + pass * 256;
            int r = e >> 2, kb = (e & 3) << 2;
            int gm = m0 + r;
            float4 v = make_float4(0.f, 0.f, 0.f, 0.f);
            if (gm < Mc) v = *(const float4*)(A + (long)gm * 64 + k0 + kb);
            As[kb + 0][r] = v.x; As[kb + 1][r] = v.y;
            As[kb + 2][r] = v.z; As[kb + 3][r] = v.w;
        }
#pragma unroll
        for (int pass = 0; pass < 2; pass++) {
            int e = t + pass * 256;
            int kk = e >> 5, n4 = (e & 31) << 2;
            float4 v = *(const float4*)(Wqkv + (long)(k0 + kk) * 384 + n0 + n4);
            *(float4*)&Bs[kk][n4] = v;
        }
        __syncthreads();
#pragma unroll
        for (int kk = 0; kk < 16; kk++) {
            float a[8], b[8];
            *(float4*)&a[0] = *(const float4*)&As[kk][ty * 8];
            *(float4*)&a[4] = *(const float4*)&As[kk][ty * 8 + 4];
            *(float4*)&b[0] = *(const float4*)&Bs[kk][tx * 8];
            *(float4*)&b[4] = *(const float4*)&Bs[kk][tx * 8 + 4];
#pragma unroll
            for (int i = 0; i < 8; i++)
#pragma unroll
                for (int j = 0; j < 8; j++) acc[i][j] += a[i] * b[j];
        }
        __syncthreads();
    }

    if (which == 2) {
        if (m0 + ty * 8 < Mc) {
            ushort* vz = Vb + (long)z * ATTc * (2 * MPAD);
#pragma unroll
            for (int j = 0; j < 8; j++) {
                int col = tx * 8 + j;
                short8 h8, l8;
#pragma unroll
                for (int i = 0; i < 8; i++) {
                    float v = fmaxf(acc[i][j] + bias[n0 + col], 0.f);
                    short hs, ls;
                    bsplit(v, hs, ls);
                    h8[i] = hs; l8[i] = ls;
                }
                *(short8*)(vz + (long)col * (2 * MPAD) + m0 + ty * 8) = h8;
                *(short8*)(vz + (long)col * (2 * MPAD) + MPAD + m0 + ty * 8) = l8;
            }
        }
    } else {
        ushort* dst = (which == 0 ? Qb : Kb) + (long)z * MPAD * 256;
#pragma unroll
        for (int i = 0; i < 8; i++) {
            int row = m0 + ty * 8 + i;
            if (row >= Mc) continue;
            short8 h8, l8;
#pragma unroll
            for (int j = 0; j < 8; j++) {
                float v = acc[i][j] + bias[n0 + tx * 8 + j];
                short hs, ls;
                bsplit(v, hs, ls);
                h8[j] = hs; l8[j] = ls;
            }
            *(short8*)(dst + (long)row * 256 + tx * 8) = h8;
            *(short8*)(dst + (long)row * 256 + 128 + tx * 8) = l8;
        }
    }
}

// -------- split-K flash: S -> softmax*adj partials -> partial PV -----------
// Grid (10 qtiles, BW, 2 splits). Split s covers keys [s*320, s*320+320),
// processed in 5 chunks of 64 keys. adj staged via LDS (coalesced prefetch
// overlapped with QK MFMAs). Writes partial numerator PN and (mx,E,S) to ST.
__global__ __launch_bounds__(256)
void flash2_k(const ushort* __restrict__ Qb, const ushort* __restrict__ Kb,
              const ushort* __restrict__ Vb, const float* __restrict__ adj,
              float* __restrict__ PN, float* __restrict__ ST, float scale)
{
    __shared__ __align__(16) float adjs[64][68];   // [qrow][key] chunk tile
    __shared__ __align__(16) short PH[4][16][72];
    __shared__ __align__(16) short PL[4][16][72];
    const int z = blockIdx.y;
    const int s = blockIdx.z;
    const int m0 = blockIdx.x * 64;
    const int t = threadIdx.x;
    const int lane = t & 63, w = t >> 6;
    const int lm = lane & 15, lq = lane >> 4;
    const int qrow0 = m0 + w * 16;

    const ushort* Qz = Qb + (long)z * MPAD * 256;
    const ushort* Kz = Kb + (long)z * MPAD * 256;
    const ushort* Vz = Vb + (long)z * ATTc * (2 * MPAD);

    short8 qh[4], ql[4];
    {
        const ushort* qp = Qz + (long)(qrow0 + lm) * 256;
#pragma unroll
        for (int ks = 0; ks < 4; ks++) {
            qh[ks] = *(const short8*)(qp + ks * 32 + lq * 8);
            ql[ks] = *(const short8*)(qp + 128 + ks * 32 + lq * 8);
        }
    }

    f32x4 oacc[8];
#pragma unroll
    for (int at = 0; at < 8; at++)
#pragma unroll
        for (int r = 0; r < 4; r++) oacc[at][r] = 0.f;
    float mx[4] = {-3e38f, -3e38f, -3e38f, -3e38f};
    float E[4] = {}, S[4] = {};

    const int kbase = s * 320;
    for (int c = 0; c < 5; c++) {
        const int kc = kbase + c * 64;
        // ---- prefetch adj chunk [64 q][64 k] into regs (coalesced) ----
        float4 areg[4];
#pragma unroll
        for (int p = 0; p < 4; p++) {
            int e = t + p * 256;
            int row = e >> 4, k4 = (e & 15) << 2;
            const float* ap = adj + (long)(m0 + row) * Mc + kc + k4;
            if (kc + k4 + 3 < Mc) areg[p] = *(const float4*)ap;
            else {
#pragma unroll
                for (int i = 0; i < 4; i++)
                    ((float*)&areg[p])[i] = (kc + k4 + i < Mc) ? ap[i] : 0.f;
            }
        }
        // ---- S = Q K^T over 4 key tiles (split bf16, frags from global) --
        f32x4 sacc[4];
#pragma unroll
        for (int nt = 0; nt < 4; nt++)
#pragma unroll
            for (int r = 0; r < 4; r++) sacc[nt][r] = 0.f;
#pragma unroll
        for (int nt = 0; nt < 4; nt++) {
            const ushort* kp = Kz + (long)(kc + nt * 16 + lm) * 256;
            short8 kh[4], kl[4];
#pragma unroll
            for (int ks = 0; ks < 4; ks++) {
                kh[ks] = *(const short8*)(kp + ks * 32 + lq * 8);
                kl[ks] = *(const short8*)(kp + 128 + ks * 32 + lq * 8);
            }
#pragma unroll
            for (int ks = 0; ks < 4; ks++) {
                sacc[nt] = __builtin_amdgcn_mfma_f32_16x16x32_bf16(qh[ks], kh[ks], sacc[nt], 0, 0, 0);
                sacc[nt] = __builtin_amdgcn_mfma_f32_16x16x32_bf16(qh[ks], kl[ks], sacc[nt], 0, 0, 0);
                sacc[nt] = __builtin_amdgcn_mfma_f32_16x16x32_bf16(ql[ks], kh[ks], sacc[nt], 0, 0, 0);
            }
        }
        // ---- adj regs -> LDS (prev chunk's reads are done by program order)
        __syncthreads();
#pragma unroll
        for (int p = 0; p < 4; p++) {
            int e = t + p * 256;
            int row = e >> 4, k4 = (e & 15) << 2;
            *(float4*)&adjs[row][k4] = areg[p];
        }
        __syncthreads();
        // ---- row stats ----
        const int keyb = kc + lm;
        float tmax[4] = {-3e38f, -3e38f, -3e38f, -3e38f};
#pragma unroll
        for (int nt = 0; nt < 4; nt++) {
            bool valid = (keyb + nt * 16) < Mc;
#pragma unroll
            for (int r = 0; r < 4; r++) {
                float sv = sacc[nt][r] * scale;
                sacc[nt][r] = sv;
                if (valid) tmax[r] = fmaxf(tmax[r], sv);
            }
        }
#pragma unroll
        for (int mk = 1; mk <= 8; mk <<= 1)
#pragma unroll
            for (int r = 0; r < 4; r++)
                tmax[r] = fmaxf(tmax[r], __shfl_xor(tmax[r], mk, 64));
        float al[4];
#pragma unroll
        for (int r = 0; r < 4; r++) {
            float nm = fmaxf(mx[r], tmax[r]);
            al[r] = __expf(mx[r] - nm);
            mx[r] = nm;
        }
        float tE[4] = {}, tS[4] = {};
#pragma unroll
        for (int nt = 0; nt < 4; nt++) {
            int key = keyb + nt * 16;
            bool valid = key < Mc;
#pragma unroll
            for (int r = 0; r < 4; r++) {
                float e = valid ? __expf(sacc[nt][r] - mx[r]) : 0.f;
                float a = adjs[lq * 4 + r][nt * 16 + lm];
                float ea = e * a;
                sacc[nt][r] = ea;
                tE[r] += e; tS[r] += ea;
            }
        }
#pragma unroll
        for (int mk = 1; mk <= 8; mk <<= 1)
#pragma unroll
            for (int r = 0; r < 4; r++) {
                tE[r] += __shfl_xor(tE[r], mk, 64);
                tS[r] += __shfl_xor(tS[r], mk, 64);
            }
#pragma unroll
        for (int r = 0; r < 4; r++) {
            E[r] = E[r] * al[r] + tE[r];
            S[r] = S[r] * al[r] + tS[r];
        }
#pragma unroll
        for (int at = 0; at < 8; at++)
#pragma unroll
            for (int r = 0; r < 4; r++) oacc[at][r] *= al[r];
        // ---- P -> LDS (wave-private, no barrier needed) ----
#pragma unroll
        for (int nt = 0; nt < 4; nt++)
#pragma unroll
            for (int r = 0; r < 4; r++) {
                short h, l;
                bsplit(sacc[nt][r], h, l);
                PH[w][lq * 4 + r][nt * 16 + lm] = h;
                PL[w][lq * 4 + r][nt * 16 + lm] = l;
            }
        // ---- O += P V (split bf16, V frags from global) ----
        short8 ph[2], pl[2];
#pragma unroll
        for (int ks = 0; ks < 2; ks++) {
            ph[ks] = *(const short8*)&PH[w][lm][ks * 32 + lq * 8];
            pl[ks] = *(const short8*)&PL[w][lm][ks * 32 + lq * 8];
        }
#pragma unroll
        for (int at = 0; at < 8; at++) {
            const ushort* vp = Vz + (long)(at * 16 + lm) * (2 * MPAD) + kc;
            short8 vh[2], vl[2];
#pragma unroll
            for (int ks = 0; ks < 2; ks++) {
                vh[ks] = *(const short8*)(vp + ks * 32 + lq * 8);
                vl[ks] = *(const short8*)(vp + MPAD + ks * 32 + lq * 8);
            }
#pragma unroll
            for (int ks = 0; ks < 2; ks++) {
                oacc[at] = __builtin_amdgcn_mfma_f32_16x16x32_bf16(ph[ks], vh[ks], oacc[at], 0, 0, 0);
                oacc[at] = __builtin_amdgcn_mfma_f32_16x16x32_bf16(ph[ks], vl[ks], oacc[at], 0, 0, 0);
                oacc[at] = __builtin_amdgcn_mfma_f32_16x16x32_bf16(pl[ks], vh[ks], oacc[at], 0, 0, 0);
            }
        }
    }
    // ---- write partials ----
    const long zb = (long)s * MAXBW + z;
#pragma unroll
    for (int at = 0; at < 8; at++)
#pragma unroll
        for (int r = 0; r < 4; r++) {
            int row = qrow0 + lq * 4 + r;
            PN[(zb * MPAD + row) * ATTc + at * 16 + lm] = oacc[at][r];
        }
    if (lm == 0) {
#pragma unroll
        for (int r = 0; r < 4; r++) {
            int row = qrow0 + lq * 4 + r;
            float* st = ST + (zb * MPAD + row) * 4;
            st[0] = mx[r]; st[1] = E[r]; st[2] = S[r];
        }
    }
}

// ---------------- combine split-K partials ----------------
__global__ __launch_bounds__(256)
void combine_k(const float* __restrict__ PN, const float* __restrict__ ST,
               float* __restrict__ O, long total)
{
    long idx = (long)blockIdx.x * 256 + threadIdx.x;
    if (idx >= total) return;
    int col = (int)(idx & 127);
    long r2 = idx >> 7;
    int row = (int)(r2 % Mc);
    int z = (int)(r2 / Mc);
    const long b0 = (long)z, b1 = (long)MAXBW + z;
    const float* s0 = ST + (b0 * MPAD + row) * 4;
    const float* s1 = ST + (b1 * MPAD + row) * 4;
    float mx0 = s0[0], E0 = s0[1], S0 = s0[2];
    float mx1 = s1[0], E1 = s1[1], S1 = s1[2];
    float mxm = fmaxf(mx0, mx1);
    float a0 = __expf(mx0 - mxm), a1 = __expf(mx1 - mxm);
    float denom = (S0 * a0 + S1 * a1) + 1e-8f * (E0 * a0 + E1 * a1);
    float num = PN[(b0 * MPAD + row) * ATTc + col] * a0
              + PN[(b1 * MPAD + row) * ATTc + col] * a1;
    O[((long)z * Mc + row) * ATTc + col] = num / denom;
}

// ---------------- running max of middle-window slice [2N:3N] ---------------
__global__ __launch_bounds__(256)
void cand_update_k(const float* __restrict__ cur, float* __restrict__ cand,
                   int bw0, long total, int first)
{
    long idx = (long)blockIdx.x * 256 + threadIdx.x;
    if (idx >= total) return;
    int c = (int)(idx & 63);
    long r = idx >> 6;
    int n = (int)(r % Nc);
    int i = (int)(r / Nc);
    long bw = bw0 + i;
    float v = cur[((bw * Mc) + 2 * Nc + n) * Cc + c];
    long o = ((bw * Nc) + n) * Cc + c;
    cand[o] = first ? v : fmaxf(cand[o], v);
}

// ---------------- output layer ----------------
__global__ __launch_bounds__(128)
void output_k(const float* __restrict__ h2, const float* __restrict__ Wo,
              const float* __restrict__ bo, float* __restrict__ out)
{
    __shared__ float ds[512];
    int row = blockIdx.x;
    int b = row / Nc, n = row % Nc;
    int t = threadIdx.x;
    for (int e = t; e < 512; e += 128) {
        int tt = e >> 6, c = e & 63;
        ds[e] = h2[(((long)b * 8 + tt) * Nc + n) * Cc + c];
    }
    __syncthreads();
    float acc = bo[t];
    for (int e = 0; e < 512; e++) acc += ds[e] * Wo[e * OUTFc + t];
    acc = fmaxf(acc, 0.f);
    for (int p = 0; p < PREDc; p++)
        out[(((long)b * PREDc + p) * Nc + n) * (long)OUTFc + t] = acc;
}

extern "C" void kernel_launch(void* const* d_in, const int* in_sizes, int n_in,
                              void* d_out, int out_size, void* d_ws, size_t ws_size,
                              hipStream_t stream)
{
    (void)in_sizes; (void)n_in; (void)out_size; (void)ws_size;
    const float* x     = (const float*)d_in[0];
    const float* Wqkv  = (const float*)d_in[4];
    const float* bqkv  = (const float*)d_in[5];
    const float* Wlin  = (const float*)d_in[6];
    const float* blin  = (const float*)d_in[7];
    const float* Wa    = (const float*)d_in[8];
    const float* Wb    = (const float*)d_in[9];
    const float* temb0 = (const float*)d_in[13];
    const float* temb1 = (const float*)d_in[14];
    const float* semb  = (const float*)d_in[15];
    const float* Wo    = (const float*)d_in[16];
    const float* bo    = (const float*)d_in[17];
    float* out = (float*)d_out;

    // ---- workspace (~88 MB) ----
    float* ws   = (float*)d_ws;
    float* CUR  = ws;                                        // 1,536,000 fl
    float* ATTB = CUR + (long)MAXBW * Mc * Cc;               // 3,072,000 fl
    float* NA   = ATTB + (long)MAXBW * Mc * ATTc;            // 38,400
    float* NB   = NA + Mc * Cc;
    float* ADJ  = NB + Mc * Cc;                              // 360,000
    float* CAND = ADJ + (long)Mc * Mc;                       // 512,000
    ushort* Qb  = (ushort*)(CAND + (long)MAXBW * Nc * Cc);   // 40*640*256 us
    ushort* Kb  = Qb + (long)MAXBW * MPAD * 256;
    ushort* Vb  = Kb + (long)MAXBW * MPAD * 256;             // 40*128*1280 us
    float* PN   = (float*)(Vb + (long)MAXBW * ATTc * 2 * MPAD); // 2*40*640*128
    float* STb  = PN + 2L * MAXBW * MPAD * ATTc;             // 2*40*640*4

    const float inv_sqrt_att = 0.08838834764831845f;         // 1/sqrt(128)

    for (int layer = 0; layer < 2; layer++) {
        int Tin = layer ? 10 : 12;
        int nw  = Tin - 2;
        int BW  = Bc * nw;                                   // 40 then 32
        int Mtot = BW * Mc;
        const float* src  = layer ? CAND : x;
        const float* temb = layer ? temb1 : temb0;

        long etotal = (long)BW * Mc * Cc;
        embed_window_k<<<dim3((unsigned)((etotal + 255) / 256)), dim3(256), 0, stream>>>(
            src, temb, semb, CUR, Tin, nw, etotal);

        for (int it = 0; it < 3; it++) {
            // adjacency: mean -> NA/NB -> sigmoid(NA NB^T / 8)
            mean_nab_k<<<dim3(38), dim3(256), 0, stream>>>(CUR, Wa, Wb, NA, NB, BW);
            gemm_k<true, false, 1><<<dim3(10, 10, 1), dim3(256), 0, stream>>>(
                NA, NB, nullptr, ADJ, Mc, Mc, Cc, Cc, Cc, Mc, 0, 0, 0, 0.125f);

            // QKV projection + packed hi/lo split (V relu'd + transposed)
            qkv_split_k<<<dim3(3, 5, BW), dim3(256), 0, stream>>>(
                CUR, Wqkv, bqkv, Qb, Kb, Vb);

            // split-K fused attention
            flash2_k<<<dim3(10, BW, 2), dim3(256), 0, stream>>>(
                Qb, Kb, Vb, ADJ, PN, STb, inv_sqrt_att);
            long ctot = (long)BW * Mc * ATTc;
            combine_k<<<dim3((unsigned)((ctot + 255) / 256)), dim3(256), 0, stream>>>(
                PN, STb, ATTB, ctot);

            // cur_next = att @ Wlin + blin
            gemm_k<false, false, 0><<<dim3(1, (Mtot + 63) / 64, 1), dim3(256), 0, stream>>>(
                ATTB, Wlin, blin, CUR, Mtot, Cc, ATTc, ATTc, Cc, Cc, 0, 0, 0, 1.f);

            // running max of middle window
            long mtot = (long)BW * Nc * Cc;
            cand_update_k<<<dim3((unsigned)((mtot + 255) / 256)), dim3(256), 0, stream>>>(
                CUR, CAND, 0, mtot, it == 0 ? 1 : 0);
        }
    }
    output_k<<<dim3(Bc * Nc), dim3(128), 0, stream>>>(CAND, Wo, bo, out);
}

// Round 8
// 1396.948 us; speedup vs baseline: 4.1249x; 1.0151x over previous
//
#include <hip/hip_runtime.h>
#include <hip/hip_bf16.h>
#include <math.h>

constexpr int Bc   = 4;
constexpr int Nc   = 200;
constexpr int Cc   = 64;
constexpr int Mc   = 600;    // 3*N
constexpr int ATTc = 128;
constexpr int OUTFc = 128;
constexpr int PREDc = 12;
constexpr int MAXBW = 40;
constexpr int MPAD  = 640;   // padded key/row count per window

typedef short short8 __attribute__((ext_vector_type(8)));
typedef float f32x4  __attribute__((ext_vector_type(4)));

static __device__ __forceinline__ void bsplit(float v, short& h, short& l) {
    __hip_bfloat16 hb = __float2bfloat16(v);
    float hf = __bfloat162float(hb);
    __hip_bfloat16 lb = __float2bfloat16(v - hf);
    h = *(short*)&hb; l = *(short*)&lb;
}

// ---------------- embed + sliding window ----------------
__global__ __launch_bounds__(256)
void embed_window_k(const float* __restrict__ src, const float* __restrict__ temb,
                    const float* __restrict__ semb, float* __restrict__ dst,
                    int Tin, int nw, long total)
{
    long idx = (long)blockIdx.x * 256 + threadIdx.x;
    if (idx >= total) return;
    int c = (int)(idx & 63);
    long r = idx >> 6;
    int n = (int)(r % Nc); r /= Nc;
    int j = (int)(r % 3);  r /= 3;
    int w = (int)(r % nw);
    int b = (int)(r / nw);
    int t = w + j;
    dst[idx] = src[(((long)b * Tin + t) * Nc + n) * Cc + c]
             + temb[t * Cc + c] + semb[n * Cc + c];
}

// ---------------- fused node-mean + NA/NB projection (16-row blocks) -------
__global__ __launch_bounds__(256)
void mean_nab_k(const float* __restrict__ cur, const float* __restrict__ Wa,
                const float* __restrict__ Wb, float* __restrict__ NA,
                float* __restrict__ NB, int BW)
{
    __shared__ float Ns[64][17];   // [k][row]
    __shared__ float Ws[64][132];  // [k][ Wa | Wb ]
    const int m0 = blockIdx.x * 16;
    const int t = threadIdx.x;
    for (int e = t; e < 1024; e += 256) {
        int r = e >> 4, c4 = (e & 15) << 2;
        *(float4*)&Ws[r][c4]      = *(const float4*)&Wa[r * 64 + c4];
        *(float4*)&Ws[r][64 + c4] = *(const float4*)&Wb[r * 64 + c4];
    }
    {
        int row = t >> 4, c4 = (t & 15) << 2;
        int gm = m0 + row;
        float4 sv = make_float4(0.f, 0.f, 0.f, 0.f);
        if (gm < Mc) {
            for (int bw = 0; bw < BW; bw++) {
                const float4 v = *(const float4*)&cur[((long)bw * Mc + gm) * Cc + c4];
                sv.x += v.x; sv.y += v.y; sv.z += v.z; sv.w += v.w;
            }
        }
        const float inv = 1.f / BW;
        Ns[c4 + 0][row] = sv.x * inv; Ns[c4 + 1][row] = sv.y * inv;
        Ns[c4 + 2][row] = sv.z * inv; Ns[c4 + 3][row] = sv.w * inv;
    }
    __syncthreads();
    const int row = t >> 4, c8 = (t & 15) * 8;
    float acc[8] = {};
    for (int k = 0; k < 64; k++) {
        float a = Ns[k][row];
        float b[8];
        *(float4*)&b[0] = *(const float4*)&Ws[k][c8];
        *(float4*)&b[4] = *(const float4*)&Ws[k][c8 + 4];
#pragma unroll
        for (int j = 0; j < 8; j++) acc[j] += a * b[j];
    }
    int gm = m0 + row;
    if (gm < Mc) {
#pragma unroll
        for (int j = 0; j < 8; j++) {
            int col = c8 + j;
            if (col < 64) NA[gm * 64 + col] = acc[j];
            else          NB[gm * 64 + col - 64] = acc[j];
        }
    }
}

// ---------------- 64-tile fp32 GEMM (adj, Wlin) ----------------
template<bool BT, bool RELUB, int EPI>
__global__ __launch_bounds__(256)
void gemm_k(const float* __restrict__ A, const float* __restrict__ Bm,
            const float* __restrict__ bias, float* __restrict__ C,
            int M, int N, int K, int lda, int ldb, int ldc,
            long sA, long sB, long sC, float alpha)
{
    __shared__ float As[16][68];
    __shared__ float Bs[16][68];
    const int z = blockIdx.z;
    A  += (long)z * sA;
    Bm += (long)z * sB;
    C  += (long)z * sC;
    const int m0 = blockIdx.y * 64, n0 = blockIdx.x * 64;
    const int t = threadIdx.x;
    const int tx = t & 15, ty = t >> 4;
    float acc[4][4] = {};
    for (int k0 = 0; k0 < K; k0 += 16) {
        {
            int r = t >> 2, kb = (t & 3) << 2;
            int gm = m0 + r;
            const float* ap = A + (long)gm * lda + k0 + kb;
#pragma unroll
            for (int i = 0; i < 4; i++) {
                int gk = k0 + kb + i;
                As[kb + i][r] = (gm < M && gk < K) ? ap[i] : 0.f;
            }
        }
        if (!BT) {
            int nn = t & 63, kq = t >> 6;
#pragma unroll
            for (int i = 0; i < 4; i++) {
                int kk = kq * 4 + i;
                int gk = k0 + kk, gn = n0 + nn;
                float v = (gk < K && gn < N) ? Bm[(long)gk * ldb + gn] : 0.f;
                if (RELUB) v = fmaxf(v, 0.f);
                Bs[kk][nn] = v;
            }
        } else {
            int nn = t >> 2, kb = (t & 3) << 2;
            int gn = n0 + nn;
            const float* bp = Bm + (long)gn * ldb + k0 + kb;
#pragma unroll
            for (int i = 0; i < 4; i++) {
                int gk = k0 + kb + i;
                float v = (gn < N && gk < K) ? bp[i] : 0.f;
                if (RELUB) v = fmaxf(v, 0.f);
                Bs[kb + i][nn] = v;
            }
        }
        __syncthreads();
#pragma unroll
        for (int kk = 0; kk < 16; kk++) {
            const float4 a4 = *(const float4*)&As[kk][ty * 4];
            const float4 b4 = *(const float4*)&Bs[kk][tx * 4];
            const float a[4] = {a4.x, a4.y, a4.z, a4.w};
            const float b[4] = {b4.x, b4.y, b4.z, b4.w};
#pragma unroll
            for (int i = 0; i < 4; i++)
#pragma unroll
                for (int j = 0; j < 4; j++) acc[i][j] += a[i] * b[j];
        }
        __syncthreads();
    }
#pragma unroll
    for (int i = 0; i < 4; i++) {
        int gm = m0 + ty * 4 + i;
        if (gm >= M) continue;
#pragma unroll
        for (int j = 0; j < 4; j++) {
            int gn = n0 + tx * 4 + j;
            if (gn >= N) continue;
            float v = acc[i][j] * alpha;
            if (bias) v += bias[gn];
            if (EPI == 1) v = 1.f / (1.f + __expf(-v));
            if (EPI == 2) v = fmaxf(v, 0.f);
            C[(long)gm * ldc + gn] = v;
        }
    }
}

// ---------------- QKV GEMM -> packed hi/lo bf16 layouts ----------------
// XCD-swizzled 1-D grid: blocks of window z pinned to XCD z%8 so flash's
// reads hit the same L2. Per z: 15 blocks (which 0..2 x tile 0..4).
__global__ __launch_bounds__(256)
void qkv_split_k(const float* __restrict__ CURp, const float* __restrict__ Wqkv,
                 const float* __restrict__ bias,
                 ushort* __restrict__ Qb, ushort* __restrict__ Kb,
                 ushort* __restrict__ Vb)
{
    __shared__ float As[16][132];
    __shared__ float Bs[16][132];
    const int bid = blockIdx.x;
    const int xcd = bid & 7, slot = bid >> 3;
    const int z = (slot / 15) * 8 + xcd;
    const int r15 = slot % 15;
    const int which = r15 % 3;             // 0=q 1=k 2=v
    const int m0 = (r15 / 3) * 128;
    const float* A = CURp + (long)z * Mc * Cc;
    const int n0 = which * 128;
    const int t = threadIdx.x;
    const int tx = t & 15, ty = t >> 4;
    float acc[8][8] = {};

    for (int k0 = 0; k0 < 64; k0 += 16) {
#pragma unroll
        for (int pass = 0; pass < 2; pass++) {
            int e = t + pass * 256;
            int rr = e >> 2, kb = (e & 3) << 2;
            int gm = m0 + rr;
            float4 v = make_float4(0.f, 0.f, 0.f, 0.f);
            if (gm < Mc) v = *(const float4*)(A + (long)gm * 64 + k0 + kb);
            As[kb + 0][rr] = v.x; As[kb + 1][rr] = v.y;
            As[kb + 2][rr] = v.z; As[kb + 3][rr] = v.w;
        }
#pragma unroll
        for (int pass = 0; pass < 2; pass++) {
            int e = t + pass * 256;
            int kk = e >> 5, n4 = (e & 31) << 2;
            float4 v = *(const float4*)(Wqkv + (long)(k0 + kk) * 384 + n0 + n4);
            *(float4*)&Bs[kk][n4] = v;
        }
        __syncthreads();
#pragma unroll
        for (int kk = 0; kk < 16; kk++) {
            float a[8], b[8];
            *(float4*)&a[0] = *(const float4*)&As[kk][ty * 8];
            *(float4*)&a[4] = *(const float4*)&As[kk][ty * 8 + 4];
            *(float4*)&b[0] = *(const float4*)&Bs[kk][tx * 8];
            *(float4*)&b[4] = *(const float4*)&Bs[kk][tx * 8 + 4];
#pragma unroll
            for (int i = 0; i < 8; i++)
#pragma unroll
                for (int j = 0; j < 8; j++) acc[i][j] += a[i] * b[j];
        }
        __syncthreads();
    }

    if (which == 2) {
        if (m0 + ty * 8 < Mc) {
            ushort* vz = Vb + (long)z * ATTc * (2 * MPAD);
#pragma unroll
            for (int j = 0; j < 8; j++) {
                int col = tx * 8 + j;
                short8 h8, l8;
#pragma unroll
                for (int i = 0; i < 8; i++) {
                    float v = fmaxf(acc[i][j] + bias[n0 + col], 0.f);
                    short hs, ls;
                    bsplit(v, hs, ls);
                    h8[i] = hs; l8[i] = ls;
                }
                *(short8*)(vz + (long)col * (2 * MPAD) + m0 + ty * 8) = h8;
                *(short8*)(vz + (long)col * (2 * MPAD) + MPAD + m0 + ty * 8) = l8;
            }
        }
    } else {
        ushort* dst = (which == 0 ? Qb : Kb) + (long)z * MPAD * 256;
#pragma unroll
        for (int i = 0; i < 8; i++) {
            int row = m0 + ty * 8 + i;
            if (row >= Mc) continue;
            short8 h8, l8;
#pragma unroll
            for (int j = 0; j < 8; j++) {
                float v = acc[i][j] + bias[n0 + tx * 8 + j];
                short hs, ls;
                bsplit(v, hs, ls);
                h8[j] = hs; l8[j] = ls;
            }
            *(short8*)(dst + (long)row * 256 + tx * 8) = h8;
            *(short8*)(dst + (long)row * 256 + 128 + tx * 8) = l8;
        }
    }
}

// -------- split-K flash: S -> softmax*adj partials -> partial PV -----------
// XCD-swizzled 1-D grid: 20 blocks per z (10 qtiles x 2 splits), z pinned to
// XCD z%8 -> K/V/Q reads served by the local L2 (written there by qkv).
__global__ __launch_bounds__(256)
void flash2_k(const ushort* __restrict__ Qb, const ushort* __restrict__ Kb,
              const ushort* __restrict__ Vb, const float* __restrict__ adj,
              float* __restrict__ PN, float* __restrict__ ST, float scale)
{
    __shared__ __align__(16) float adjs[64][68];   // [qrow][key] chunk tile
    __shared__ __align__(16) short PH[4][16][72];
    __shared__ __align__(16) short PL[4][16][72];
    const int bid = blockIdx.x;
    const int xcd = bid & 7, slot = bid >> 3;
    const int z = (slot / 20) * 8 + xcd;
    const int r20 = slot % 20;
    const int s = r20 / 10;
    const int m0 = (r20 % 10) * 64;
    const int t = threadIdx.x;
    const int lane = t & 63, w = t >> 6;
    const int lm = lane & 15, lq = lane >> 4;
    const int qrow0 = m0 + w * 16;

    const ushort* Qz = Qb + (long)z * MPAD * 256;
    const ushort* Kz = Kb + (long)z * MPAD * 256;
    const ushort* Vz = Vb + (long)z * ATTc * (2 * MPAD);

    short8 qh[4], ql[4];
    {
        const ushort* qp = Qz + (long)(qrow0 + lm) * 256;
#pragma unroll
        for (int ks = 0; ks < 4; ks++) {
            qh[ks] = *(const short8*)(qp + ks * 32 + lq * 8);
            ql[ks] = *(const short8*)(qp + 128 + ks * 32 + lq * 8);
        }
    }

    f32x4 oacc[8];
#pragma unroll
    for (int at = 0; at < 8; at++)
#pragma unroll
        for (int r = 0; r < 4; r++) oacc[at][r] = 0.f;
    float mx[4] = {-3e38f, -3e38f, -3e38f, -3e38f};
    float E[4] = {}, S[4] = {};

    const int kbase = s * 320;
    for (int c = 0; c < 5; c++) {
        const int kc = kbase + c * 64;
        // ---- prefetch adj chunk [64 q][64 k] into regs (coalesced) ----
        float4 areg[4];
#pragma unroll
        for (int p = 0; p < 4; p++) {
            int e = t + p * 256;
            int row = e >> 4, k4 = (e & 15) << 2;
            const float* ap = adj + (long)(m0 + row) * Mc + kc + k4;
            bool rin = (m0 + row) < Mc;
            if (rin && kc + k4 + 3 < Mc) areg[p] = *(const float4*)ap;
            else {
#pragma unroll
                for (int i = 0; i < 4; i++)
                    ((float*)&areg[p])[i] = (rin && kc + k4 + i < Mc) ? ap[i] : 0.f;
            }
        }
        // ---- S = Q K^T over 4 key tiles (split bf16, frags from global) --
        f32x4 sacc[4];
#pragma unroll
        for (int nt = 0; nt < 4; nt++)
#pragma unroll
            for (int r = 0; r < 4; r++) sacc[nt][r] = 0.f;
#pragma unroll
        for (int nt = 0; nt < 4; nt++) {
            const ushort* kp = Kz + (long)(kc + nt * 16 + lm) * 256;
            short8 kh[4], kl[4];
#pragma unroll
            for (int ks = 0; ks < 4; ks++) {
                kh[ks] = *(const short8*)(kp + ks * 32 + lq * 8);
                kl[ks] = *(const short8*)(kp + 128 + ks * 32 + lq * 8);
            }
#pragma unroll
            for (int ks = 0; ks < 4; ks++) {
                sacc[nt] = __builtin_amdgcn_mfma_f32_16x16x32_bf16(qh[ks], kh[ks], sacc[nt], 0, 0, 0);
                sacc[nt] = __builtin_amdgcn_mfma_f32_16x16x32_bf16(qh[ks], kl[ks], sacc[nt], 0, 0, 0);
                sacc[nt] = __builtin_amdgcn_mfma_f32_16x16x32_bf16(ql[ks], kh[ks], sacc[nt], 0, 0, 0);
            }
        }
        // ---- adj regs -> LDS ----
        __syncthreads();
#pragma unroll
        for (int p = 0; p < 4; p++) {
            int e = t + p * 256;
            int row = e >> 4, k4 = (e & 15) << 2;
            *(float4*)&adjs[row][k4] = areg[p];
        }
        __syncthreads();
        // ---- row stats ----
        const int keyb = kc + lm;
        float tmax[4] = {-3e38f, -3e38f, -3e38f, -3e38f};
#pragma unroll
        for (int nt = 0; nt < 4; nt++) {
            bool valid = (keyb + nt * 16) < Mc;
#pragma unroll
            for (int r = 0; r < 4; r++) {
                float sv = sacc[nt][r] * scale;
                sacc[nt][r] = sv;
                if (valid) tmax[r] = fmaxf(tmax[r], sv);
            }
        }
#pragma unroll
        for (int mk = 1; mk <= 8; mk <<= 1)
#pragma unroll
            for (int r = 0; r < 4; r++)
                tmax[r] = fmaxf(tmax[r], __shfl_xor(tmax[r], mk, 64));
        float al[4];
#pragma unroll
        for (int r = 0; r < 4; r++) {
            float nm = fmaxf(mx[r], tmax[r]);
            al[r] = __expf(mx[r] - nm);
            mx[r] = nm;
        }
        float tE[4] = {}, tS[4] = {};
#pragma unroll
        for (int nt = 0; nt < 4; nt++) {
            int key = keyb + nt * 16;
            bool valid = key < Mc;
#pragma unroll
            for (int r = 0; r < 4; r++) {
                float e = valid ? __expf(sacc[nt][r] - mx[r]) : 0.f;
                float a = adjs[w * 16 + lq * 4 + r][nt * 16 + lm];  // BUGFIX: +w*16
                float ea = e * a;
                sacc[nt][r] = ea;
                tE[r] += e; tS[r] += ea;
            }
        }
#pragma unroll
        for (int mk = 1; mk <= 8; mk <<= 1)
#pragma unroll
            for (int r = 0; r < 4; r++) {
                tE[r] += __shfl_xor(tE[r], mk, 64);
                tS[r] += __shfl_xor(tS[r], mk, 64);
            }
#pragma unroll
        for (int r = 0; r < 4; r++) {
            E[r] = E[r] * al[r] + tE[r];
            S[r] = S[r] * al[r] + tS[r];
        }
#pragma unroll
        for (int at = 0; at < 8; at++)
#pragma unroll
            for (int r = 0; r < 4; r++) oacc[at][r] *= al[r];
        // ---- P -> LDS (wave-private, no barrier needed) ----
#pragma unroll
        for (int nt = 0; nt < 4; nt++)
#pragma unroll
            for (int r = 0; r < 4; r++) {
                short h, l;
                bsplit(sacc[nt][r], h, l);
                PH[w][lq * 4 + r][nt * 16 + lm] = h;
                PL[w][lq * 4 + r][nt * 16 + lm] = l;
            }
        // ---- O += P V (split bf16, V frags from global) ----
        short8 ph[2], pl[2];
#pragma unroll
        for (int ks = 0; ks < 2; ks++) {
            ph[ks] = *(const short8*)&PH[w][lm][ks * 32 + lq * 8];
            pl[ks] = *(const short8*)&PL[w][lm][ks * 32 + lq * 8];
        }
#pragma unroll
        for (int at = 0; at < 8; at++) {
            const ushort* vp = Vz + (long)(at * 16 + lm) * (2 * MPAD) + kc;
            short8 vh[2], vl[2];
#pragma unroll
            for (int ks = 0; ks < 2; ks++) {
                vh[ks] = *(const short8*)(vp + ks * 32 + lq * 8);
                vl[ks] = *(const short8*)(vp + MPAD + ks * 32 + lq * 8);
            }
#pragma unroll
            for (int ks = 0; ks < 2; ks++) {
                oacc[at] = __builtin_amdgcn_mfma_f32_16x16x32_bf16(ph[ks], vh[ks], oacc[at], 0, 0, 0);
                oacc[at] = __builtin_amdgcn_mfma_f32_16x16x32_bf16(ph[ks], vl[ks], oacc[at], 0, 0, 0);
                oacc[at] = __builtin_amdgcn_mfma_f32_16x16x32_bf16(pl[ks], vh[ks], oacc[at], 0, 0, 0);
            }
        }
    }
    // ---- write partials ----
    const long zb = (long)s * MAXBW + z;
#pragma unroll
    for (int at = 0; at < 8; at++)
#pragma unroll
        for (int r = 0; r < 4; r++) {
            int row = qrow0 + lq * 4 + r;
            PN[(zb * MPAD + row) * ATTc + at * 16 + lm] = oacc[at][r];
        }
    if (lm == 0) {
#pragma unroll
        for (int r = 0; r < 4; r++) {
            int row = qrow0 + lq * 4 + r;
            float* st = ST + (zb * MPAD + row) * 4;
            st[0] = mx[r]; st[1] = E[r]; st[2] = S[r];
        }
    }
}

// ---------------- combine split-K partials ----------------
__global__ __launch_bounds__(256)
void combine_k(const float* __restrict__ PN, const float* __restrict__ ST,
               float* __restrict__ O, long total)
{
    long idx = (long)blockIdx.x * 256 + threadIdx.x;
    if (idx >= total) return;
    int col = (int)(idx & 127);
    long r2 = idx >> 7;
    int row = (int)(r2 % Mc);
    int z = (int)(r2 / Mc);
    const long b0 = (long)z, b1 = (long)MAXBW + z;
    const float* s0 = ST + (b0 * MPAD + row) * 4;
    const float* s1 = ST + (b1 * MPAD + row) * 4;
    float mx0 = s0[0], E0 = s0[1], S0 = s0[2];
    float mx1 = s1[0], E1 = s1[1], S1 = s1[2];
    float mxm = fmaxf(mx0, mx1);
    float a0 = __expf(mx0 - mxm), a1 = __expf(mx1 - mxm);
    float denom = (S0 * a0 + S1 * a1) + 1e-8f * (E0 * a0 + E1 * a1);
    float num = PN[(b0 * MPAD + row) * ATTc + col] * a0
              + PN[(b1 * MPAD + row) * ATTc + col] * a1;
    O[((long)z * Mc + row) * ATTc + col] = num / denom;
}

// ---------------- running max of middle-window slice [2N:3N] ---------------
__global__ __launch_bounds__(256)
void cand_update_k(const float* __restrict__ cur, float* __restrict__ cand,
                   int bw0, long total, int first)
{
    long idx = (long)blockIdx.x * 256 + threadIdx.x;
    if (idx >= total) return;
    int c = (int)(idx & 63);
    long r = idx >> 6;
    int n = (int)(r % Nc);
    int i = (int)(r / Nc);
    long bw = bw0 + i;
    float v = cur[((bw * Mc) + 2 * Nc + n) * Cc + c];
    long o = ((bw * Nc) + n) * Cc + c;
    cand[o] = first ? v : fmaxf(cand[o], v);
}

// ---------------- output layer ----------------
__global__ __launch_bounds__(128)
void output_k(const float* __restrict__ h2, const float* __restrict__ Wo,
              const float* __restrict__ bo, float* __restrict__ out)
{
    __shared__ float ds[512];
    int row = blockIdx.x;
    int b = row / Nc, n = row % Nc;
    int t = threadIdx.x;
    for (int e = t; e < 512; e += 128) {
        int tt = e >> 6, c = e & 63;
        ds[e] = h2[(((long)b * 8 + tt) * Nc + n) * Cc + c];
    }
    __syncthreads();
    float acc = bo[t];
    for (int e = 0; e < 512; e++) acc += ds[e] * Wo[e * OUTFc + t];
    acc = fmaxf(acc, 0.f);
    for (int p = 0; p < PREDc; p++)
        out[(((long)b * PREDc + p) * Nc + n) * (long)OUTFc + t] = acc;
}

extern "C" void kernel_launch(void* const* d_in, const int* in_sizes, int n_in,
                              void* d_out, int out_size, void* d_ws, size_t ws_size,
                              hipStream_t stream)
{
    (void)in_sizes; (void)n_in; (void)out_size; (void)ws_size;
    const float* x     = (const float*)d_in[0];
    const float* Wqkv  = (const float*)d_in[4];
    const float* bqkv  = (const float*)d_in[5];
    const float* Wlin  = (const float*)d_in[6];
    const float* blin  = (const float*)d_in[7];
    const float* Wa    = (const float*)d_in[8];
    const float* Wb    = (const float*)d_in[9];
    const float* temb0 = (const float*)d_in[13];
    const float* temb1 = (const float*)d_in[14];
    const float* semb  = (const float*)d_in[15];
    const float* Wo    = (const float*)d_in[16];
    const float* bo    = (const float*)d_in[17];
    float* out = (float*)d_out;

    // ---- workspace (~88 MB) ----
    float* ws   = (float*)d_ws;
    float* CUR  = ws;                                        // 1,536,000 fl
    float* ATTB = CUR + (long)MAXBW * Mc * Cc;               // 3,072,000 fl
    float* NA   = ATTB + (long)MAXBW * Mc * ATTc;            // 38,400
    float* NB   = NA + Mc * Cc;
    float* ADJ  = NB + Mc * Cc;                              // 360,000
    float* CAND = ADJ + (long)Mc * Mc;                       // 512,000
    ushort* Qb  = (ushort*)(CAND + (long)MAXBW * Nc * Cc);   // 40*640*256 us
    ushort* Kb  = Qb + (long)MAXBW * MPAD * 256;
    ushort* Vb  = Kb + (long)MAXBW * MPAD * 256;             // 40*128*1280 us
    float* PN   = (float*)(Vb + (long)MAXBW * ATTc * 2 * MPAD); // 2*40*640*128
    float* STb  = PN + 2L * MAXBW * MPAD * ATTc;             // 2*40*640*4

    const float inv_sqrt_att = 0.08838834764831845f;         // 1/sqrt(128)

    for (int layer = 0; layer < 2; layer++) {
        int Tin = layer ? 10 : 12;
        int nw  = Tin - 2;
        int BW  = Bc * nw;                                   // 40 then 32
        int Mtot = BW * Mc;
        const float* src  = layer ? CAND : x;
        const float* temb = layer ? temb1 : temb0;

        long etotal = (long)BW * Mc * Cc;
        embed_window_k<<<dim3((unsigned)((etotal + 255) / 256)), dim3(256), 0, stream>>>(
            src, temb, semb, CUR, Tin, nw, etotal);

        for (int it = 0; it < 3; it++) {
            // adjacency: mean -> NA/NB -> sigmoid(NA NB^T / 8)
            mean_nab_k<<<dim3(38), dim3(256), 0, stream>>>(CUR, Wa, Wb, NA, NB, BW);
            gemm_k<true, false, 1><<<dim3(10, 10, 1), dim3(256), 0, stream>>>(
                NA, NB, nullptr, ADJ, Mc, Mc, Cc, Cc, Cc, Mc, 0, 0, 0, 0.125f);

            // QKV projection + packed hi/lo split (XCD-swizzled: z -> XCD z%8)
            qkv_split_k<<<dim3(BW * 15), dim3(256), 0, stream>>>(
                CUR, Wqkv, bqkv, Qb, Kb, Vb);

            // split-K fused attention (XCD-swizzled, same z -> XCD mapping)
            flash2_k<<<dim3(BW * 20), dim3(256), 0, stream>>>(
                Qb, Kb, Vb, ADJ, PN, STb, inv_sqrt_att);
            long ctot = (long)BW * Mc * ATTc;
            combine_k<<<dim3((unsigned)((ctot + 255) / 256)), dim3(256), 0, stream>>>(
                PN, STb, ATTB, ctot);

            // cur_next = att @ Wlin + blin
            gemm_k<false, false, 0><<<dim3(1, (Mtot + 63) / 64, 1), dim3(256), 0, stream>>>(
                ATTB, Wlin, blin, CUR, Mtot, Cc, ATTc, ATTc, Cc, Cc, 0, 0, 0, 1.f);

            // running max of middle window
            long mtot = (long)BW * Nc * Cc;
            cand_update_k<<<dim3((unsigned)((mtot + 255) / 256)), dim3(256), 0, stream>>>(
                CUR, CAND, 0, mtot, it == 0 ? 1 : 0);
        }
    }
    output_k<<<dim3(Bc * Nc), dim3(128), 0, stream>>>(CAND, Wo, bo, out);
}

// Round 9
// 1180.120 us; speedup vs baseline: 4.8828x; 1.1837x over previous
//
#include <hip/hip_runtime.h>
#include <hip/hip_bf16.h>
#include <math.h>

constexpr int Bc   = 4;
constexpr int Nc   = 200;
constexpr int Cc   = 64;
constexpr int Mc   = 600;    // 3*N
constexpr int ATTc = 128;
constexpr int OUTFc = 128;
constexpr int PREDc = 12;
constexpr int MAXBW = 40;
constexpr int MPAD  = 640;   // padded V^T leading dim

typedef short short8 __attribute__((ext_vector_type(8)));
typedef float f32x4  __attribute__((ext_vector_type(4)));

static __device__ __forceinline__ void bsplit(float v, short& h, short& l) {
    __hip_bfloat16 hb = __float2bfloat16(v);
    float hf = __bfloat162float(hb);
    __hip_bfloat16 lb = __float2bfloat16(v - hf);
    h = *(short*)&hb; l = *(short*)&lb;
}

// ---------------- embed + sliding window ----------------
__global__ __launch_bounds__(256)
void embed_window_k(const float* __restrict__ src, const float* __restrict__ temb,
                    const float* __restrict__ semb, float* __restrict__ dst,
                    int Tin, int nw, long total)
{
    long idx = (long)blockIdx.x * 256 + threadIdx.x;
    if (idx >= total) return;
    int c = (int)(idx & 63);
    long r = idx >> 6;
    int n = (int)(r % Nc); r /= Nc;
    int j = (int)(r % 3);  r /= 3;
    int w = (int)(r % nw);
    int b = (int)(r / nw);
    int t = w + j;
    dst[idx] = src[(((long)b * Tin + t) * Nc + n) * Cc + c]
             + temb[t * Cc + c] + semb[n * Cc + c];
}

// ---------------- fused node-mean + NA/NB projection (16-row blocks) -------
__global__ __launch_bounds__(256)
void mean_nab_k(const float* __restrict__ cur, const float* __restrict__ Wa,
                const float* __restrict__ Wb, float* __restrict__ NA,
                float* __restrict__ NB, int BW)
{
    __shared__ float Ns[64][17];   // [k][row]
    __shared__ float Ws[64][132];  // [k][ Wa | Wb ]
    const int m0 = blockIdx.x * 16;
    const int t = threadIdx.x;
    for (int e = t; e < 1024; e += 256) {
        int r = e >> 4, c4 = (e & 15) << 2;
        *(float4*)&Ws[r][c4]      = *(const float4*)&Wa[r * 64 + c4];
        *(float4*)&Ws[r][64 + c4] = *(const float4*)&Wb[r * 64 + c4];
    }
    {
        int row = t >> 4, c4 = (t & 15) << 2;
        int gm = m0 + row;
        float4 sv = make_float4(0.f, 0.f, 0.f, 0.f);
        if (gm < Mc) {
            for (int bw = 0; bw < BW; bw++) {
                const float4 v = *(const float4*)&cur[((long)bw * Mc + gm) * Cc + c4];
                sv.x += v.x; sv.y += v.y; sv.z += v.z; sv.w += v.w;
            }
        }
        const float inv = 1.f / BW;
        Ns[c4 + 0][row] = sv.x * inv; Ns[c4 + 1][row] = sv.y * inv;
        Ns[c4 + 2][row] = sv.z * inv; Ns[c4 + 3][row] = sv.w * inv;
    }
    __syncthreads();
    const int row = t >> 4, c8 = (t & 15) * 8;
    float acc[8] = {};
    for (int k = 0; k < 64; k++) {
        float a = Ns[k][row];
        float b[8];
        *(float4*)&b[0] = *(const float4*)&Ws[k][c8];
        *(float4*)&b[4] = *(const float4*)&Ws[k][c8 + 4];
#pragma unroll
        for (int j = 0; j < 8; j++) acc[j] += a * b[j];
    }
    int gm = m0 + row;
    if (gm < Mc) {
#pragma unroll
        for (int j = 0; j < 8; j++) {
            int col = c8 + j;
            if (col < 64) NA[gm * 64 + col] = acc[j];
            else          NB[gm * 64 + col - 64] = acc[j];
        }
    }
}

// ---------------- 64-tile fp32 GEMM (adj, Wlin) ----------------
template<bool BT, bool RELUB, int EPI>
__global__ __launch_bounds__(256)
void gemm_k(const float* __restrict__ A, const float* __restrict__ Bm,
            const float* __restrict__ bias, float* __restrict__ C,
            int M, int N, int K, int lda, int ldb, int ldc,
            long sA, long sB, long sC, float alpha)
{
    __shared__ float As[16][68];
    __shared__ float Bs[16][68];
    const int z = blockIdx.z;
    A  += (long)z * sA;
    Bm += (long)z * sB;
    C  += (long)z * sC;
    const int m0 = blockIdx.y * 64, n0 = blockIdx.x * 64;
    const int t = threadIdx.x;
    const int tx = t & 15, ty = t >> 4;
    float acc[4][4] = {};
    for (int k0 = 0; k0 < K; k0 += 16) {
        {
            int r = t >> 2, kb = (t & 3) << 2;
            int gm = m0 + r;
            const float* ap = A + (long)gm * lda + k0 + kb;
#pragma unroll
            for (int i = 0; i < 4; i++) {
                int gk = k0 + kb + i;
                As[kb + i][r] = (gm < M && gk < K) ? ap[i] : 0.f;
            }
        }
        if (!BT) {
            int nn = t & 63, kq = t >> 6;
#pragma unroll
            for (int i = 0; i < 4; i++) {
                int kk = kq * 4 + i;
                int gk = k0 + kk, gn = n0 + nn;
                float v = (gk < K && gn < N) ? Bm[(long)gk * ldb + gn] : 0.f;
                if (RELUB) v = fmaxf(v, 0.f);
                Bs[kk][nn] = v;
            }
        } else {
            int nn = t >> 2, kb = (t & 3) << 2;
            int gn = n0 + nn;
            const float* bp = Bm + (long)gn * ldb + k0 + kb;
#pragma unroll
            for (int i = 0; i < 4; i++) {
                int gk = k0 + kb + i;
                float v = (gn < N && gk < K) ? bp[i] : 0.f;
                if (RELUB) v = fmaxf(v, 0.f);
                Bs[kb + i][nn] = v;
            }
        }
        __syncthreads();
#pragma unroll
        for (int kk = 0; kk < 16; kk++) {
            const float4 a4 = *(const float4*)&As[kk][ty * 4];
            const float4 b4 = *(const float4*)&Bs[kk][tx * 4];
            const float a[4] = {a4.x, a4.y, a4.z, a4.w};
            const float b[4] = {b4.x, b4.y, b4.z, b4.w};
#pragma unroll
            for (int i = 0; i < 4; i++)
#pragma unroll
                for (int j = 0; j < 4; j++) acc[i][j] += a[i] * b[j];
        }
        __syncthreads();
    }
#pragma unroll
    for (int i = 0; i < 4; i++) {
        int gm = m0 + ty * 4 + i;
        if (gm >= M) continue;
#pragma unroll
        for (int j = 0; j < 4; j++) {
            int gn = n0 + tx * 4 + j;
            if (gn >= N) continue;
            float v = acc[i][j] * alpha;
            if (bias) v += bias[gn];
            if (EPI == 1) v = 1.f / (1.f + __expf(-v));
            if (EPI == 2) v = fmaxf(v, 0.f);
            C[(long)gm * ldc + gn] = v;
        }
    }
}

// ---------------- QKV GEMM -> hi/lo bf16 buffers (packed 16B stores) -------
// Q/K: row-major [z][600][128] hi and lo. V: relu, transposed [z][128][MPAD].
__global__ __launch_bounds__(256)
void qkv_split_k(const float* __restrict__ CURp, const float* __restrict__ Wqkv,
                 const float* __restrict__ bias,
                 ushort* __restrict__ QH, ushort* __restrict__ QL,
                 ushort* __restrict__ KH, ushort* __restrict__ KL,
                 ushort* __restrict__ VTH, ushort* __restrict__ VTL)
{
    __shared__ float As[16][132];
    __shared__ float Bs[16][132];
    const int which = blockIdx.x;          // 0=q 1=k 2=v
    const int m0 = blockIdx.y * 128;
    const int z  = blockIdx.z;
    const float* A = CURp + (long)z * Mc * Cc;
    const int n0 = which * 128;
    const int t = threadIdx.x;
    const int tx = t & 15, ty = t >> 4;
    float acc[8][8] = {};

    for (int k0 = 0; k0 < 64; k0 += 16) {
#pragma unroll
        for (int pass = 0; pass < 2; pass++) {
            int e = t + pass * 256;
            int rr = e >> 2, kb = (e & 3) << 2;
            int gm = m0 + rr;
            float4 v = make_float4(0.f, 0.f, 0.f, 0.f);
            if (gm < Mc) v = *(const float4*)(A + (long)gm * 64 + k0 + kb);
            As[kb + 0][rr] = v.x; As[kb + 1][rr] = v.y;
            As[kb + 2][rr] = v.z; As[kb + 3][rr] = v.w;
        }
#pragma unroll
        for (int pass = 0; pass < 2; pass++) {
            int e = t + pass * 256;
            int kk = e >> 5, n4 = (e & 31) << 2;
            float4 v = *(const float4*)(Wqkv + (long)(k0 + kk) * 384 + n0 + n4);
            *(float4*)&Bs[kk][n4] = v;
        }
        __syncthreads();
#pragma unroll
        for (int kk = 0; kk < 16; kk++) {
            float a[8], b[8];
            *(float4*)&a[0] = *(const float4*)&As[kk][ty * 8];
            *(float4*)&a[4] = *(const float4*)&As[kk][ty * 8 + 4];
            *(float4*)&b[0] = *(const float4*)&Bs[kk][tx * 8];
            *(float4*)&b[4] = *(const float4*)&Bs[kk][tx * 8 + 4];
#pragma unroll
            for (int i = 0; i < 8; i++)
#pragma unroll
                for (int j = 0; j < 8; j++) acc[i][j] += a[i] * b[j];
        }
        __syncthreads();
    }

    if (which == 2) {
        // V: transpose store. row group m0+ty*8..+7 all-valid or all-invalid.
        if (m0 + ty * 8 < Mc) {
            ushort* vh = VTH + (long)z * ATTc * MPAD;
            ushort* vl = VTL + (long)z * ATTc * MPAD;
#pragma unroll
            for (int j = 0; j < 8; j++) {
                int col = tx * 8 + j;
                short8 h8, l8;
#pragma unroll
                for (int i = 0; i < 8; i++) {
                    float v = fmaxf(acc[i][j] + bias[n0 + col], 0.f);
                    short hs, ls;
                    bsplit(v, hs, ls);
                    h8[i] = hs; l8[i] = ls;
                }
                *(short8*)(vh + (long)col * MPAD + m0 + ty * 8) = h8;
                *(short8*)(vl + (long)col * MPAD + m0 + ty * 8) = l8;
            }
        }
    } else {
        ushort* dh = (which == 0 ? QH : KH) + (long)z * Mc * ATTc;
        ushort* dl = (which == 0 ? QL : KL) + (long)z * Mc * ATTc;
#pragma unroll
        for (int i = 0; i < 8; i++) {
            int row = m0 + ty * 8 + i;
            if (row >= Mc) continue;
            short8 h8, l8;
#pragma unroll
            for (int j = 0; j < 8; j++) {
                float v = acc[i][j] + bias[n0 + tx * 8 + j];
                short hs, ls;
                bsplit(v, hs, ls);
                h8[j] = hs; l8[j] = ls;
            }
            *(short8*)(dh + (long)row * ATTc + tx * 8) = h8;
            *(short8*)(dl + (long)row * ATTc + tx * 8) = l8;
        }
    }
}

// ---------------- split-bf16 MFMA GEMM: C = alpha * (Ah+Al) (Bh+Bl)^T ------
// A: [M][K] bf16 (lda), B: [N][K] bf16 (ldb). C fp32 [M][N] (ldc).
// BM=BN=128, BK=32; 4 waves of 64x64 (4x4 frags of 16x16x32 mfma).
__global__ __launch_bounds__(256)
void mfma_bt_k(const ushort* __restrict__ Ah, const ushort* __restrict__ Al,
               const ushort* __restrict__ Bh, const ushort* __restrict__ Bl,
               float* __restrict__ C,
               int M, int N, int K, int lda, int ldb, int ldc,
               long zA, long zB, long zC, float alpha)
{
    __shared__ __align__(16) ushort As[2][128][40];  // [hi/lo][row][k] pad 40
    __shared__ __align__(16) ushort Bs[2][128][40];
    const int z = blockIdx.z;
    Ah += (long)z * zA; Al += (long)z * zA;
    Bh += (long)z * zB; Bl += (long)z * zB;
    C  += (long)z * zC;
    const int m0 = blockIdx.y * 128, n0 = blockIdx.x * 128;
    const int t = threadIdx.x;
    const int lane = t & 63, w = t >> 6;
    const int wm = (w >> 1) * 64, wn = (w & 1) * 64;
    const int lm = lane & 15, lq = lane >> 4;

    f32x4 acc[4][4];
#pragma unroll
    for (int i = 0; i < 4; i++)
#pragma unroll
        for (int j = 0; j < 4; j++)
#pragma unroll
            for (int r = 0; r < 4; r++) acc[i][j][r] = 0.f;

    for (int k0 = 0; k0 < K; k0 += 32) {
        __syncthreads();
#pragma unroll
        for (int p = 0; p < 2; p++) {
            int e = t + p * 256;                 // 0..511
            int row = e >> 2, ks = (e & 3) << 3; // seg of 8
            int gk = k0 + ks;
            bool kin = (gk < K);                 // K % 8 == 0 -> seg granularity
            {
                int gm = m0 + row;
                short8 vh, vl;
#pragma unroll
                for (int q = 0; q < 8; q++) { vh[q] = 0; vl[q] = 0; }
                if (gm < M && kin) {
                    vh = *(const short8*)(Ah + (long)gm * lda + gk);
                    vl = *(const short8*)(Al + (long)gm * lda + gk);
                }
                *(short8*)&As[0][row][ks] = vh;
                *(short8*)&As[1][row][ks] = vl;
            }
            {
                int gn = n0 + row;
                short8 vh, vl;
#pragma unroll
                for (int q = 0; q < 8; q++) { vh[q] = 0; vl[q] = 0; }
                if (gn < N && kin) {
                    vh = *(const short8*)(Bh + (long)gn * ldb + gk);
                    vl = *(const short8*)(Bl + (long)gn * ldb + gk);
                }
                *(short8*)&Bs[0][row][ks] = vh;
                *(short8*)&Bs[1][row][ks] = vl;
            }
        }
        __syncthreads();

        short8 af[4][2], bf[4][2];
#pragma unroll
        for (int i = 0; i < 4; i++) {
            af[i][0] = *(const short8*)&As[0][wm + i * 16 + lm][lq * 8];
            af[i][1] = *(const short8*)&As[1][wm + i * 16 + lm][lq * 8];
        }
#pragma unroll
        for (int j = 0; j < 4; j++) {
            bf[j][0] = *(const short8*)&Bs[0][wn + j * 16 + lm][lq * 8];
            bf[j][1] = *(const short8*)&Bs[1][wn + j * 16 + lm][lq * 8];
        }
#pragma unroll
        for (int i = 0; i < 4; i++)
#pragma unroll
            for (int j = 0; j < 4; j++) {
                acc[i][j] = __builtin_amdgcn_mfma_f32_16x16x32_bf16(
                    af[i][0], bf[j][0], acc[i][j], 0, 0, 0);
                acc[i][j] = __builtin_amdgcn_mfma_f32_16x16x32_bf16(
                    af[i][0], bf[j][1], acc[i][j], 0, 0, 0);
                acc[i][j] = __builtin_amdgcn_mfma_f32_16x16x32_bf16(
                    af[i][1], bf[j][0], acc[i][j], 0, 0, 0);
            }
    }
#pragma unroll
    for (int i = 0; i < 4; i++) {
        int gmb = m0 + wm + i * 16 + lq * 4;
#pragma unroll
        for (int j = 0; j < 4; j++) {
            int gn = n0 + wn + j * 16 + lm;
            if (gn >= N) continue;
#pragma unroll
            for (int r = 0; r < 4; r++) {
                int gm = gmb + r;
                if (gm < M) C[(long)gm * ldc + gn] = acc[i][j][r] * alpha;
            }
        }
    }
}

// -------- softmax*adj + renorm + bf16 hi/lo split, 1 row/wave, in place ----
// w_j = e_j*a_j / (S + 1e-8 E), e = exp(s-mx), E = sum e, S = sum e*a.
__global__ __launch_bounds__(256)
void softmax4_k(float* __restrict__ sc, const float* __restrict__ adj)
{
    const int row = blockIdx.x * 4 + (threadIdx.x >> 6);
    const int lane = threadIdx.x & 63;
    const int m = row % Mc;
    float* s = sc + (long)row * Mc;
    const float* a = adj + (long)m * Mc;

    float v[10], av[10];
    float mx = -3e38f;
#pragma unroll
    for (int i = 0; i < 10; i++) {
        int j = lane + i * 64;
        if (j < Mc) { v[i] = s[j]; av[i] = a[j]; mx = fmaxf(mx, v[i]); }
        else        { v[i] = 0.f; av[i] = 0.f; }
    }
#pragma unroll
    for (int o = 32; o > 0; o >>= 1) mx = fmaxf(mx, __shfl_xor(mx, o, 64));
    float E = 0.f, S = 0.f;
#pragma unroll
    for (int i = 0; i < 10; i++) {
        int j = lane + i * 64;
        if (j < Mc) {
            float e = __expf(v[i] - mx);
            float ea = e * av[i];
            v[i] = ea;
            E += e; S += ea;
        }
    }
#pragma unroll
    for (int o = 32; o > 0; o >>= 1) {
        E += __shfl_xor(E, o, 64);
        S += __shfl_xor(S, o, 64);
    }
    const float inv = 1.f / (S + 1e-8f * E);
    ushort* hi = (ushort*)s;
    ushort* lo = hi + Mc;
#pragma unroll
    for (int i = 0; i < 10; i++) {
        int j = lane + i * 64;
        if (j < Mc) {
            float wv = v[i] * inv;
            short h, l;
            bsplit(wv, h, l);
            hi[j] = (ushort)h; lo[j] = (ushort)l;
        }
    }
}

// ---------------- running max of middle-window slice [2N:3N] ---------------
__global__ __launch_bounds__(256)
void cand_update_k(const float* __restrict__ cur, float* __restrict__ cand,
                   int bw0, long total, int first)
{
    long idx = (long)blockIdx.x * 256 + threadIdx.x;
    if (idx >= total) return;
    int c = (int)(idx & 63);
    long r = idx >> 6;
    int n = (int)(r % Nc);
    int i = (int)(r / Nc);
    long bw = bw0 + i;
    float v = cur[((bw * Mc) + 2 * Nc + n) * Cc + c];
    long o = ((bw * Nc) + n) * Cc + c;
    cand[o] = first ? v : fmaxf(cand[o], v);
}

// ---------------- output layer ----------------
__global__ __launch_bounds__(128)
void output_k(const float* __restrict__ h2, const float* __restrict__ Wo,
              const float* __restrict__ bo, float* __restrict__ out)
{
    __shared__ float ds[512];
    int row = blockIdx.x;
    int b = row / Nc, n = row % Nc;
    int t = threadIdx.x;
    for (int e = t; e < 512; e += 128) {
        int tt = e >> 6, c = e & 63;
        ds[e] = h2[(((long)b * 8 + tt) * Nc + n) * Cc + c];
    }
    __syncthreads();
    float acc = bo[t];
    for (int e = 0; e < 512; e++) acc += ds[e] * Wo[e * OUTFc + t];
    acc = fmaxf(acc, 0.f);
    for (int p = 0; p < PREDc; p++)
        out[(((long)b * PREDc + p) * Nc + n) * (long)OUTFc + t] = acc;
}

extern "C" void kernel_launch(void* const* d_in, const int* in_sizes, int n_in,
                              void* d_out, int out_size, void* d_ws, size_t ws_size,
                              hipStream_t stream)
{
    (void)in_sizes; (void)n_in; (void)out_size; (void)ws_size;
    const float* x     = (const float*)d_in[0];
    const float* Wqkv  = (const float*)d_in[4];
    const float* bqkv  = (const float*)d_in[5];
    const float* Wlin  = (const float*)d_in[6];
    const float* blin  = (const float*)d_in[7];
    const float* Wa    = (const float*)d_in[8];
    const float* Wb    = (const float*)d_in[9];
    const float* temb0 = (const float*)d_in[13];
    const float* temb1 = (const float*)d_in[14];
    const float* semb  = (const float*)d_in[15];
    const float* Wo    = (const float*)d_in[16];
    const float* bo    = (const float*)d_in[17];
    float* out = (float*)d_out;

    // ---- workspace (float offsets), ~105 MB ----
    float* ws   = (float*)d_ws;
    float* CUR  = ws;                                  // 1,536,000
    float* NA   = CUR + (long)MAXBW * Mc * Cc;         // 38,400
    float* NB   = NA + Mc * Cc;                        // 38,400
    float* ADJ  = NB + Mc * Cc;                        // 360,000
    float* CAND = ADJ + (long)Mc * Mc;                 // 512,000
    float* SC   = CAND + (long)MAXBW * Nc * Cc;        // 14,400,000 (W hi/lo in place)
    float* QHf  = SC + (long)MAXBW * Mc * Mc;          // 4 x 1,536,000
    const long QSZ = (long)MAXBW * Mc * ATTc / 2;      // in floats
    float* QLf  = QHf + QSZ;
    float* KHf  = QLf + QSZ;
    float* KLf  = KHf + QSZ;
    float* VTHf = KLf + QSZ;                           // 2 x 1,638,400
    float* VTLf = VTHf + (long)MAXBW * ATTc * MPAD / 2;
    float* ATTB = QHf;                                 // alias: Q dead after scores

    ushort* QH  = (ushort*)QHf;
    ushort* QL  = (ushort*)QLf;
    ushort* KH  = (ushort*)KHf;
    ushort* KL  = (ushort*)KLf;
    ushort* VTH = (ushort*)VTHf;
    ushort* VTL = (ushort*)VTLf;

    const float inv_sqrt_att = 0.08838834764831845f;   // 1/sqrt(128)

    for (int layer = 0; layer < 2; layer++) {
        int Tin = layer ? 10 : 12;
        int nw  = Tin - 2;
        int BW  = Bc * nw;                             // 40 then 32
        int Mtot = BW * Mc;
        const float* src  = layer ? CAND : x;
        const float* temb = layer ? temb1 : temb0;

        long etotal = (long)BW * Mc * Cc;
        embed_window_k<<<dim3((unsigned)((etotal + 255) / 256)), dim3(256), 0, stream>>>(
            src, temb, semb, CUR, Tin, nw, etotal);

        for (int it = 0; it < 3; it++) {
            // adjacency: mean -> NA/NB -> sigmoid(NA NB^T / 8)
            mean_nab_k<<<dim3(38), dim3(256), 0, stream>>>(CUR, Wa, Wb, NA, NB, BW);
            gemm_k<true, false, 1><<<dim3(10, 10, 1), dim3(256), 0, stream>>>(
                NA, NB, nullptr, ADJ, Mc, Mc, Cc, Cc, Cc, Mc, 0, 0, 0, 0.125f);

            // QKV projection + hi/lo split (packed 16B stores)
            qkv_split_k<<<dim3(3, 5, BW), dim3(256), 0, stream>>>(
                CUR, Wqkv, bqkv, QH, QL, KH, KL, VTH, VTL);

            // scores = Q K^T / sqrt(ATT) -> SC fp32
            mfma_bt_k<<<dim3(5, 5, BW), dim3(256), 0, stream>>>(
                QH, QL, KH, KL, SC, Mc, Mc, ATTc, ATTc, ATTc, Mc,
                (long)Mc * ATTc, (long)Mc * ATTc, (long)Mc * Mc, inv_sqrt_att);

            // softmax*adj + renorm, write W hi/lo bf16 in place (1 row/wave)
            softmax4_k<<<dim3(Mtot / 4), dim3(256), 0, stream>>>(SC, ADJ);

            // att = W @ relu(V): A = W (packed hi|lo rows), B = V^T
            mfma_bt_k<<<dim3(1, 5, BW), dim3(256), 0, stream>>>(
                (const ushort*)SC, (const ushort*)SC + Mc, VTH, VTL,
                ATTB, Mc, ATTc, Mc, 2 * Mc, MPAD, ATTc,
                (long)2 * Mc * Mc, (long)ATTc * MPAD, (long)Mc * ATTc, 1.f);

            // cur_next = att @ Wlin + blin
            gemm_k<false, false, 0><<<dim3(1, (Mtot + 63) / 64, 1), dim3(256), 0, stream>>>(
                ATTB, Wlin, blin, CUR, Mtot, Cc, ATTc, ATTc, Cc, Cc, 0, 0, 0, 1.f);

            // running max of middle window
            long mtot = (long)BW * Nc * Cc;
            cand_update_k<<<dim3((unsigned)((mtot + 255) / 256)), dim3(256), 0, stream>>>(
                CUR, CAND, 0, mtot, it == 0 ? 1 : 0);
        }
    }
    output_k<<<dim3(Bc * Nc), dim3(128), 0, stream>>>(CAND, Wo, bo, out);
}

// Round 10
// 1169.044 us; speedup vs baseline: 4.9291x; 1.0095x over previous
//
#include <hip/hip_runtime.h>
#include <hip/hip_bf16.h>
#include <math.h>

constexpr int Bc   = 4;
constexpr int Nc   = 200;
constexpr int Cc   = 64;
constexpr int Mc   = 600;    // 3*N
constexpr int ATTc = 128;
constexpr int OUTFc = 128;
constexpr int PREDc = 12;
constexpr int MAXBW = 40;
constexpr int MPAD  = 640;   // padded V^T leading dim

typedef short short8 __attribute__((ext_vector_type(8)));
typedef float f32x4  __attribute__((ext_vector_type(4)));

static __device__ __forceinline__ void bsplit(float v, short& h, short& l) {
    __hip_bfloat16 hb = __float2bfloat16(v);
    float hf = __bfloat162float(hb);
    __hip_bfloat16 lb = __float2bfloat16(v - hf);
    h = *(short*)&hb; l = *(short*)&lb;
}

// ---------------- embed + sliding window ----------------
__global__ __launch_bounds__(256)
void embed_window_k(const float* __restrict__ src, const float* __restrict__ temb,
                    const float* __restrict__ semb, float* __restrict__ dst,
                    int Tin, int nw, long total)
{
    long idx = (long)blockIdx.x * 256 + threadIdx.x;
    if (idx >= total) return;
    int c = (int)(idx & 63);
    long r = idx >> 6;
    int n = (int)(r % Nc); r /= Nc;
    int j = (int)(r % 3);  r /= 3;
    int w = (int)(r % nw);
    int b = (int)(r / nw);
    int t = w + j;
    dst[idx] = src[(((long)b * Tin + t) * Nc + n) * Cc + c]
             + temb[t * Cc + c] + semb[n * Cc + c];
}

// ---------------- fused node-mean + NA/NB projection (16-row blocks) -------
__global__ __launch_bounds__(256)
void mean_nab_k(const float* __restrict__ cur, const float* __restrict__ Wa,
                const float* __restrict__ Wb, float* __restrict__ NA,
                float* __restrict__ NB, int BW)
{
    __shared__ float Ns[64][17];   // [k][row]
    __shared__ float Ws[64][132];  // [k][ Wa | Wb ]
    const int m0 = blockIdx.x * 16;
    const int t = threadIdx.x;
    for (int e = t; e < 1024; e += 256) {
        int r = e >> 4, c4 = (e & 15) << 2;
        *(float4*)&Ws[r][c4]      = *(const float4*)&Wa[r * 64 + c4];
        *(float4*)&Ws[r][64 + c4] = *(const float4*)&Wb[r * 64 + c4];
    }
    {
        int row = t >> 4, c4 = (t & 15) << 2;
        int gm = m0 + row;
        float4 sv = make_float4(0.f, 0.f, 0.f, 0.f);
        if (gm < Mc) {
            for (int bw = 0; bw < BW; bw++) {
                const float4 v = *(const float4*)&cur[((long)bw * Mc + gm) * Cc + c4];
                sv.x += v.x; sv.y += v.y; sv.z += v.z; sv.w += v.w;
            }
        }
        const float inv = 1.f / BW;
        Ns[c4 + 0][row] = sv.x * inv; Ns[c4 + 1][row] = sv.y * inv;
        Ns[c4 + 2][row] = sv.z * inv; Ns[c4 + 3][row] = sv.w * inv;
    }
    __syncthreads();
    const int row = t >> 4, c8 = (t & 15) * 8;
    float acc[8] = {};
    for (int k = 0; k < 64; k++) {
        float a = Ns[k][row];
        float b[8];
        *(float4*)&b[0] = *(const float4*)&Ws[k][c8];
        *(float4*)&b[4] = *(const float4*)&Ws[k][c8 + 4];
#pragma unroll
        for (int j = 0; j < 8; j++) acc[j] += a * b[j];
    }
    int gm = m0 + row;
    if (gm < Mc) {
#pragma unroll
        for (int j = 0; j < 8; j++) {
            int col = c8 + j;
            if (col < 64) NA[gm * 64 + col] = acc[j];
            else          NB[gm * 64 + col - 64] = acc[j];
        }
    }
}

// ---------------- 64-tile fp32 GEMM (adj, Wlin) ----------------
// If Ee/Ss non-null: A rows are scaled by 1/(Ss[gm] + 1e-8*Ee[gm]) on load.
template<bool BT, int EPI>
__global__ __launch_bounds__(256)
void gemm_k(const float* __restrict__ A, const float* __restrict__ Bm,
            const float* __restrict__ bias, float* __restrict__ C,
            const float* __restrict__ Ee, const float* __restrict__ Ss,
            int M, int N, int K, int lda, int ldb, int ldc,
            long sA, long sB, long sC, float alpha)
{
    __shared__ float As[16][68];
    __shared__ float Bs[16][68];
    const int z = blockIdx.z;
    A  += (long)z * sA;
    Bm += (long)z * sB;
    C  += (long)z * sC;
    const int m0 = blockIdx.y * 64, n0 = blockIdx.x * 64;
    const int t = threadIdx.x;
    const int tx = t & 15, ty = t >> 4;
    float acc[4][4] = {};
    for (int k0 = 0; k0 < K; k0 += 16) {
        {
            int r = t >> 2, kb = (t & 3) << 2;
            int gm = m0 + r;
            float inv = 1.f;
            if (Ee && gm < M) inv = 1.f / (Ss[gm] + 1e-8f * Ee[gm]);
            const float* ap = A + (long)gm * lda + k0 + kb;
#pragma unroll
            for (int i = 0; i < 4; i++) {
                int gk = k0 + kb + i;
                As[kb + i][r] = (gm < M && gk < K) ? ap[i] * inv : 0.f;
            }
        }
        if (!BT) {
            int nn = t & 63, kq = t >> 6;
#pragma unroll
            for (int i = 0; i < 4; i++) {
                int kk = kq * 4 + i;
                int gk = k0 + kk, gn = n0 + nn;
                Bs[kk][nn] = (gk < K && gn < N) ? Bm[(long)gk * ldb + gn] : 0.f;
            }
        } else {
            int nn = t >> 2, kb = (t & 3) << 2;
            int gn = n0 + nn;
            const float* bp = Bm + (long)gn * ldb + k0 + kb;
#pragma unroll
            for (int i = 0; i < 4; i++) {
                int gk = k0 + kb + i;
                Bs[kb + i][nn] = (gn < N && gk < K) ? bp[i] : 0.f;
            }
        }
        __syncthreads();
#pragma unroll
        for (int kk = 0; kk < 16; kk++) {
            const float4 a4 = *(const float4*)&As[kk][ty * 4];
            const float4 b4 = *(const float4*)&Bs[kk][tx * 4];
            const float a[4] = {a4.x, a4.y, a4.z, a4.w};
            const float b[4] = {b4.x, b4.y, b4.z, b4.w};
#pragma unroll
            for (int i = 0; i < 4; i++)
#pragma unroll
                for (int j = 0; j < 4; j++) acc[i][j] += a[i] * b[j];
        }
        __syncthreads();
    }
#pragma unroll
    for (int i = 0; i < 4; i++) {
        int gm = m0 + ty * 4 + i;
        if (gm >= M) continue;
#pragma unroll
        for (int j = 0; j < 4; j++) {
            int gn = n0 + tx * 4 + j;
            if (gn >= N) continue;
            float v = acc[i][j] * alpha;
            if (bias) v += bias[gn];
            if (EPI == 1) v = 1.f / (1.f + __expf(-v));
            if (EPI == 2) v = fmaxf(v, 0.f);
            C[(long)gm * ldc + gn] = v;
        }
    }
}

// ---------------- QKV GEMM -> hi/lo bf16 buffers (packed 16B stores) -------
__global__ __launch_bounds__(256)
void qkv_split_k(const float* __restrict__ CURp, const float* __restrict__ Wqkv,
                 const float* __restrict__ bias,
                 ushort* __restrict__ QH, ushort* __restrict__ QL,
                 ushort* __restrict__ KH, ushort* __restrict__ KL,
                 ushort* __restrict__ VTH, ushort* __restrict__ VTL)
{
    __shared__ float As[16][132];
    __shared__ float Bs[16][132];
    const int which = blockIdx.x;          // 0=q 1=k 2=v
    const int m0 = blockIdx.y * 128;
    const int z  = blockIdx.z;
    const float* A = CURp + (long)z * Mc * Cc;
    const int n0 = which * 128;
    const int t = threadIdx.x;
    const int tx = t & 15, ty = t >> 4;
    float acc[8][8] = {};

    for (int k0 = 0; k0 < 64; k0 += 16) {
#pragma unroll
        for (int pass = 0; pass < 2; pass++) {
            int e = t + pass * 256;
            int rr = e >> 2, kb = (e & 3) << 2;
            int gm = m0 + rr;
            float4 v = make_float4(0.f, 0.f, 0.f, 0.f);
            if (gm < Mc) v = *(const float4*)(A + (long)gm * 64 + k0 + kb);
            As[kb + 0][rr] = v.x; As[kb + 1][rr] = v.y;
            As[kb + 2][rr] = v.z; As[kb + 3][rr] = v.w;
        }
#pragma unroll
        for (int pass = 0; pass < 2; pass++) {
            int e = t + pass * 256;
            int kk = e >> 5, n4 = (e & 31) << 2;
            float4 v = *(const float4*)(Wqkv + (long)(k0 + kk) * 384 + n0 + n4);
            *(float4*)&Bs[kk][n4] = v;
        }
        __syncthreads();
#pragma unroll
        for (int kk = 0; kk < 16; kk++) {
            float a[8], b[8];
            *(float4*)&a[0] = *(const float4*)&As[kk][ty * 8];
            *(float4*)&a[4] = *(const float4*)&As[kk][ty * 8 + 4];
            *(float4*)&b[0] = *(const float4*)&Bs[kk][tx * 8];
            *(float4*)&b[4] = *(const float4*)&Bs[kk][tx * 8 + 4];
#pragma unroll
            for (int i = 0; i < 8; i++)
#pragma unroll
                for (int j = 0; j < 8; j++) acc[i][j] += a[i] * b[j];
        }
        __syncthreads();
    }

    if (which == 2) {
        if (m0 + ty * 8 < Mc) {
            ushort* vh = VTH + (long)z * ATTc * MPAD;
            ushort* vl = VTL + (long)z * ATTc * MPAD;
#pragma unroll
            for (int j = 0; j < 8; j++) {
                int col = tx * 8 + j;
                short8 h8, l8;
#pragma unroll
                for (int i = 0; i < 8; i++) {
                    float v = fmaxf(acc[i][j] + bias[n0 + col], 0.f);
                    short hs, ls;
                    bsplit(v, hs, ls);
                    h8[i] = hs; l8[i] = ls;
                }
                *(short8*)(vh + (long)col * MPAD + m0 + ty * 8) = h8;
                *(short8*)(vl + (long)col * MPAD + m0 + ty * 8) = l8;
            }
        }
    } else {
        ushort* dh = (which == 0 ? QH : KH) + (long)z * Mc * ATTc;
        ushort* dl = (which == 0 ? QL : KL) + (long)z * Mc * ATTc;
#pragma unroll
        for (int i = 0; i < 8; i++) {
            int row = m0 + ty * 8 + i;
            if (row >= Mc) continue;
            short8 h8, l8;
#pragma unroll
            for (int j = 0; j < 8; j++) {
                float v = acc[i][j] + bias[n0 + tx * 8 + j];
                short hs, ls;
                bsplit(v, hs, ls);
                h8[j] = hs; l8[j] = ls;
            }
            *(short8*)(dh + (long)row * ATTc + tx * 8) = h8;
            *(short8*)(dl + (long)row * ATTc + tx * 8) = l8;
        }
    }
}

// ---- score GEMM + fused no-max softmax numerator: P = exp(s)*adj ----------
// XCD-swizzled 1-D grid, 25 blocks per z. Writes P packed (lo16<<16|hi16)
// uint32 [z][600][600]; atomically accumulates Erow=sum(e), Srow=sum(e*adj).
__global__ __launch_bounds__(256)
void score_k(const ushort* __restrict__ QH, const ushort* __restrict__ QL,
             const ushort* __restrict__ KH, const ushort* __restrict__ KL,
             const float* __restrict__ adj, uint* __restrict__ P,
             float* __restrict__ Erow, float* __restrict__ Srow, float scale)
{
    __shared__ __align__(16) ushort As[2][128][40];
    __shared__ __align__(16) ushort Bs[2][128][40];
    const int bid = blockIdx.x;
    const int xcd = bid & 7, slot = bid >> 3;
    const int z = (slot / 25) * 8 + xcd;
    const int r25 = slot % 25;
    const int m0 = (r25 / 5) * 128, n0 = (r25 % 5) * 128;
    const ushort* Ah = QH + (long)z * Mc * ATTc;
    const ushort* Al = QL + (long)z * Mc * ATTc;
    const ushort* Bh = KH + (long)z * Mc * ATTc;
    const ushort* Bl = KL + (long)z * Mc * ATTc;
    uint* Pz = P + (long)z * Mc * Mc;
    const int t = threadIdx.x;
    const int lane = t & 63, w = t >> 6;
    const int wm = (w >> 1) * 64, wn = (w & 1) * 64;
    const int lm = lane & 15, lq = lane >> 4;

    f32x4 acc[4][4];
#pragma unroll
    for (int i = 0; i < 4; i++)
#pragma unroll
        for (int j = 0; j < 4; j++)
#pragma unroll
            for (int r = 0; r < 4; r++) acc[i][j][r] = 0.f;

    for (int k0 = 0; k0 < ATTc; k0 += 32) {
        __syncthreads();
#pragma unroll
        for (int p = 0; p < 2; p++) {
            int e = t + p * 256;
            int row = e >> 2, ks = (e & 3) << 3;
            int gk = k0 + ks;
            {
                int gm = m0 + row;
                short8 vh, vl;
#pragma unroll
                for (int q = 0; q < 8; q++) { vh[q] = 0; vl[q] = 0; }
                if (gm < Mc) {
                    vh = *(const short8*)(Ah + (long)gm * ATTc + gk);
                    vl = *(const short8*)(Al + (long)gm * ATTc + gk);
                }
                *(short8*)&As[0][row][ks] = vh;
                *(short8*)&As[1][row][ks] = vl;
            }
            {
                int gn = n0 + row;
                short8 vh, vl;
#pragma unroll
                for (int q = 0; q < 8; q++) { vh[q] = 0; vl[q] = 0; }
                if (gn < Mc) {
                    vh = *(const short8*)(Bh + (long)gn * ATTc + gk);
                    vl = *(const short8*)(Bl + (long)gn * ATTc + gk);
                }
                *(short8*)&Bs[0][row][ks] = vh;
                *(short8*)&Bs[1][row][ks] = vl;
            }
        }
        __syncthreads();

        short8 af[4][2], bf[4][2];
#pragma unroll
        for (int i = 0; i < 4; i++) {
            af[i][0] = *(const short8*)&As[0][wm + i * 16 + lm][lq * 8];
            af[i][1] = *(const short8*)&As[1][wm + i * 16 + lm][lq * 8];
        }
#pragma unroll
        for (int j = 0; j < 4; j++) {
            bf[j][0] = *(const short8*)&Bs[0][wn + j * 16 + lm][lq * 8];
            bf[j][1] = *(const short8*)&Bs[1][wn + j * 16 + lm][lq * 8];
        }
#pragma unroll
        for (int i = 0; i < 4; i++)
#pragma unroll
            for (int j = 0; j < 4; j++) {
                acc[i][j] = __builtin_amdgcn_mfma_f32_16x16x32_bf16(
                    af[i][0], bf[j][0], acc[i][j], 0, 0, 0);
                acc[i][j] = __builtin_amdgcn_mfma_f32_16x16x32_bf16(
                    af[i][0], bf[j][1], acc[i][j], 0, 0, 0);
                acc[i][j] = __builtin_amdgcn_mfma_f32_16x16x32_bf16(
                    af[i][1], bf[j][0], acc[i][j], 0, 0, 0);
            }
    }
    // ---- epilogue: p = exp(s*scale)*adj, packed store + row-sum atomics ----
#pragma unroll
    for (int i = 0; i < 4; i++) {
#pragma unroll
        for (int r = 0; r < 4; r++) {
            int row = m0 + wm + i * 16 + lq * 4 + r;
            bool rok = row < Mc;
            float Ep = 0.f, Sp = 0.f;
#pragma unroll
            for (int j = 0; j < 4; j++) {
                int col = n0 + wn + j * 16 + lm;
                bool ok = rok && (col < Mc);
                float e = ok ? __expf(acc[i][j][r] * scale) : 0.f;
                float a = ok ? adj[(long)row * Mc + col] : 0.f;
                float p = e * a;
                Ep += e; Sp += p;
                if (ok) {
                    short hs, ls;
                    bsplit(p, hs, ls);
                    Pz[(long)row * Mc + col] =
                        ((uint)(ushort)ls << 16) | (uint)(ushort)hs;
                }
            }
#pragma unroll
            for (int mk = 1; mk <= 8; mk <<= 1) {
                Ep += __shfl_xor(Ep, mk, 64);
                Sp += __shfl_xor(Sp, mk, 64);
            }
            if (lm == 0 && rok) {
                atomicAdd(&Erow[(long)z * Mc + row], Ep);
                atomicAdd(&Srow[(long)z * Mc + row], Sp);
            }
        }
    }
}

// ---- AV GEMM: numerator = P @ V, A from packed uint P, B = V^T hi/lo ------
// XCD-swizzled 1-D grid, 5 blocks per z.
__global__ __launch_bounds__(256)
void av_k(const uint* __restrict__ P, const ushort* __restrict__ VTH,
          const ushort* __restrict__ VTL, float* __restrict__ C)
{
    __shared__ __align__(16) ushort As[2][128][40];
    __shared__ __align__(16) ushort Bs[2][128][40];
    const int bid = blockIdx.x;
    const int xcd = bid & 7, slot = bid >> 3;
    const int z = (slot / 5) * 8 + xcd;
    const int m0 = (slot % 5) * 128;
    const uint* Pz = P + (long)z * Mc * Mc;
    const ushort* Bh = VTH + (long)z * ATTc * MPAD;
    const ushort* Bl = VTL + (long)z * ATTc * MPAD;
    float* Cz = C + (long)z * Mc * ATTc;
    const int t = threadIdx.x;
    const int lane = t & 63, w = t >> 6;
    const int wm = (w >> 1) * 64, wn = (w & 1) * 64;
    const int lm = lane & 15, lq = lane >> 4;

    f32x4 acc[4][4];
#pragma unroll
    for (int i = 0; i < 4; i++)
#pragma unroll
        for (int j = 0; j < 4; j++)
#pragma unroll
            for (int r = 0; r < 4; r++) acc[i][j][r] = 0.f;

    for (int k0 = 0; k0 < Mc; k0 += 32) {
        __syncthreads();
#pragma unroll
        for (int p = 0; p < 2; p++) {
            int e = t + p * 256;
            int row = e >> 2, ks = (e & 3) << 3;
            int gk = k0 + ks;
            bool kin = gk < Mc;          // Mc % 8 == 0 -> seg granularity
            {
                int gm = m0 + row;
                short8 vh, vl;
#pragma unroll
                for (int q = 0; q < 8; q++) { vh[q] = 0; vl[q] = 0; }
                if (gm < Mc && kin) {
                    const uint4 u0 = *(const uint4*)(Pz + (long)gm * Mc + gk);
                    const uint4 u1 = *(const uint4*)(Pz + (long)gm * Mc + gk + 4);
#pragma unroll
                    for (int q = 0; q < 4; q++) {
                        uint u = ((const uint*)&u0)[q];
                        vh[q] = (short)(u & 0xffff);
                        vl[q] = (short)(u >> 16);
                    }
#pragma unroll
                    for (int q = 0; q < 4; q++) {
                        uint u = ((const uint*)&u1)[q];
                        vh[4 + q] = (short)(u & 0xffff);
                        vl[4 + q] = (short)(u >> 16);
                    }
                }
                *(short8*)&As[0][row][ks] = vh;
                *(short8*)&As[1][row][ks] = vl;
            }
            {
                short8 vh, vl;
#pragma unroll
                for (int q = 0; q < 8; q++) { vh[q] = 0; vl[q] = 0; }
                if (kin) {   // B rows: 128 att cols, all valid
                    vh = *(const short8*)(Bh + (long)row * MPAD + gk);
                    vl = *(const short8*)(Bl + (long)row * MPAD + gk);
                }
                *(short8*)&Bs[0][row][ks] = vh;
                *(short8*)&Bs[1][row][ks] = vl;
            }
        }
        __syncthreads();

        short8 af[4][2], bf[4][2];
#pragma unroll
        for (int i = 0; i < 4; i++) {
            af[i][0] = *(const short8*)&As[0][wm + i * 16 + lm][lq * 8];
            af[i][1] = *(const short8*)&As[1][wm + i * 16 + lm][lq * 8];
        }
#pragma unroll
        for (int j = 0; j < 4; j++) {
            bf[j][0] = *(const short8*)&Bs[0][wn + j * 16 + lm][lq * 8];
            bf[j][1] = *(const short8*)&Bs[1][wn + j * 16 + lm][lq * 8];
        }
#pragma unroll
        for (int i = 0; i < 4; i++)
#pragma unroll
            for (int j = 0; j < 4; j++) {
                acc[i][j] = __builtin_amdgcn_mfma_f32_16x16x32_bf16(
                    af[i][0], bf[j][0], acc[i][j], 0, 0, 0);
                acc[i][j] = __builtin_amdgcn_mfma_f32_16x16x32_bf16(
                    af[i][0], bf[j][1], acc[i][j], 0, 0, 0);
                acc[i][j] = __builtin_amdgcn_mfma_f32_16x16x32_bf16(
                    af[i][1], bf[j][0], acc[i][j], 0, 0, 0);
            }
    }
#pragma unroll
    for (int i = 0; i < 4; i++) {
        int gmb = m0 + wm + i * 16 + lq * 4;
#pragma unroll
        for (int j = 0; j < 4; j++) {
            int gn = wn + j * 16 + lm;
#pragma unroll
            for (int r = 0; r < 4; r++) {
                int gm = gmb + r;
                if (gm < Mc) Cz[(long)gm * ATTc + gn] = acc[i][j][r];
            }
        }
    }
}

// ---------------- running max of middle-window slice [2N:3N] ---------------
__global__ __launch_bounds__(256)
void cand_update_k(const float* __restrict__ cur, float* __restrict__ cand,
                   int bw0, long total, int first)
{
    long idx = (long)blockIdx.x * 256 + threadIdx.x;
    if (idx >= total) return;
    int c = (int)(idx & 63);
    long r = idx >> 6;
    int n = (int)(r % Nc);
    int i = (int)(r / Nc);
    long bw = bw0 + i;
    float v = cur[((bw * Mc) + 2 * Nc + n) * Cc + c];
    long o = ((bw * Nc) + n) * Cc + c;
    cand[o] = first ? v : fmaxf(cand[o], v);
}

// ---------------- output layer ----------------
__global__ __launch_bounds__(128)
void output_k(const float* __restrict__ h2, const float* __restrict__ Wo,
              const float* __restrict__ bo, float* __restrict__ out)
{
    __shared__ float ds[512];
    int row = blockIdx.x;
    int b = row / Nc, n = row % Nc;
    int t = threadIdx.x;
    for (int e = t; e < 512; e += 128) {
        int tt = e >> 6, c = e & 63;
        ds[e] = h2[(((long)b * 8 + tt) * Nc + n) * Cc + c];
    }
    __syncthreads();
    float acc = bo[t];
    for (int e = 0; e < 512; e++) acc += ds[e] * Wo[e * OUTFc + t];
    acc = fmaxf(acc, 0.f);
    for (int p = 0; p < PREDc; p++)
        out[(((long)b * PREDc + p) * Nc + n) * (long)OUTFc + t] = acc;
}

extern "C" void kernel_launch(void* const* d_in, const int* in_sizes, int n_in,
                              void* d_out, int out_size, void* d_ws, size_t ws_size,
                              hipStream_t stream)
{
    (void)in_sizes; (void)n_in; (void)out_size; (void)ws_size;
    const float* x     = (const float*)d_in[0];
    const float* Wqkv  = (const float*)d_in[4];
    const float* bqkv  = (const float*)d_in[5];
    const float* Wlin  = (const float*)d_in[6];
    const float* blin  = (const float*)d_in[7];
    const float* Wa    = (const float*)d_in[8];
    const float* Wb    = (const float*)d_in[9];
    const float* temb0 = (const float*)d_in[13];
    const float* temb1 = (const float*)d_in[14];
    const float* semb  = (const float*)d_in[15];
    const float* Wo    = (const float*)d_in[16];
    const float* bo    = (const float*)d_in[17];
    float* out = (float*)d_out;

    // ---- workspace (float offsets), ~105 MB ----
    float* ws   = (float*)d_ws;
    float* CUR  = ws;                                  // 1,536,000
    float* NA   = CUR + (long)MAXBW * Mc * Cc;
    float* NB   = NA + Mc * Cc;
    float* ADJ  = NB + Mc * Cc;                        // 360,000
    float* CAND = ADJ + (long)Mc * Mc;                 // 512,000
    uint*  P    = (uint*)(CAND + (long)MAXBW * Nc * Cc); // 14,400,000 u32
    float* QHf  = (float*)(P + (long)MAXBW * Mc * Mc);
    const long QSZ = (long)MAXBW * Mc * ATTc / 2;      // in floats
    float* QLf  = QHf + QSZ;
    float* KHf  = QLf + QSZ;
    float* KLf  = KHf + QSZ;
    float* VTHf = KLf + QSZ;
    float* VTLf = VTHf + (long)MAXBW * ATTc * MPAD / 2;
    float* Erow = VTLf + (long)MAXBW * ATTc * MPAD / 2; // 24,000
    float* Srow = Erow + (long)MAXBW * Mc;              // 24,000
    float* ATTB = QHf;                                 // alias: Q dead after scores

    ushort* QH  = (ushort*)QHf;
    ushort* QL  = (ushort*)QLf;
    ushort* KH  = (ushort*)KHf;
    ushort* KL  = (ushort*)KLf;
    ushort* VTH = (ushort*)VTHf;
    ushort* VTL = (ushort*)VTLf;

    const float inv_sqrt_att = 0.08838834764831845f;   // 1/sqrt(128)

    for (int layer = 0; layer < 2; layer++) {
        int Tin = layer ? 10 : 12;
        int nw  = Tin - 2;
        int BW  = Bc * nw;                             // 40 then 32
        int Mtot = BW * Mc;
        const float* src  = layer ? CAND : x;
        const float* temb = layer ? temb1 : temb0;

        long etotal = (long)BW * Mc * Cc;
        embed_window_k<<<dim3((unsigned)((etotal + 255) / 256)), dim3(256), 0, stream>>>(
            src, temb, semb, CUR, Tin, nw, etotal);

        for (int it = 0; it < 3; it++) {
            // adjacency: mean -> NA/NB -> sigmoid(NA NB^T / 8)
            mean_nab_k<<<dim3(38), dim3(256), 0, stream>>>(CUR, Wa, Wb, NA, NB, BW);
            gemm_k<true, 1><<<dim3(10, 10, 1), dim3(256), 0, stream>>>(
                NA, NB, nullptr, ADJ, nullptr, nullptr,
                Mc, Mc, Cc, Cc, Cc, Mc, 0, 0, 0, 0.125f);

            // QKV projection + hi/lo split
            qkv_split_k<<<dim3(3, 5, BW), dim3(256), 0, stream>>>(
                CUR, Wqkv, bqkv, QH, QL, KH, KL, VTH, VTL);

            // zero row-sum accumulators, then fused score+exp*adj
            hipMemsetAsync(Erow, 0, (size_t)2 * MAXBW * Mc * sizeof(float), stream);
            score_k<<<dim3(BW * 25), dim3(256), 0, stream>>>(
                QH, QL, KH, KL, ADJ, P, Erow, Srow, inv_sqrt_att);

            // numerator = P @ V
            av_k<<<dim3(BW * 5), dim3(256), 0, stream>>>(P, VTH, VTL, ATTB);

            // cur = diag(1/(S+1e-8E)) ATTB @ Wlin + blin
            gemm_k<false, 0><<<dim3(1, (Mtot + 63) / 64, 1), dim3(256), 0, stream>>>(
                ATTB, Wlin, blin, CUR, Erow, Srow,
                Mtot, Cc, ATTc, ATTc, Cc, Cc, 0, 0, 0, 1.f);

            // running max of middle window
            long mtot = (long)BW * Nc * Cc;
            cand_update_k<<<dim3((unsigned)((mtot + 255) / 256)), dim3(256), 0, stream>>>(
                CUR, CAND, 0, mtot, it == 0 ? 1 : 0);
        }
    }
    output_k<<<dim3(Bc * Nc), dim3(128), 0, stream>>>(CAND, Wo, bo, out);
}

// Round 11
// 1025.705 us; speedup vs baseline: 5.6179x; 1.1397x over previous
//
#include <hip/hip_runtime.h>
#include <hip/hip_bf16.h>
#include <math.h>

constexpr int Bc   = 4;
constexpr int Nc   = 200;
constexpr int Cc   = 64;
constexpr int Mc   = 600;    // 3*N
constexpr int ATTc = 128;
constexpr int OUTFc = 128;
constexpr int PREDc = 12;
constexpr int MAXBW = 40;
constexpr int MPAD  = 640;   // padded V^T leading dim

typedef short short8 __attribute__((ext_vector_type(8)));
typedef float f32x4  __attribute__((ext_vector_type(4)));

static __device__ __forceinline__ void bsplit(float v, short& h, short& l) {
    __hip_bfloat16 hb = __float2bfloat16(v);
    float hf = __bfloat162float(hb);
    __hip_bfloat16 lb = __float2bfloat16(v - hf);
    h = *(short*)&hb; l = *(short*)&lb;
}

// ---------------- embed + sliding window ----------------
__global__ __launch_bounds__(256)
void embed_window_k(const float* __restrict__ src, const float* __restrict__ temb,
                    const float* __restrict__ semb, float* __restrict__ dst,
                    int Tin, int nw, long total)
{
    long idx = (long)blockIdx.x * 256 + threadIdx.x;
    if (idx >= total) return;
    int c = (int)(idx & 63);
    long r = idx >> 6;
    int n = (int)(r % Nc); r /= Nc;
    int j = (int)(r % 3);  r /= 3;
    int w = (int)(r % nw);
    int b = (int)(r / nw);
    int t = w + j;
    dst[idx] = src[(((long)b * Tin + t) * Nc + n) * Cc + c]
             + temb[t * Cc + c] + semb[n * Cc + c];
}

// ---------------- fused node-mean + NA/NB projection (16-row blocks) -------
__global__ __launch_bounds__(256)
void mean_nab_k(const float* __restrict__ cur, const float* __restrict__ Wa,
                const float* __restrict__ Wb, float* __restrict__ NA,
                float* __restrict__ NB, int BW)
{
    __shared__ float Ns[64][17];   // [k][row]
    __shared__ float Ws[64][132];  // [k][ Wa | Wb ]
    const int m0 = blockIdx.x * 16;
    const int t = threadIdx.x;
    for (int e = t; e < 1024; e += 256) {
        int r = e >> 4, c4 = (e & 15) << 2;
        *(float4*)&Ws[r][c4]      = *(const float4*)&Wa[r * 64 + c4];
        *(float4*)&Ws[r][64 + c4] = *(const float4*)&Wb[r * 64 + c4];
    }
    {
        int row = t >> 4, c4 = (t & 15) << 2;
        int gm = m0 + row;
        float4 sv = make_float4(0.f, 0.f, 0.f, 0.f);
        if (gm < Mc) {
            for (int bw = 0; bw < BW; bw++) {
                const float4 v = *(const float4*)&cur[((long)bw * Mc + gm) * Cc + c4];
                sv.x += v.x; sv.y += v.y; sv.z += v.z; sv.w += v.w;
            }
        }
        const float inv = 1.f / BW;
        Ns[c4 + 0][row] = sv.x * inv; Ns[c4 + 1][row] = sv.y * inv;
        Ns[c4 + 2][row] = sv.z * inv; Ns[c4 + 3][row] = sv.w * inv;
    }
    __syncthreads();
    const int row = t >> 4, c8 = (t & 15) * 8;
    float acc[8] = {};
    for (int k = 0; k < 64; k++) {
        float a = Ns[k][row];
        float b[8];
        *(float4*)&b[0] = *(const float4*)&Ws[k][c8];
        *(float4*)&b[4] = *(const float4*)&Ws[k][c8 + 4];
#pragma unroll
        for (int j = 0; j < 8; j++) acc[j] += a * b[j];
    }
    int gm = m0 + row;
    if (gm < Mc) {
#pragma unroll
        for (int j = 0; j < 8; j++) {
            int col = c8 + j;
            if (col < 64) NA[gm * 64 + col] = acc[j];
            else          NB[gm * 64 + col - 64] = acc[j];
        }
    }
}

// ---------------- 64-tile fp32 GEMM (adj, Wlin) ----------------
template<bool BT, int EPI>
__global__ __launch_bounds__(256)
void gemm_k(const float* __restrict__ A, const float* __restrict__ Bm,
            const float* __restrict__ bias, float* __restrict__ C,
            int M, int N, int K, int lda, int ldb, int ldc,
            long sA, long sB, long sC, float alpha)
{
    __shared__ float As[16][68];
    __shared__ float Bs[16][68];
    const int z = blockIdx.z;
    A  += (long)z * sA;
    Bm += (long)z * sB;
    C  += (long)z * sC;
    const int m0 = blockIdx.y * 64, n0 = blockIdx.x * 64;
    const int t = threadIdx.x;
    const int tx = t & 15, ty = t >> 4;
    float acc[4][4] = {};
    for (int k0 = 0; k0 < K; k0 += 16) {
        {
            int r = t >> 2, kb = (t & 3) << 2;
            int gm = m0 + r;
            const float* ap = A + (long)gm * lda + k0 + kb;
#pragma unroll
            for (int i = 0; i < 4; i++) {
                int gk = k0 + kb + i;
                As[kb + i][r] = (gm < M && gk < K) ? ap[i] : 0.f;
            }
        }
        if (!BT) {
            int nn = t & 63, kq = t >> 6;
#pragma unroll
            for (int i = 0; i < 4; i++) {
                int kk = kq * 4 + i;
                int gk = k0 + kk, gn = n0 + nn;
                Bs[kk][nn] = (gk < K && gn < N) ? Bm[(long)gk * ldb + gn] : 0.f;
            }
        } else {
            int nn = t >> 2, kb = (t & 3) << 2;
            int gn = n0 + nn;
            const float* bp = Bm + (long)gn * ldb + k0 + kb;
#pragma unroll
            for (int i = 0; i < 4; i++) {
                int gk = k0 + kb + i;
                Bs[kb + i][nn] = (gn < N && gk < K) ? bp[i] : 0.f;
            }
        }
        __syncthreads();
#pragma unroll
        for (int kk = 0; kk < 16; kk++) {
            const float4 a4 = *(const float4*)&As[kk][ty * 4];
            const float4 b4 = *(const float4*)&Bs[kk][tx * 4];
            const float a[4] = {a4.x, a4.y, a4.z, a4.w};
            const float b[4] = {b4.x, b4.y, b4.z, b4.w};
#pragma unroll
            for (int i = 0; i < 4; i++)
#pragma unroll
                for (int j = 0; j < 4; j++) acc[i][j] += a[i] * b[j];
        }
        __syncthreads();
    }
#pragma unroll
    for (int i = 0; i < 4; i++) {
        int gm = m0 + ty * 4 + i;
        if (gm >= M) continue;
#pragma unroll
        for (int j = 0; j < 4; j++) {
            int gn = n0 + tx * 4 + j;
            if (gn >= N) continue;
            float v = acc[i][j] * alpha;
            if (bias) v += bias[gn];
            if (EPI == 1) v = 1.f / (1.f + __expf(-v));
            if (EPI == 2) v = fmaxf(v, 0.f);
            C[(long)gm * ldc + gn] = v;
        }
    }
}

// ---------------- QKV GEMM -> hi/lo bf16 buffers (packed 16B stores) -------
__global__ __launch_bounds__(256)
void qkv_split_k(const float* __restrict__ CURp, const float* __restrict__ Wqkv,
                 const float* __restrict__ bias,
                 ushort* __restrict__ QH, ushort* __restrict__ QL,
                 ushort* __restrict__ KH, ushort* __restrict__ KL,
                 ushort* __restrict__ VTH, ushort* __restrict__ VTL)
{
    __shared__ float As[16][132];
    __shared__ float Bs[16][132];
    const int which = blockIdx.x;          // 0=q 1=k 2=v
    const int m0 = blockIdx.y * 128;
    const int z  = blockIdx.z;
    const float* A = CURp + (long)z * Mc * Cc;
    const int n0 = which * 128;
    const int t = threadIdx.x;
    const int tx = t & 15, ty = t >> 4;
    float acc[8][8] = {};

    for (int k0 = 0; k0 < 64; k0 += 16) {
#pragma unroll
        for (int pass = 0; pass < 2; pass++) {
            int e = t + pass * 256;
            int rr = e >> 2, kb = (e & 3) << 2;
            int gm = m0 + rr;
            float4 v = make_float4(0.f, 0.f, 0.f, 0.f);
            if (gm < Mc) v = *(const float4*)(A + (long)gm * 64 + k0 + kb);
            As[kb + 0][rr] = v.x; As[kb + 1][rr] = v.y;
            As[kb + 2][rr] = v.z; As[kb + 3][rr] = v.w;
        }
#pragma unroll
        for (int pass = 0; pass < 2; pass++) {
            int e = t + pass * 256;
            int kk = e >> 5, n4 = (e & 31) << 2;
            float4 v = *(const float4*)(Wqkv + (long)(k0 + kk) * 384 + n0 + n4);
            *(float4*)&Bs[kk][n4] = v;
        }
        __syncthreads();
#pragma unroll
        for (int kk = 0; kk < 16; kk++) {
            float a[8], b[8];
            *(float4*)&a[0] = *(const float4*)&As[kk][ty * 8];
            *(float4*)&a[4] = *(const float4*)&As[kk][ty * 8 + 4];
            *(float4*)&b[0] = *(const float4*)&Bs[kk][tx * 8];
            *(float4*)&b[4] = *(const float4*)&Bs[kk][tx * 8 + 4];
#pragma unroll
            for (int i = 0; i < 8; i++)
#pragma unroll
                for (int j = 0; j < 8; j++) acc[i][j] += a[i] * b[j];
        }
        __syncthreads();
    }

    if (which == 2) {
        if (m0 + ty * 8 < Mc) {
            ushort* vh = VTH + (long)z * ATTc * MPAD;
            ushort* vl = VTL + (long)z * ATTc * MPAD;
#pragma unroll
            for (int j = 0; j < 8; j++) {
                int col = tx * 8 + j;
                short8 h8, l8;
#pragma unroll
                for (int i = 0; i < 8; i++) {
                    float v = fmaxf(acc[i][j] + bias[n0 + col], 0.f);
                    short hs, ls;
                    bsplit(v, hs, ls);
                    h8[i] = hs; l8[i] = ls;
                }
                *(short8*)(vh + (long)col * MPAD + m0 + ty * 8) = h8;
                *(short8*)(vl + (long)col * MPAD + m0 + ty * 8) = l8;
            }
        }
    } else {
        ushort* dh = (which == 0 ? QH : KH) + (long)z * Mc * ATTc;
        ushort* dl = (which == 0 ? QL : KL) + (long)z * Mc * ATTc;
#pragma unroll
        for (int i = 0; i < 8; i++) {
            int row = m0 + ty * 8 + i;
            if (row >= Mc) continue;
            short8 h8, l8;
#pragma unroll
            for (int j = 0; j < 8; j++) {
                float v = acc[i][j] + bias[n0 + tx * 8 + j];
                short hs, ls;
                bsplit(v, hs, ls);
                h8[j] = hs; l8[j] = ls;
            }
            *(short8*)(dh + (long)row * ATTc + tx * 8) = h8;
            *(short8*)(dl + (long)row * ATTc + tx * 8) = l8;
        }
    }
}

// ---- fused attention: S = QK^T -> P = exp(s)*adj (no-max, exact) -> PV ----
// Grid BW*10, XCD-swizzled (10 blocks per z on one XCD). Block = 64 q-rows,
// 4 waves x 16 rows. K/V staged cooperatively in a shared 64-k LDS buffer;
// P lives in wave-private LDS (never touches HBM). Per-row E=sum(e),
// S=sum(e*adj) accumulate in registers; O scaled by 1/(S+1e-8E) on store.
__global__ __launch_bounds__(256)
void attn_k(const ushort* __restrict__ QH, const ushort* __restrict__ QL,
            const ushort* __restrict__ KH, const ushort* __restrict__ KL,
            const ushort* __restrict__ VTH, const ushort* __restrict__ VTL,
            const float* __restrict__ adj, float* __restrict__ O, float scale)
{
    __shared__ __align__(16) ushort SB[2][128][72];   // K or V stage (64 k)
    __shared__ __align__(16) ushort PH[4][16][152];   // wave-private P hi
    __shared__ __align__(16) ushort PL[4][16][152];   //                lo
    const int bid = blockIdx.x;
    const int xcd = bid & 7, slot = bid >> 3;
    const int z = (slot / 10) * 8 + xcd;
    const int m0 = (slot % 10) * 64;
    const int t = threadIdx.x;
    const int lane = t & 63, w = t >> 6;
    const int lm = lane & 15, lq = lane >> 4;
    const int qrow0 = m0 + w * 16;

    const ushort* Qhz = QH + (long)z * Mc * ATTc;
    const ushort* Qlz = QL + (long)z * Mc * ATTc;
    const ushort* Khz = KH + (long)z * Mc * ATTc;
    const ushort* Klz = KL + (long)z * Mc * ATTc;
    const ushort* Vhz = VTH + (long)z * ATTc * MPAD;
    const ushort* Vlz = VTL + (long)z * ATTc * MPAD;

    // Q fragments for this wave's 16 rows, full 128-att, in registers.
    short8 qh[4], ql[4];
    {
        int qr = qrow0 + lm;
        if (qr < Mc) {
            const ushort* qp = Qhz + (long)qr * ATTc;
            const ushort* qp2 = Qlz + (long)qr * ATTc;
#pragma unroll
            for (int ks = 0; ks < 4; ks++) {
                qh[ks] = *(const short8*)(qp + ks * 32 + lq * 8);
                ql[ks] = *(const short8*)(qp2 + ks * 32 + lq * 8);
            }
        } else {
#pragma unroll
            for (int ks = 0; ks < 4; ks++)
#pragma unroll
                for (int q = 0; q < 8; q++) { qh[ks][q] = 0; ql[ks][q] = 0; }
        }
    }

    f32x4 oacc[8];
#pragma unroll
    for (int j = 0; j < 8; j++)
#pragma unroll
        for (int r = 0; r < 4; r++) oacc[j][r] = 0.f;
    float Er[4] = {}, Sr[4] = {};

    for (int kc = 0; kc < 640; kc += 128) {       // 5 key chunks
        f32x4 sacc[8];
#pragma unroll
        for (int j = 0; j < 8; j++)
#pragma unroll
            for (int r = 0; r < 4; r++) sacc[j][r] = 0.f;

        // ---- QK phase: 2 staging rounds of 64 att ----
#pragma unroll
        for (int g = 0; g < 2; g++) {
            __syncthreads();
#pragma unroll
            for (int p = 0; p < 4; p++) {
                int e = t + p * 256;              // 0..1023
                int row = e >> 3, ks = (e & 7) << 3;
                int key = kc + row;
                short8 vh, vl;
#pragma unroll
                for (int q = 0; q < 8; q++) { vh[q] = 0; vl[q] = 0; }
                if (key < Mc) {
                    vh = *(const short8*)(Khz + (long)key * ATTc + g * 64 + ks);
                    vl = *(const short8*)(Klz + (long)key * ATTc + g * 64 + ks);
                }
                *(short8*)&SB[0][row][ks] = vh;
                *(short8*)&SB[1][row][ks] = vl;
            }
            __syncthreads();
#pragma unroll
            for (int kk = 0; kk < 2; kk++) {
                int ks = g * 2 + kk;
#pragma unroll
                for (int j = 0; j < 8; j++) {
                    short8 bh = *(const short8*)&SB[0][j * 16 + lm][kk * 32 + lq * 8];
                    short8 bl = *(const short8*)&SB[1][j * 16 + lm][kk * 32 + lq * 8];
                    sacc[j] = __builtin_amdgcn_mfma_f32_16x16x32_bf16(qh[ks], bh, sacc[j], 0, 0, 0);
                    sacc[j] = __builtin_amdgcn_mfma_f32_16x16x32_bf16(qh[ks], bl, sacc[j], 0, 0, 0);
                    sacc[j] = __builtin_amdgcn_mfma_f32_16x16x32_bf16(ql[ks], bh, sacc[j], 0, 0, 0);
                }
            }
        }

        // ---- epilogue: P = exp(s*scale)*adj -> wave-private LDS ----
#pragma unroll
        for (int j = 0; j < 8; j++) {
            int col = kc + j * 16 + lm;
            bool cok = col < Mc;
#pragma unroll
            for (int r = 0; r < 4; r++) {
                int row = qrow0 + lq * 4 + r;
                float e = cok ? __expf(sacc[j][r] * scale) : 0.f;
                float a = (cok && row < Mc) ? adj[(long)row * Mc + col] : 0.f;
                float p = e * a;
                Er[r] += e; Sr[r] += p;
                short hs, ls;
                bsplit(p, hs, ls);
                PH[w][lq * 4 + r][j * 16 + lm] = (ushort)hs;
                PL[w][lq * 4 + r][j * 16 + lm] = (ushort)ls;
            }
        }

        // ---- PV phase: 2 staging rounds of 64 keys ----
#pragma unroll
        for (int g = 0; g < 2; g++) {
            __syncthreads();
#pragma unroll
            for (int p = 0; p < 4; p++) {
                int e = t + p * 256;
                int att = e >> 3, ks = (e & 7) << 3;
                int key = kc + g * 64 + ks;       // < 640 = MPAD, always in buf
                short8 vh = *(const short8*)(Vhz + (long)att * MPAD + key);
                short8 vl = *(const short8*)(Vlz + (long)att * MPAD + key);
                *(short8*)&SB[0][att][ks] = vh;
                *(short8*)&SB[1][att][ks] = vl;
            }
            __syncthreads();
#pragma unroll
            for (int kk = 0; kk < 2; kk++) {
                short8 ph = *(const short8*)&PH[w][lm][g * 64 + kk * 32 + lq * 8];
                short8 pl = *(const short8*)&PL[w][lm][g * 64 + kk * 32 + lq * 8];
#pragma unroll
                for (int j = 0; j < 8; j++) {
                    short8 vh = *(const short8*)&SB[0][j * 16 + lm][kk * 32 + lq * 8];
                    short8 vl = *(const short8*)&SB[1][j * 16 + lm][kk * 32 + lq * 8];
                    oacc[j] = __builtin_amdgcn_mfma_f32_16x16x32_bf16(ph, vh, oacc[j], 0, 0, 0);
                    oacc[j] = __builtin_amdgcn_mfma_f32_16x16x32_bf16(ph, vl, oacc[j], 0, 0, 0);
                    oacc[j] = __builtin_amdgcn_mfma_f32_16x16x32_bf16(pl, vh, oacc[j], 0, 0, 0);
                }
            }
        }
    }

    // ---- row sums across the 16 lm lanes, then scaled store ----
#pragma unroll
    for (int mk = 1; mk <= 8; mk <<= 1)
#pragma unroll
        for (int r = 0; r < 4; r++) {
            Er[r] += __shfl_xor(Er[r], mk, 64);
            Sr[r] += __shfl_xor(Sr[r], mk, 64);
        }
    float inv[4];
#pragma unroll
    for (int r = 0; r < 4; r++) inv[r] = 1.f / (Sr[r] + 1e-8f * Er[r]);
    float* Oz = O + (long)z * Mc * ATTc;
#pragma unroll
    for (int j = 0; j < 8; j++)
#pragma unroll
        for (int r = 0; r < 4; r++) {
            int row = qrow0 + lq * 4 + r;
            if (row < Mc)
                Oz[(long)row * ATTc + j * 16 + lm] = oacc[j][r] * inv[r];
        }
}

// ---------------- running max of middle-window slice [2N:3N] ---------------
__global__ __launch_bounds__(256)
void cand_update_k(const float* __restrict__ cur, float* __restrict__ cand,
                   int bw0, long total, int first)
{
    long idx = (long)blockIdx.x * 256 + threadIdx.x;
    if (idx >= total) return;
    int c = (int)(idx & 63);
    long r = idx >> 6;
    int n = (int)(r % Nc);
    int i = (int)(r / Nc);
    long bw = bw0 + i;
    float v = cur[((bw * Mc) + 2 * Nc + n) * Cc + c];
    long o = ((bw * Nc) + n) * Cc + c;
    cand[o] = first ? v : fmaxf(cand[o], v);
}

// ---------------- output layer ----------------
__global__ __launch_bounds__(128)
void output_k(const float* __restrict__ h2, const float* __restrict__ Wo,
              const float* __restrict__ bo, float* __restrict__ out)
{
    __shared__ float ds[512];
    int row = blockIdx.x;
    int b = row / Nc, n = row % Nc;
    int t = threadIdx.x;
    for (int e = t; e < 512; e += 128) {
        int tt = e >> 6, c = e & 63;
        ds[e] = h2[(((long)b * 8 + tt) * Nc + n) * Cc + c];
    }
    __syncthreads();
    float acc = bo[t];
    for (int e = 0; e < 512; e++) acc += ds[e] * Wo[e * OUTFc + t];
    acc = fmaxf(acc, 0.f);
    for (int p = 0; p < PREDc; p++)
        out[(((long)b * PREDc + p) * Nc + n) * (long)OUTFc + t] = acc;
}

extern "C" void kernel_launch(void* const* d_in, const int* in_sizes, int n_in,
                              void* d_out, int out_size, void* d_ws, size_t ws_size,
                              hipStream_t stream)
{
    (void)in_sizes; (void)n_in; (void)out_size; (void)ws_size;
    const float* x     = (const float*)d_in[0];
    const float* Wqkv  = (const float*)d_in[4];
    const float* bqkv  = (const float*)d_in[5];
    const float* Wlin  = (const float*)d_in[6];
    const float* blin  = (const float*)d_in[7];
    const float* Wa    = (const float*)d_in[8];
    const float* Wb    = (const float*)d_in[9];
    const float* temb0 = (const float*)d_in[13];
    const float* temb1 = (const float*)d_in[14];
    const float* semb  = (const float*)d_in[15];
    const float* Wo    = (const float*)d_in[16];
    const float* bo    = (const float*)d_in[17];
    float* out = (float*)d_out;

    // ---- workspace (float offsets), ~60 MB ----
    float* ws   = (float*)d_ws;
    float* CUR  = ws;                                  // 1,536,000
    float* NA   = CUR + (long)MAXBW * Mc * Cc;
    float* NB   = NA + Mc * Cc;
    float* ADJ  = NB + Mc * Cc;                        // 360,000
    float* CAND = ADJ + (long)Mc * Mc;                 // 512,000
    float* ATTB = CAND + (long)MAXBW * Nc * Cc;        // 3,072,000
    float* QHf  = ATTB + (long)MAXBW * Mc * ATTc;
    const long QSZ = (long)MAXBW * Mc * ATTc / 2;      // in floats
    float* QLf  = QHf + QSZ;
    float* KHf  = QLf + QSZ;
    float* KLf  = KHf + QSZ;
    float* VTHf = KLf + QSZ;
    float* VTLf = VTHf + (long)MAXBW * ATTc * MPAD / 2;

    ushort* QH  = (ushort*)QHf;
    ushort* QL  = (ushort*)QLf;
    ushort* KH  = (ushort*)KHf;
    ushort* KL  = (ushort*)KLf;
    ushort* VTH = (ushort*)VTHf;
    ushort* VTL = (ushort*)VTLf;

    const float inv_sqrt_att = 0.08838834764831845f;   // 1/sqrt(128)

    for (int layer = 0; layer < 2; layer++) {
        int Tin = layer ? 10 : 12;
        int nw  = Tin - 2;
        int BW  = Bc * nw;                             // 40 then 32
        int Mtot = BW * Mc;
        const float* src  = layer ? CAND : x;
        const float* temb = layer ? temb1 : temb0;

        long etotal = (long)BW * Mc * Cc;
        embed_window_k<<<dim3((unsigned)((etotal + 255) / 256)), dim3(256), 0, stream>>>(
            src, temb, semb, CUR, Tin, nw, etotal);

        for (int it = 0; it < 3; it++) {
            // adjacency: mean -> NA/NB -> sigmoid(NA NB^T / 8)
            mean_nab_k<<<dim3(38), dim3(256), 0, stream>>>(CUR, Wa, Wb, NA, NB, BW);
            gemm_k<true, 1><<<dim3(10, 10, 1), dim3(256), 0, stream>>>(
                NA, NB, nullptr, ADJ, Mc, Mc, Cc, Cc, Cc, Mc, 0, 0, 0, 0.125f);

            // QKV projection + hi/lo split
            qkv_split_k<<<dim3(3, 5, BW), dim3(256), 0, stream>>>(
                CUR, Wqkv, bqkv, QH, QL, KH, KL, VTH, VTL);

            // fused attention (P in LDS, no-max softmax, scale folded in)
            attn_k<<<dim3(BW * 10), dim3(256), 0, stream>>>(
                QH, QL, KH, KL, VTH, VTL, ADJ, ATTB, inv_sqrt_att);

            // cur = ATTB @ Wlin + blin
            gemm_k<false, 0><<<dim3(1, (Mtot + 63) / 64, 1), dim3(256), 0, stream>>>(
                ATTB, Wlin, blin, CUR, Mtot, Cc, ATTc, ATTc, Cc, Cc, 0, 0, 0, 1.f);

            // running max of middle window
            long mtot = (long)BW * Nc * Cc;
            cand_update_k<<<dim3((unsigned)((mtot + 255) / 256)), dim3(256), 0, stream>>>(
                CUR, CAND, 0, mtot, it == 0 ? 1 : 0);
        }
    }
    output_k<<<dim3(Bc * Nc), dim3(128), 0, stream>>>(CAND, Wo, bo, out);
}